// Round 2
// baseline (5909.898 us; speedup 1.0000x reference)
//
#include <hip/hip_runtime.h>
#include <math.h>
#include <stdint.h>

#define NFL   16384
#define NCELL 64

struct EdgeData { int src; int ixiy; float fx; float fy; };
struct Pair     { int src; int tgt;  float w; };

__device__ __forceinline__ float frelu(float x){ return x > 0.f ? x : 0.f; }

// ---------------------------------------------------------------- prep edges
__global__ void prep_edges_k(const float* __restrict__ qpos,
                             const float* __restrict__ ppos,
                             const int* __restrict__ tgt,
                             const int* __restrict__ src,
                             int nE, float support, float sgn,
                             EdgeData* __restrict__ out)
{
    int e = blockIdx.x * blockDim.x + threadIdx.x;
    if (e >= nE) return;
    int t = tgt[e], s = src[e];
    float dx = sgn * (ppos[2*s]   - qpos[2*t])   / support;
    float dy = sgn * (ppos[2*s+1] - qpos[2*t+1]) / support;
    dx = fminf(1.f, fmaxf(-1.f, dx));
    dy = fminf(1.f, fmaxf(-1.f, dy));
    float r  = sqrtf(dx*dx + dy*dy + 1e-12f);
    float th = atan2f(dy, dx);
    float m0 = fminf(1.f, fmaxf(-1.f, 2.f*r - 1.f));
    float m1 = fminf(1.f, fmaxf(-1.f, th * 0.3183098861837907f));
    float u = (m0 + 1.f) * 3.5f;
    float v = (m1 + 1.f) * 3.5f;
    int ix = (int)u; if (ix > 6) ix = 6;
    int iy = (int)v; if (iy > 6) iy = 6;
    EdgeData ed;
    ed.src  = s;
    ed.ixiy = ix*8 + iy;
    ed.fx   = u - (float)ix;
    ed.fy   = v - (float)iy;
    out[e] = ed;
}

// ------------------------------------------------- cell-bucket build (fluid)
__global__ void zero_cnt_k(int* __restrict__ cnt)
{
    int i = threadIdx.x;
    if (i < NCELL) cnt[i] = 0;
}

__global__ void hist_k(const EdgeData* __restrict__ ed, int nE, int* __restrict__ cnt)
{
    int e = blockIdx.x * blockDim.x + threadIdx.x;
    if (e >= nE) return;
    int k = ed[e].ixiy;
    atomicAdd(&cnt[k],   1);
    atomicAdd(&cnt[k+1], 1);
    atomicAdd(&cnt[k+8], 1);
    atomicAdd(&cnt[k+9], 1);
}

__global__ void scan_k(const int* __restrict__ cnt, int* __restrict__ cellOff,
                       int* __restrict__ cursor)
{
    if (threadIdx.x == 0){
        int s = 0;
        for (int k = 0; k < NCELL; ++k){ cellOff[k] = s; cursor[k] = s; s += cnt[k]; }
        cellOff[NCELL] = s;
    }
}

__global__ void scatter_k(const EdgeData* __restrict__ ed, const int* __restrict__ tgt,
                          int nE, int* __restrict__ cursor, Pair* __restrict__ pairs)
{
    int e = blockIdx.x * blockDim.x + threadIdx.x;
    if (e >= nE) return;
    EdgeData d = ed[e];
    int t = tgt[e];
    float fx = d.fx, fy = d.fy;
    float w00 = (1.f-fx)*(1.f-fy), w01 = (1.f-fx)*fy, w10 = fx*(1.f-fy), w11 = fx*fy;
    int k = d.ixiy;
    int p;
    p = atomicAdd(&cursor[k],   1); pairs[p] = {d.src, t, w00};
    p = atomicAdd(&cursor[k+1], 1); pairs[p] = {d.src, t, w01};
    p = atomicAdd(&cursor[k+8], 1); pairs[p] = {d.src, t, w10};
    p = atomicAdd(&cursor[k+9], 1); pairs[p] = {d.src, t, w11};
}

// --------------------------------------- lin0 + conv0 accumulator init (bc0)
__global__ void lin0_k(const float* __restrict__ feat,
                       const float* __restrict__ Wl0,
                       const float* __restrict__ bl0,
                       const float* __restrict__ bc0,
                       float* __restrict__ ansA)
{
    int idx = blockIdx.x * blockDim.x + threadIdx.x;
    if (idx >= NFL*64) return;
    int t = idx >> 6, c = idx & 63;
    if (c < 32){
        float a = bl0[c];
#pragma unroll
        for (int ci = 0; ci < 8; ++ci)
            a += feat[t*8 + ci] * Wl0[ci*32 + c];
        ansA[(size_t)t*96 + c] = a;
    } else {
        ansA[(size_t)t*96 + c] = bc0[c-32];   // init for conv0 atomic accumulation
    }
}

// -------------------- dns branch + biases (+residual) -> init y; write relu x
template<int CIN, int COUT, bool RESID>
__global__ __launch_bounds__(256)
void dns_init_k(const float* __restrict__ prev,
                const float* __restrict__ Wl, const float* __restrict__ bl,
                const float* __restrict__ bc,
                float* __restrict__ xr,
                float* __restrict__ y)
{
    int t = blockIdx.x * (blockDim.x >> 6) + (threadIdx.x >> 6);
    if (t >= NFL) return;
    int lane = threadIdx.x & 63;
    const float* pr = prev + (size_t)t * CIN;
    for (int ci = lane; ci < CIN; ci += 64)
        xr[(size_t)t*CIN + ci] = frelu(pr[ci]);
    int cl = lane < COUT ? lane : 0;
    float acc = bl[cl] + bc[cl];
#pragma unroll 8
    for (int ci = 0; ci < CIN; ++ci)
        acc += frelu(pr[ci]) * Wl[ci*COUT + cl];
    if (RESID) acc += pr[cl];
    if (lane < COUT) y[(size_t)t*COUT + cl] = acc;
}

// --------------------------------------------- cell-bucketed conv (the meat)
// Pairs sorted by cell. Block handles a contiguous pair range; stages each
// cell's W (transposed, padded) in LDS; each wave processes PPI pairs per
// W-read (ds_read_b128 amortized over PPI accumulators); x rows via scalar
// loads (pair index is wave-uniform); atomicAdd scatter to y.
template<int CIN, int COUT, int PPI>
__global__ __launch_bounds__(256)
void conv_pairs_k(const float* __restrict__ xr,
                  const Pair* __restrict__ pairs,
                  const int* __restrict__ cellOff,     // [NCELL+1]
                  const float* __restrict__ Wc,        // [NCELL][CIN][COUT]
                  float* __restrict__ y, int ystride, int yoff,
                  int nP, int pairsPerBlock)
{
    constexpr int CINP = CIN + 4;                      // keeps 16B row alignment, breaks bank stride
    __shared__ float WT[COUT][CINP];

    int p0 = blockIdx.x * pairsPerBlock;
    int p1 = min(nP, p0 + pairsPerBlock);
    if (p0 >= p1) return;

    int tid  = threadIdx.x;
    int lane = tid & 63;
    int wave = tid >> 6;
    int cl   = lane < COUT ? lane : 0;

    // cell containing p0
    int cell = 0;
    { int lo = 0, hi = NCELL;
      while (hi - lo > 1){ int mid = (lo + hi) >> 1; if (cellOff[mid] <= p0) lo = mid; else hi = mid; }
      cell = lo; }

    int p = p0;
    while (p < p1){
        while (cellOff[cell+1] <= p) ++cell;           // skip empty cells
        int pend = min(p1, cellOff[cell+1]);

        __syncthreads();
        for (int idx = tid; idx < CIN*COUT; idx += 256){
            int co = idx % COUT, ci = idx / COUT;
            WT[co][ci] = Wc[(size_t)cell*CIN*COUT + idx];
        }
        __syncthreads();

        for (int q = p + wave*PPI; q < pend; q += 4*PPI){
            int   srcs[PPI], tgts[PPI];
            float ws[PPI];
#pragma unroll
            for (int j = 0; j < PPI; ++j){
                int qq = q + j;
                bool ok = qq < pend;
                Pair pr = pairs[ok ? qq : q];          // pad with valid pair, w=0
                srcs[j] = __builtin_amdgcn_readfirstlane(pr.src);
                tgts[j] = __builtin_amdgcn_readfirstlane(pr.tgt);
                ws[j]   = ok ? pr.w : 0.f;
            }
            float acc[PPI];
#pragma unroll
            for (int j = 0; j < PPI; ++j) acc[j] = 0.f;

#pragma unroll
            for (int ci = 0; ci < CIN; ci += 4){
                float4 wv = *(const float4*)&WT[cl][ci];
#pragma unroll
                for (int j = 0; j < PPI; ++j){
                    const float* xp = xr + (size_t)srcs[j]*CIN + ci;
                    acc[j] += wv.x*xp[0] + wv.y*xp[1] + wv.z*xp[2] + wv.w*xp[3];
                }
            }
            if (lane < COUT){
#pragma unroll
                for (int j = 0; j < PPI; ++j)
                    atomicAdd(&y[(size_t)tgts[j]*ystride + yoff + cl], ws[j]*acc[j]);
            }
        }
        p = pend;
    }
}

// ------------------------------- per-target conv (kept for bconv + final 64->2)
template<int CIN, int COUT, bool RELU_IN, bool HAS_DNS, bool RESID, bool FINAL>
__global__ __launch_bounds__(256)
void conv_tgt_k(const float* __restrict__ xsrc,
                const float* __restrict__ xtgt,
                const EdgeData* __restrict__ ed,
                const int* __restrict__ tgt, int nE,
                const float* __restrict__ Wc, const float* __restrict__ bc,
                const float* __restrict__ Wl, const float* __restrict__ bl,
                float* __restrict__ out, int out_stride, int out_off)
{
    int t = blockIdx.x * (blockDim.x >> 6) + (threadIdx.x >> 6);
    if (t >= NFL) return;
    int lane = threadIdx.x & 63;
    int cl = lane < COUT ? lane : 0;

    int lo = 0, hi = nE;
    while (lo < hi){ int mid = (lo + hi) >> 1; if (tgt[mid] <  t) lo = mid + 1; else hi = mid; }
    int eb = lo; hi = nE;
    while (lo < hi){ int mid = (lo + hi) >> 1; if (tgt[mid] <= t) lo = mid + 1; else hi = mid; }
    int ee = lo;

    float acc = 0.f;
    for (int e = eb; e < ee; ++e){
        EdgeData d = ed[e];
        int s  = __builtin_amdgcn_readfirstlane(d.src);
        int kk = __builtin_amdgcn_readfirstlane(d.ixiy);
        const float* xp = xsrc + (size_t)s * CIN;
        const float* wp = Wc + (size_t)kk * (CIN*COUT) + cl;
        float t00 = 0.f, t01 = 0.f, t10 = 0.f, t11 = 0.f;
#pragma unroll 8
        for (int ci = 0; ci < CIN; ++ci){
            float xv = xp[ci];
            if (RELU_IN) xv = frelu(xv);
            t00 += xv * wp[ci*COUT];
            t01 += xv * wp[ci*COUT +   CIN*COUT];
            t10 += xv * wp[ci*COUT + 8*CIN*COUT];
            t11 += xv * wp[ci*COUT + 9*CIN*COUT];
        }
        float wx1 = d.fx, wy1 = d.fy;
        float wx0 = 1.f - wx1, wy0 = 1.f - wy1;
        acc += (wx0*wy0)*t00 + (wx0*wy1)*t01 + (wx1*wy0)*t10 + (wx1*wy1)*t11;
    }
    acc += bc[cl];

    if (HAS_DNS){
        const float* xt = xtgt + (size_t)t * CIN;
        float td = 0.f;
#pragma unroll 8
        for (int ci = 0; ci < CIN; ++ci)
            td += frelu(xt[ci]) * Wl[ci*COUT + cl];
        acc += td + bl[cl];
        if (RESID) acc += xt[cl];
    }
    if (FINAL) acc *= (1.0f/128.0f);
    if (lane < COUT)
        out[(size_t)t*out_stride + out_off + lane] = acc;
}

// ---------------------------------------------------------------------------
extern "C" void kernel_launch(void* const* d_in, const int* in_sizes, int n_in,
                              void* d_out, int out_size, void* d_ws, size_t ws_size,
                              hipStream_t stream)
{
    const float* fluid_pos  = (const float*)d_in[0];
    const float* bnd_pos    = (const float*)d_in[1];
    const float* fluid_feat = (const float*)d_in[2];
    const float* bnd_feat   = (const float*)d_in[3];
    const int*   f_tgt      = (const int*)  d_in[4];
    const int*   f_src      = (const int*)  d_in[5];
    const int*   b_tgt      = (const int*)  d_in[6];
    const int*   b_src      = (const int*)  d_in[7];
    const float* Wc0 = (const float*)d_in[8];  const float* bc0 = (const float*)d_in[9];
    const float* Wc1 = (const float*)d_in[10]; const float* bc1 = (const float*)d_in[11];
    const float* Wc2 = (const float*)d_in[12]; const float* bc2 = (const float*)d_in[13];
    const float* Wc3 = (const float*)d_in[14]; const float* bc3 = (const float*)d_in[15];
    const float* Wc4 = (const float*)d_in[16]; const float* bc4 = (const float*)d_in[17];
    const float* Wl0 = (const float*)d_in[18]; const float* bl0 = (const float*)d_in[19];
    const float* Wl1 = (const float*)d_in[20]; const float* bl1 = (const float*)d_in[21];
    const float* Wl2 = (const float*)d_in[22]; const float* bl2 = (const float*)d_in[23];
    const float* Wl3 = (const float*)d_in[24]; const float* bl3 = (const float*)d_in[25];

    int nEf = in_sizes[4];
    int nEb = in_sizes[6];
    int nP  = 4 * nEf;
    float support = (float)sqrt(16.0 / (M_PI * 16384.0));

    char* w = (char*)d_ws;
    auto alloc = [&](size_t bytes){ char* r = w; w += (bytes + 255) & ~(size_t)255; return r; };
    EdgeData* edF     = (EdgeData*)alloc((size_t)nEf * sizeof(EdgeData));
    EdgeData* edB     = (EdgeData*)alloc((size_t)nEb * sizeof(EdgeData));
    int*      cnt     = (int*)     alloc(NCELL * sizeof(int));
    int*      cellOff = (int*)     alloc((NCELL+1) * sizeof(int));
    int*      cursor  = (int*)     alloc(NCELL * sizeof(int));
    Pair*     pairs   = (Pair*)    alloc((size_t)nP * sizeof(Pair));
    float*    ansA    = (float*)   alloc((size_t)NFL * 96 * sizeof(float));
    float*    xrA     = (float*)   alloc((size_t)NFL * 96 * sizeof(float));
    float*    y1      = (float*)   alloc((size_t)NFL * 64 * sizeof(float));
    float*    xr1     = (float*)   alloc((size_t)NFL * 64 * sizeof(float));
    float*    y2      = (float*)   alloc((size_t)NFL * 64 * sizeof(float));

    // edge prep (+ bucket build, shared by conv0/conv2/conv3)
    prep_edges_k<<<(nEf+255)/256, 256, 0, stream>>>(fluid_pos, fluid_pos, f_tgt, f_src, nEf, support, -1.f, edF);
    prep_edges_k<<<(nEb+255)/256, 256, 0, stream>>>(fluid_pos, bnd_pos,   b_tgt, b_src, nEb, support,  1.f, edB);
    zero_cnt_k<<<1, 64, 0, stream>>>(cnt);
    hist_k<<<(nEf+255)/256, 256, 0, stream>>>(edF, nEf, cnt);
    scan_k<<<1, 64, 0, stream>>>(cnt, cellOff, cursor);
    scatter_k<<<(nEf+255)/256, 256, 0, stream>>>(edF, f_tgt, nEf, cursor, pairs);

    const int PB = 1024;
    int nBlk = (nP + PB - 1) / PB;

    // input block: lin (cols 0:32) + conv0-init bc0 (cols 32:64)
    lin0_k<<<(NFL*64+255)/256, 256, 0, stream>>>(fluid_feat, Wl0, bl0, bc0, ansA);
    // conv0: fluid_feat -> ansA[:,32:64] (atomic accumulate)
    conv_pairs_k<8,32,8><<<nBlk, 256, 0, stream>>>(fluid_feat, pairs, cellOff, Wc0, ansA, 96, 32, nP, PB);
    // bconv: bnd_feat -> ansA[:,64:96] (per-target, includes bias)
    conv_tgt_k<8,32,false,false,false,false><<<NFL/4, 256, 0, stream>>>(bnd_feat, nullptr, edB, b_tgt, nEb, Wc1, bc1, nullptr, nullptr, ansA, 96, 64);

    // block 1: y1 = conv(relu(ansA),Wc2)+bc2 + relu(ansA)@Wl1+bl1
    dns_init_k<96,64,false><<<NFL/4, 256, 0, stream>>>(ansA, Wl1, bl1, bc2, xrA, y1);
    conv_pairs_k<96,64,8><<<nBlk, 256, 0, stream>>>(xrA, pairs, cellOff, Wc2, y1, 64, 0, nP, PB);

    // block 2: y2 = conv(relu(y1),Wc3)+bc3 + relu(y1)@Wl2+bl2 + y1
    dns_init_k<64,64,true><<<NFL/4, 256, 0, stream>>>(y1, Wl2, bl2, bc3, xr1, y2);
    conv_pairs_k<64,64,8><<<nBlk, 256, 0, stream>>>(xr1, pairs, cellOff, Wc3, y2, 64, 0, nP, PB);

    // block 3 (final): out = (conv(relu(y2),Wc4)+bc4 + relu(y2)@Wl3+bl3)/128
    conv_tgt_k<64,2,true,true,false,true><<<NFL/4, 256, 0, stream>>>(y2, y2, edF, f_tgt, nEf, Wc4, bc4, Wl3, bl3, (float*)d_out, 2, 0);
}

// Round 3
// 1290.322 us; speedup vs baseline: 4.5802x; 4.5802x over previous
//
#include <hip/hip_runtime.h>
#include <math.h>
#include <stdint.h>

#define NFL   16384
#define NCC   55      // base cells: ix,iy in 0..6 -> ixiy = ix*8+iy in 0..54
#define PADQ  128     // bucket pad quantum (multiple of all TILE_E)

struct EdgeData { int src; int ixiy; float fx; float fy; };

__device__ __forceinline__ float frelu(float x){ return x > 0.f ? x : 0.f; }
__device__ __forceinline__ unsigned short f2bf(float f){
    unsigned int u = __float_as_uint(f);
    unsigned int r = (u + 0x7FFFu + ((u >> 16) & 1u)) >> 16;   // RNE
    return (unsigned short)r;
}

// ---------------------------------------------------------------- prep edges
__global__ void prep_edges_k(const float* __restrict__ qpos,
                             const float* __restrict__ ppos,
                             const int* __restrict__ tgt,
                             const int* __restrict__ src,
                             int nE, float support, float sgn,
                             EdgeData* __restrict__ out)
{
    int e = blockIdx.x * blockDim.x + threadIdx.x;
    if (e >= nE) return;
    int t = tgt[e], s = src[e];
    float dx = sgn * (ppos[2*s]   - qpos[2*t])   / support;
    float dy = sgn * (ppos[2*s+1] - qpos[2*t+1]) / support;
    dx = fminf(1.f, fmaxf(-1.f, dx));
    dy = fminf(1.f, fmaxf(-1.f, dy));
    float r  = sqrtf(dx*dx + dy*dy + 1e-12f);
    float th = atan2f(dy, dx);
    float m0 = fminf(1.f, fmaxf(-1.f, 2.f*r - 1.f));
    float m1 = fminf(1.f, fmaxf(-1.f, th * 0.3183098861837907f));
    float u = (m0 + 1.f) * 3.5f;
    float v = (m1 + 1.f) * 3.5f;
    int ix = (int)u; if (ix > 6) ix = 6;
    int iy = (int)v; if (iy > 6) iy = 6;
    EdgeData ed;
    ed.src  = s;
    ed.ixiy = ix*8 + iy;
    ed.fx   = u - (float)ix;
    ed.fy   = v - (float)iy;
    out[e] = ed;
}

// ------------------------------------------------------------- bucket build
__global__ void zero64_k(int* __restrict__ a){ if (threadIdx.x < 64) a[threadIdx.x] = 0; }

__global__ void hist_k(const EdgeData* __restrict__ ed, int nE, int* __restrict__ cnt)
{
    __shared__ int lc[64];
    int tid = threadIdx.x;
    if (tid < 64) lc[tid] = 0;
    __syncthreads();
    int e = blockIdx.x * blockDim.x + tid;
    if (e < nE) atomicAdd(&lc[ed[e].ixiy], 1);
    __syncthreads();
    if (tid < 64 && lc[tid] > 0) atomicAdd(&cnt[tid], lc[tid]);
}

__global__ void scan_pad_k(const int* __restrict__ cnt, int* __restrict__ cellOff,
                           int* __restrict__ gcursor)
{
    if (threadIdx.x < 64) gcursor[threadIdx.x] = 0;
    if (threadIdx.x == 0){
        int s = 0;
        for (int k = 0; k < NCC; ++k){
            cellOff[k] = s;
            s += ((cnt[k] + PADQ - 1) / PADQ) * PADQ;
        }
        cellOff[NCC] = s;
    }
}

__global__ void fill_entries_k(int4* __restrict__ entries, int n)
{
    int i = blockIdx.x * blockDim.x + threadIdx.x;
    if (i < n) entries[i] = make_int4(0, -1, 0, 0);
}

__global__ void scatter_k(const EdgeData* __restrict__ ed, int nE,
                          const int* __restrict__ cellOff,
                          int* __restrict__ gcursor,
                          int4* __restrict__ entries,
                          int* __restrict__ e2s)
{
    __shared__ int lc[64], base[64];
    int tid = threadIdx.x;
    if (tid < 64) lc[tid] = 0;
    __syncthreads();
    int e = blockIdx.x * blockDim.x + tid;
    bool ok = e < nE;
    EdgeData d; int k = 0, r = 0;
    if (ok){ d = ed[e]; k = d.ixiy; r = atomicAdd(&lc[k], 1); }
    __syncthreads();
    if (tid < 64 && lc[tid] > 0) base[tid] = atomicAdd(&gcursor[tid], lc[tid]);
    __syncthreads();
    if (ok){
        int slot = cellOff[k] + base[k] + r;
        entries[slot] = make_int4(d.src, e, __float_as_int(d.fx), __float_as_int(d.fy));
        e2s[e] = slot;
    }
}

// ------------------------------------------------------------ W fp32 -> bf16
__global__ void wcvt_k(const float* __restrict__ in, unsigned short* __restrict__ out, int n)
{
    int i = blockIdx.x * blockDim.x + threadIdx.x;
    if (i < n) out[i] = f2bf(in[i]);
}

// ------------------------------------------- bucketed conv: edges -> messages
// Block = 128 threads, TILE_E edges of ONE cell. 4 corner W's (bf16) + x-tile
// (fp32, transposed) staged in LDS. Thread = 4 edges x 8 couts. Corner-split
// accumulators; bilinear combine in registers; per-edge msg store (no atomics).
template<int CIN, int COUT, int TILE_E, bool RELU>
__global__ __launch_bounds__(128)
void conv_cell_k(const float* __restrict__ x,
                 const int4* __restrict__ entries,
                 const int* __restrict__ cellOff,
                 const unsigned short* __restrict__ Wbf,   // [64][CIN][COUT] bf16
                 float* __restrict__ msg)                  // [slot][COUT]
{
    constexpr int TEP = TILE_E + 4;          // dword stride; (TEP*4)%16==0
    constexpr int EG  = TILE_E / 4;
    constexpr int CG  = COUT / 8;
    static_assert(EG * CG == 128, "tile/thread mismatch");
    constexpr int C4  = CIN / 4;

    __shared__ float XT[CIN][TEP];
    __shared__ unsigned short WL[4][CIN][COUT];
    __shared__ int4 EN[TILE_E];

    int total = cellOff[NCC];
    int p0 = blockIdx.x * TILE_E;
    if (p0 >= total) return;
    int tid = threadIdx.x;

    // cell of this chunk (chunks never straddle cells: counts padded to PADQ)
    int lo = 0, hi = NCC;
    while (hi - lo > 1){ int mid = (lo + hi) >> 1; if (cellOff[mid] <= p0) lo = mid; else hi = mid; }
    const int cell = lo;

    // stage entries
    for (int i = tid; i < TILE_E; i += 128) EN[i] = entries[p0 + i];

    // stage 4 corner W's (bf16)
    const int kc[4] = { cell, cell + 1, cell + 8, cell + 9 };
#pragma unroll
    for (int c = 0; c < 4; ++c){
        const uint4* s = (const uint4*)(Wbf + (size_t)kc[c] * (CIN * COUT));
        uint4* dlds = (uint4*)(&WL[c][0][0]);
        for (int i = tid; i < CIN * COUT / 8; i += 128) dlds[i] = s[i];
    }
    __syncthreads();

    // stage x-tile transposed (relu folded on gather)
    for (int i = tid; i < TILE_E * C4; i += 128){
        int e  = i / C4;
        int c4 = i - e * C4;
        int4 en = EN[e];
        float4 v = make_float4(0.f, 0.f, 0.f, 0.f);
        if (en.y >= 0){
            v = *(const float4*)(x + (size_t)en.x * CIN + 4 * c4);
            if (RELU){ v.x = frelu(v.x); v.y = frelu(v.y); v.z = frelu(v.z); v.w = frelu(v.w); }
        }
        XT[4*c4+0][e] = v.x;
        XT[4*c4+1][e] = v.y;
        XT[4*c4+2][e] = v.z;
        XT[4*c4+3][e] = v.w;
    }
    __syncthreads();

    const int egrp = tid % EG;
    const int cgrp = tid / EG;
    const int e0 = egrp * 4;

    float fx[4], fy[4];
#pragma unroll
    for (int j = 0; j < 4; ++j){
        int4 en = EN[e0 + j];
        fx[j] = __int_as_float(en.z);
        fy[j] = __int_as_float(en.w);
    }

    float accT[4][8];
#pragma unroll
    for (int j = 0; j < 4; ++j)
#pragma unroll
        for (int c = 0; c < 8; ++c) accT[j][c] = 0.f;

#pragma unroll
    for (int cr = 0; cr < 4; ++cr){
        float accC[4][8];
#pragma unroll
        for (int j = 0; j < 4; ++j)
#pragma unroll
            for (int c = 0; c < 8; ++c) accC[j][c] = 0.f;

#pragma unroll 4
        for (int ci = 0; ci < CIN; ++ci){
            float4 xv = *(const float4*)&XT[ci][e0];
            uint4 wp = *(const uint4*)&WL[cr][ci][cgrp * 8];
            float wf0 = __uint_as_float(wp.x << 16);
            float wf1 = __uint_as_float(wp.x & 0xFFFF0000u);
            float wf2 = __uint_as_float(wp.y << 16);
            float wf3 = __uint_as_float(wp.y & 0xFFFF0000u);
            float wf4 = __uint_as_float(wp.z << 16);
            float wf5 = __uint_as_float(wp.z & 0xFFFF0000u);
            float wf6 = __uint_as_float(wp.w << 16);
            float wf7 = __uint_as_float(wp.w & 0xFFFF0000u);
            const float xe[4] = { xv.x, xv.y, xv.z, xv.w };
#pragma unroll
            for (int j = 0; j < 4; ++j){
                accC[j][0] += xe[j] * wf0;
                accC[j][1] += xe[j] * wf1;
                accC[j][2] += xe[j] * wf2;
                accC[j][3] += xe[j] * wf3;
                accC[j][4] += xe[j] * wf4;
                accC[j][5] += xe[j] * wf5;
                accC[j][6] += xe[j] * wf6;
                accC[j][7] += xe[j] * wf7;
            }
        }
#pragma unroll
        for (int j = 0; j < 4; ++j){
            float wc = (cr == 0) ? (1.f - fx[j]) * (1.f - fy[j]) :
                       (cr == 1) ? (1.f - fx[j]) * fy[j] :
                       (cr == 2) ? fx[j] * (1.f - fy[j]) :
                                   fx[j] * fy[j];
#pragma unroll
            for (int c = 0; c < 8; ++c) accT[j][c] += wc * accC[j][c];
        }
    }

#pragma unroll
    for (int j = 0; j < 4; ++j){
        float* mp = msg + (size_t)(p0 + e0 + j) * COUT + cgrp * 8;
        *(float4*)mp       = make_float4(accT[j][0], accT[j][1], accT[j][2], accT[j][3]);
        *(float4*)(mp + 4) = make_float4(accT[j][4], accT[j][5], accT[j][6], accT[j][7]);
    }
}

// --------------------------------------------- combine: msg-sum + dns + bias
// wave per target; lane = cout
__global__ __launch_bounds__(256)
void combine0_k(const float* __restrict__ feat,
                const float* __restrict__ Wl0, const float* __restrict__ bl0,
                const float* __restrict__ bc0,
                const float* __restrict__ msg,           // [slot][32]
                const int* __restrict__ e2s,
                const int* __restrict__ tgt, int nE,
                float* __restrict__ ansA)
{
    int t = blockIdx.x * (blockDim.x >> 6) + (threadIdx.x >> 6);
    if (t >= NFL) return;
    int lane = threadIdx.x & 63;

    int lo = 0, hi = nE;
    while (lo < hi){ int mid = (lo + hi) >> 1; if (tgt[mid] <  t) lo = mid + 1; else hi = mid; }
    int eb = lo; hi = nE;
    while (lo < hi){ int mid = (lo + hi) >> 1; if (tgt[mid] <= t) lo = mid + 1; else hi = mid; }
    int ee = lo;

    if (lane < 32){
        float a = bl0[lane];
#pragma unroll
        for (int ci = 0; ci < 8; ++ci)
            a += feat[t*8 + ci] * Wl0[ci*32 + lane];
        ansA[(size_t)t*96 + lane] = a;
    } else {
        int c = lane - 32;
        float a = bc0[c];
        for (int e = eb; e < ee; ++e){
            int slot = e2s[e];
            a += msg[(size_t)slot*32 + c];
        }
        ansA[(size_t)t*96 + 32 + c] = a;
    }
}

template<int CIN, bool RESID>
__global__ __launch_bounds__(256)
void combine12_k(const float* __restrict__ prev,
                 const float* __restrict__ Wl, const float* __restrict__ bl,
                 const float* __restrict__ bc,
                 const float* __restrict__ msg,          // [slot][64]
                 const int* __restrict__ e2s,
                 const int* __restrict__ tgt, int nE,
                 float* __restrict__ y)
{
    int t = blockIdx.x * (blockDim.x >> 6) + (threadIdx.x >> 6);
    if (t >= NFL) return;
    int lane = threadIdx.x & 63;

    int lo = 0, hi = nE;
    while (lo < hi){ int mid = (lo + hi) >> 1; if (tgt[mid] <  t) lo = mid + 1; else hi = mid; }
    int eb = lo; hi = nE;
    while (lo < hi){ int mid = (lo + hi) >> 1; if (tgt[mid] <= t) lo = mid + 1; else hi = mid; }
    int ee = lo;

    const float* pr = prev + (size_t)t * CIN;
    float acc = bc[lane] + bl[lane];
#pragma unroll 8
    for (int ci = 0; ci < CIN; ++ci)
        acc += frelu(pr[ci]) * Wl[ci*64 + lane];
    if (RESID) acc += pr[lane];

    for (int e = eb; e < ee; ++e){
        int slot = e2s[e];
        acc += msg[(size_t)slot*64 + lane];
    }
    y[(size_t)t*64 + lane] = acc;
}

// ----------------------- per-target conv (bconv + final 64->2), round-1 style
template<int CIN, int COUT, bool RELU_IN, bool HAS_DNS, bool RESID, bool FINAL>
__global__ __launch_bounds__(256)
void conv_tgt_k(const float* __restrict__ xsrc,
                const float* __restrict__ xtgt,
                const EdgeData* __restrict__ ed,
                const int* __restrict__ tgt, int nE,
                const float* __restrict__ Wc, const float* __restrict__ bc,
                const float* __restrict__ Wl, const float* __restrict__ bl,
                float* __restrict__ out, int out_stride, int out_off)
{
    int t = blockIdx.x * (blockDim.x >> 6) + (threadIdx.x >> 6);
    if (t >= NFL) return;
    int lane = threadIdx.x & 63;
    int cl = lane < COUT ? lane : 0;

    int lo = 0, hi = nE;
    while (lo < hi){ int mid = (lo + hi) >> 1; if (tgt[mid] <  t) lo = mid + 1; else hi = mid; }
    int eb = lo; hi = nE;
    while (lo < hi){ int mid = (lo + hi) >> 1; if (tgt[mid] <= t) lo = mid + 1; else hi = mid; }
    int ee = lo;

    float acc = 0.f;
    for (int e = eb; e < ee; ++e){
        EdgeData d = ed[e];
        int s  = __builtin_amdgcn_readfirstlane(d.src);
        int kk = __builtin_amdgcn_readfirstlane(d.ixiy);
        const float* xp = xsrc + (size_t)s * CIN;
        const float* wp = Wc + (size_t)kk * (CIN*COUT) + cl;
        float t00 = 0.f, t01 = 0.f, t10 = 0.f, t11 = 0.f;
#pragma unroll 8
        for (int ci = 0; ci < CIN; ++ci){
            float xv = xp[ci];
            if (RELU_IN) xv = frelu(xv);
            t00 += xv * wp[ci*COUT];
            t01 += xv * wp[ci*COUT +   CIN*COUT];
            t10 += xv * wp[ci*COUT + 8*CIN*COUT];
            t11 += xv * wp[ci*COUT + 9*CIN*COUT];
        }
        float wx1 = d.fx, wy1 = d.fy;
        float wx0 = 1.f - wx1, wy0 = 1.f - wy1;
        acc += (wx0*wy0)*t00 + (wx0*wy1)*t01 + (wx1*wy0)*t10 + (wx1*wy1)*t11;
    }
    acc += bc[cl];

    if (HAS_DNS){
        const float* xt = xtgt + (size_t)t * CIN;
        float td = 0.f;
#pragma unroll 8
        for (int ci = 0; ci < CIN; ++ci)
            td += frelu(xt[ci]) * Wl[ci*COUT + cl];
        acc += td + bl[cl];
        if (RESID) acc += xt[cl];
    }
    if (FINAL) acc *= (1.0f/128.0f);
    if (lane < COUT)
        out[(size_t)t*out_stride + out_off + lane] = acc;
}

// ---------------------------------------------------------------------------
extern "C" void kernel_launch(void* const* d_in, const int* in_sizes, int n_in,
                              void* d_out, int out_size, void* d_ws, size_t ws_size,
                              hipStream_t stream)
{
    const float* fluid_pos  = (const float*)d_in[0];
    const float* bnd_pos    = (const float*)d_in[1];
    const float* fluid_feat = (const float*)d_in[2];
    const float* bnd_feat   = (const float*)d_in[3];
    const int*   f_tgt      = (const int*)  d_in[4];
    const int*   f_src      = (const int*)  d_in[5];
    const int*   b_tgt      = (const int*)  d_in[6];
    const int*   b_src      = (const int*)  d_in[7];
    const float* Wc0 = (const float*)d_in[8];  const float* bc0 = (const float*)d_in[9];
    const float* Wc1 = (const float*)d_in[10]; const float* bc1 = (const float*)d_in[11];
    const float* Wc2 = (const float*)d_in[12]; const float* bc2 = (const float*)d_in[13];
    const float* Wc3 = (const float*)d_in[14]; const float* bc3 = (const float*)d_in[15];
    const float* Wc4 = (const float*)d_in[16]; const float* bc4 = (const float*)d_in[17];
    const float* Wl0 = (const float*)d_in[18]; const float* bl0 = (const float*)d_in[19];
    const float* Wl1 = (const float*)d_in[20]; const float* bl1 = (const float*)d_in[21];
    const float* Wl2 = (const float*)d_in[22]; const float* bl2 = (const float*)d_in[23];
    const float* Wl3 = (const float*)d_in[24]; const float* bl3 = (const float*)d_in[25];

    int nEf = in_sizes[4];
    int nEb = in_sizes[6];
    int entPadMax = nEf + NCC * PADQ;
    float support = (float)sqrt(16.0 / (M_PI * 16384.0));

    char* w = (char*)d_ws;
    auto alloc = [&](size_t bytes){ char* r = w; w += (bytes + 255) & ~(size_t)255; return r; };
    EdgeData* edF      = (EdgeData*)alloc((size_t)nEf * sizeof(EdgeData));
    EdgeData* edB      = (EdgeData*)alloc((size_t)nEb * sizeof(EdgeData));
    int*      cnt      = (int*)     alloc(64 * sizeof(int));
    int*      cellOff  = (int*)     alloc(64 * sizeof(int));
    int*      gcursor  = (int*)     alloc(64 * sizeof(int));
    int4*     entries  = (int4*)    alloc((size_t)entPadMax * sizeof(int4));
    int*      e2s      = (int*)     alloc((size_t)nEf * sizeof(int));
    unsigned short* wb0 = (unsigned short*)alloc((size_t)64*8*32  * 2);
    unsigned short* wb2 = (unsigned short*)alloc((size_t)64*96*64 * 2);
    unsigned short* wb3 = (unsigned short*)alloc((size_t)64*64*64 * 2);
    float*    ansA     = (float*)   alloc((size_t)NFL * 96 * sizeof(float));
    float*    y1       = (float*)   alloc((size_t)NFL * 64 * sizeof(float));
    float*    y2       = (float*)   alloc((size_t)NFL * 64 * sizeof(float));
    float*    msg      = (float*)   alloc((size_t)entPadMax * 64 * sizeof(float));

    // ---- edge prep + bucket build (reused by conv0/conv1/conv2)
    prep_edges_k<<<(nEf+255)/256, 256, 0, stream>>>(fluid_pos, fluid_pos, f_tgt, f_src, nEf, support, -1.f, edF);
    prep_edges_k<<<(nEb+255)/256, 256, 0, stream>>>(fluid_pos, bnd_pos,   b_tgt, b_src, nEb, support,  1.f, edB);
    zero64_k<<<1, 64, 0, stream>>>(cnt);
    hist_k<<<(nEf+255)/256, 256, 0, stream>>>(edF, nEf, cnt);
    scan_pad_k<<<1, 64, 0, stream>>>(cnt, cellOff, gcursor);
    fill_entries_k<<<(entPadMax+255)/256, 256, 0, stream>>>(entries, entPadMax);
    scatter_k<<<(nEf+255)/256, 256, 0, stream>>>(edF, nEf, cellOff, gcursor, entries, e2s);

    // ---- W -> bf16 (once per launch; layouts identical)
    wcvt_k<<<(64*8*32 +255)/256, 256, 0, stream>>>(Wc0, wb0, 64*8*32);
    wcvt_k<<<(64*96*64+255)/256, 256, 0, stream>>>(Wc2, wb2, 64*96*64);
    wcvt_k<<<(64*64*64+255)/256, 256, 0, stream>>>(Wc3, wb3, 64*64*64);

    int grid64  = (entPadMax + 63)  / 64;
    int grid128 = (entPadMax + 127) / 128;
    dim3 tgrid(NFL/4);

    // ---- input block
    conv_cell_k<8,32,128,false><<<grid128, 128, 0, stream>>>(fluid_feat, entries, cellOff, wb0, msg);
    conv_tgt_k<8,32,false,false,false,false><<<tgrid, 256, 0, stream>>>(bnd_feat, nullptr, edB, b_tgt, nEb, Wc1, bc1, nullptr, nullptr, ansA, 96, 64);
    combine0_k<<<tgrid, 256, 0, stream>>>(fluid_feat, Wl0, bl0, bc0, msg, e2s, f_tgt, nEf, ansA);

    // ---- block 1: y1 = conv(relu(ansA),Wc2)+bc2 + relu(ansA)@Wl1+bl1
    conv_cell_k<96,64,64,true><<<grid64, 128, 0, stream>>>(ansA, entries, cellOff, wb2, msg);
    combine12_k<96,false><<<tgrid, 256, 0, stream>>>(ansA, Wl1, bl1, bc2, msg, e2s, f_tgt, nEf, y1);

    // ---- block 2: y2 = conv(relu(y1),Wc3)+bc3 + relu(y1)@Wl2+bl2 + y1
    conv_cell_k<64,64,64,true><<<grid64, 128, 0, stream>>>(y1, entries, cellOff, wb3, msg);
    combine12_k<64,true><<<tgrid, 256, 0, stream>>>(y1, Wl2, bl2, bc3, msg, e2s, f_tgt, nEf, y2);

    // ---- block 3 (final): out = (conv(relu(y2),Wc4)+bc4 + relu(y2)@Wl3+bl3)/128
    conv_tgt_k<64,2,true,true,false,true><<<tgrid, 256, 0, stream>>>(y2, y2, edF, f_tgt, nEf, Wc4, bc4, Wl3, bl3, (float*)d_out, 2, 0);
}

// Round 4
// 792.818 us; speedup vs baseline: 7.4543x; 1.6275x over previous
//
#include <hip/hip_runtime.h>
#include <math.h>
#include <stdint.h>

#define NFL   16384
#define NCC   55      // base cells: ix,iy in 0..6 -> ixiy = ix*8+iy in 0..54
#define PADQ  128     // bucket pad quantum (multiple of all TILE_E)

struct EdgeData { int src; int ixiy; float fx; float fy; };

__device__ __forceinline__ float frelu(float x){ return x > 0.f ? x : 0.f; }
__device__ __forceinline__ unsigned short f2bf(float f){
    unsigned int u = __float_as_uint(f);
    unsigned int r = (u + 0x7FFFu + ((u >> 16) & 1u)) >> 16;   // RNE
    return (unsigned short)r;
}

// ---------------------------------------------------------------- prep edges
__global__ void prep_edges_k(const float* __restrict__ qpos,
                             const float* __restrict__ ppos,
                             const int* __restrict__ tgt,
                             const int* __restrict__ src,
                             int nE, float support, float sgn,
                             EdgeData* __restrict__ out)
{
    int e = blockIdx.x * blockDim.x + threadIdx.x;
    if (e >= nE) return;
    int t = tgt[e], s = src[e];
    float dx = sgn * (ppos[2*s]   - qpos[2*t])   / support;
    float dy = sgn * (ppos[2*s+1] - qpos[2*t+1]) / support;
    dx = fminf(1.f, fmaxf(-1.f, dx));
    dy = fminf(1.f, fmaxf(-1.f, dy));
    float r  = sqrtf(dx*dx + dy*dy + 1e-12f);
    float th = atan2f(dy, dx);
    float m0 = fminf(1.f, fmaxf(-1.f, 2.f*r - 1.f));
    float m1 = fminf(1.f, fmaxf(-1.f, th * 0.3183098861837907f));
    float u = (m0 + 1.f) * 3.5f;
    float v = (m1 + 1.f) * 3.5f;
    int ix = (int)u; if (ix > 6) ix = 6;
    int iy = (int)v; if (iy > 6) iy = 6;
    EdgeData ed;
    ed.src  = s;
    ed.ixiy = ix*8 + iy;
    ed.fx   = u - (float)ix;
    ed.fy   = v - (float)iy;
    out[e] = ed;
}

// ------------------------------------------------------------- bucket build
__global__ void zero64_k(int* __restrict__ a){ if (threadIdx.x < 64) a[threadIdx.x] = 0; }

__global__ void hist_k(const EdgeData* __restrict__ ed, int nE, int* __restrict__ cnt)
{
    __shared__ int lc[64];
    int tid = threadIdx.x;
    if (tid < 64) lc[tid] = 0;
    __syncthreads();
    int e = blockIdx.x * blockDim.x + tid;
    if (e < nE) atomicAdd(&lc[ed[e].ixiy], 1);
    __syncthreads();
    if (tid < 64 && lc[tid] > 0) atomicAdd(&cnt[tid], lc[tid]);
}

__global__ void scan_pad_k(const int* __restrict__ cnt, int* __restrict__ cellOff,
                           int* __restrict__ gcursor)
{
    if (threadIdx.x < 64) gcursor[threadIdx.x] = 0;
    if (threadIdx.x == 0){
        int s = 0;
        for (int k = 0; k < NCC; ++k){
            cellOff[k] = s;
            s += ((cnt[k] + PADQ - 1) / PADQ) * PADQ;
        }
        cellOff[NCC] = s;
    }
}

__global__ void fill_entries_k(int4* __restrict__ entries, int n)
{
    int i = blockIdx.x * blockDim.x + threadIdx.x;
    if (i < n) entries[i] = make_int4(0, -1, 0, 0);
}

__global__ void scatter_k(const EdgeData* __restrict__ ed, int nE,
                          const int* __restrict__ cellOff,
                          int* __restrict__ gcursor,
                          int4* __restrict__ entries,
                          int* __restrict__ e2s)
{
    __shared__ int lc[64], base[64];
    int tid = threadIdx.x;
    if (tid < 64) lc[tid] = 0;
    __syncthreads();
    int e = blockIdx.x * blockDim.x + tid;
    bool ok = e < nE;
    EdgeData d; int k = 0, r = 0;
    if (ok){ d = ed[e]; k = d.ixiy; r = atomicAdd(&lc[k], 1); }
    __syncthreads();
    if (tid < 64 && lc[tid] > 0) base[tid] = atomicAdd(&gcursor[tid], lc[tid]);
    __syncthreads();
    if (ok){
        int slot = cellOff[k] + base[k] + r;
        entries[slot] = make_int4(d.src, e, __float_as_int(d.fx), __float_as_int(d.fy));
        e2s[e] = slot;
    }
}

// ------------------------------------------------------------ W fp32 -> bf16
__global__ void wcvt_k(const float* __restrict__ in, unsigned short* __restrict__ out, int n)
{
    int i = blockIdx.x * blockDim.x + threadIdx.x;
    if (i < n) out[i] = f2bf(in[i]);
}

// ------------------------------------------- bucketed conv: edges -> messages
template<int CIN, int COUT, int TILE_E, bool RELU>
__global__ __launch_bounds__(128)
void conv_cell_k(const float* __restrict__ x,
                 const int4* __restrict__ entries,
                 const int* __restrict__ cellOff,
                 const unsigned short* __restrict__ Wbf,   // [64][CIN][COUT] bf16
                 float* __restrict__ msg)                  // [slot][COUT]
{
    constexpr int TEP = TILE_E + 4;
    constexpr int EG  = TILE_E / 4;
    constexpr int CG  = COUT / 8;
    static_assert(EG * CG == 128, "tile/thread mismatch");
    constexpr int C4  = CIN / 4;

    __shared__ float XT[CIN][TEP];
    __shared__ unsigned short WL[4][CIN][COUT];
    __shared__ int4 EN[TILE_E];

    int total = cellOff[NCC];
    int p0 = blockIdx.x * TILE_E;
    if (p0 >= total) return;
    int tid = threadIdx.x;

    int lo = 0, hi = NCC;
    while (hi - lo > 1){ int mid = (lo + hi) >> 1; if (cellOff[mid] <= p0) lo = mid; else hi = mid; }
    const int cell = lo;

    for (int i = tid; i < TILE_E; i += 128) EN[i] = entries[p0 + i];

    const int kc[4] = { cell, cell + 1, cell + 8, cell + 9 };
#pragma unroll
    for (int c = 0; c < 4; ++c){
        const uint4* s = (const uint4*)(Wbf + (size_t)kc[c] * (CIN * COUT));
        uint4* dlds = (uint4*)(&WL[c][0][0]);
        for (int i = tid; i < CIN * COUT / 8; i += 128) dlds[i] = s[i];
    }
    __syncthreads();

    for (int i = tid; i < TILE_E * C4; i += 128){
        int e  = i / C4;
        int c4 = i - e * C4;
        int4 en = EN[e];
        float4 v = make_float4(0.f, 0.f, 0.f, 0.f);
        if (en.y >= 0){
            v = *(const float4*)(x + (size_t)en.x * CIN + 4 * c4);
            if (RELU){ v.x = frelu(v.x); v.y = frelu(v.y); v.z = frelu(v.z); v.w = frelu(v.w); }
        }
        XT[4*c4+0][e] = v.x;
        XT[4*c4+1][e] = v.y;
        XT[4*c4+2][e] = v.z;
        XT[4*c4+3][e] = v.w;
    }
    __syncthreads();

    const int egrp = tid % EG;
    const int cgrp = tid / EG;
    const int e0 = egrp * 4;

    float fx[4], fy[4];
#pragma unroll
    for (int j = 0; j < 4; ++j){
        int4 en = EN[e0 + j];
        fx[j] = __int_as_float(en.z);
        fy[j] = __int_as_float(en.w);
    }

    float accT[4][8];
#pragma unroll
    for (int j = 0; j < 4; ++j)
#pragma unroll
        for (int c = 0; c < 8; ++c) accT[j][c] = 0.f;

#pragma unroll
    for (int cr = 0; cr < 4; ++cr){
        float accC[4][8];
#pragma unroll
        for (int j = 0; j < 4; ++j)
#pragma unroll
            for (int c = 0; c < 8; ++c) accC[j][c] = 0.f;

#pragma unroll 4
        for (int ci = 0; ci < CIN; ++ci){
            float4 xv = *(const float4*)&XT[ci][e0];
            uint4 wp = *(const uint4*)&WL[cr][ci][cgrp * 8];
            float wf0 = __uint_as_float(wp.x << 16);
            float wf1 = __uint_as_float(wp.x & 0xFFFF0000u);
            float wf2 = __uint_as_float(wp.y << 16);
            float wf3 = __uint_as_float(wp.y & 0xFFFF0000u);
            float wf4 = __uint_as_float(wp.z << 16);
            float wf5 = __uint_as_float(wp.z & 0xFFFF0000u);
            float wf6 = __uint_as_float(wp.w << 16);
            float wf7 = __uint_as_float(wp.w & 0xFFFF0000u);
            const float xe[4] = { xv.x, xv.y, xv.z, xv.w };
#pragma unroll
            for (int j = 0; j < 4; ++j){
                accC[j][0] += xe[j] * wf0;
                accC[j][1] += xe[j] * wf1;
                accC[j][2] += xe[j] * wf2;
                accC[j][3] += xe[j] * wf3;
                accC[j][4] += xe[j] * wf4;
                accC[j][5] += xe[j] * wf5;
                accC[j][6] += xe[j] * wf6;
                accC[j][7] += xe[j] * wf7;
            }
        }
#pragma unroll
        for (int j = 0; j < 4; ++j){
            float wc = (cr == 0) ? (1.f - fx[j]) * (1.f - fy[j]) :
                       (cr == 1) ? (1.f - fx[j]) * fy[j] :
                       (cr == 2) ? fx[j] * (1.f - fy[j]) :
                                   fx[j] * fy[j];
#pragma unroll
            for (int c = 0; c < 8; ++c) accT[j][c] += wc * accC[j][c];
        }
    }

#pragma unroll
    for (int j = 0; j < 4; ++j){
        float* mp = msg + (size_t)(p0 + e0 + j) * COUT + cgrp * 8;
        *(float4*)mp       = make_float4(accT[j][0], accT[j][1], accT[j][2], accT[j][3]);
        *(float4*)(mp + 4) = make_float4(accT[j][4], accT[j][5], accT[j][6], accT[j][7]);
    }
}

// --------------------------- final conv (64->2): thread-per-edge -> msg2
__global__ __launch_bounds__(128)
void conv2_msg_k(const float* __restrict__ x,            // y2 [NFL][64]
                 const int4* __restrict__ entries,
                 const int* __restrict__ cellOff,
                 const float* __restrict__ Wc,            // [64][64][2] fp32
                 float* __restrict__ msg2)                // [slot][2]
{
    __shared__ float WL[4][64][2];
    int total = cellOff[NCC];
    int p0 = blockIdx.x * 128;
    if (p0 >= total) return;
    int tid = threadIdx.x;

    int lo = 0, hi = NCC;
    while (hi - lo > 1){ int mid = (lo + hi) >> 1; if (cellOff[mid] <= p0) lo = mid; else hi = mid; }
    const int cell = lo;
    const int kc[4] = { cell, cell + 1, cell + 8, cell + 9 };
#pragma unroll
    for (int c = 0; c < 4; ++c)
        ((float*)&WL[c][0][0])[tid] = Wc[(size_t)kc[c] * 128 + tid];
    __syncthreads();

    int4 en = entries[p0 + tid];
    if (en.y < 0) return;
    float fx = __int_as_float(en.z), fy = __int_as_float(en.w);
    const float* xp = x + (size_t)en.x * 64;

    float a[4][2] = {{0.f,0.f},{0.f,0.f},{0.f,0.f},{0.f,0.f}};
#pragma unroll 4
    for (int ci = 0; ci < 64; ci += 4){
        float4 v = *(const float4*)(xp + ci);
        float xe[4] = { frelu(v.x), frelu(v.y), frelu(v.z), frelu(v.w) };
#pragma unroll
        for (int j = 0; j < 4; ++j){
#pragma unroll
            for (int cr = 0; cr < 4; ++cr){
                a[cr][0] += xe[j] * WL[cr][ci+j][0];
                a[cr][1] += xe[j] * WL[cr][ci+j][1];
            }
        }
    }
    float w0 = (1.f-fx)*(1.f-fy), w1 = (1.f-fx)*fy, w2 = fx*(1.f-fy), w3 = fx*fy;
    float m0 = w0*a[0][0] + w1*a[1][0] + w2*a[2][0] + w3*a[3][0];
    float m1 = w0*a[0][1] + w1*a[1][1] + w2*a[2][1] + w3*a[3][1];
    *(float2*)(msg2 + (size_t)(p0 + tid) * 2) = make_float2(m0, m1);
}

// --------------------------- final combine: thread-per-target, out = .../128
__global__ __launch_bounds__(256)
void final_combine_k(const float* __restrict__ y2,
                     const float* __restrict__ Wl3, const float* __restrict__ bl3,
                     const float* __restrict__ bc4,
                     const float* __restrict__ msg2,
                     const int* __restrict__ e2s,
                     const int* __restrict__ tgt, int nE,
                     float* __restrict__ out)
{
    __shared__ float WS[128];
    int tid = threadIdx.x;
    if (tid < 128) WS[tid] = Wl3[tid];
    __syncthreads();

    int t = blockIdx.x * blockDim.x + tid;
    if (t >= NFL) return;

    int lo = 0, hi = nE;
    while (lo < hi){ int mid = (lo + hi) >> 1; if (tgt[mid] <  t) lo = mid + 1; else hi = mid; }
    int eb = lo; hi = nE;
    while (lo < hi){ int mid = (lo + hi) >> 1; if (tgt[mid] <= t) lo = mid + 1; else hi = mid; }
    int ee = lo;

    float a0 = bc4[0] + bl3[0];
    float a1 = bc4[1] + bl3[1];
    const float* pr = y2 + (size_t)t * 64;
#pragma unroll 4
    for (int ci = 0; ci < 64; ci += 4){
        float4 v = *(const float4*)(pr + ci);
        float xe[4] = { frelu(v.x), frelu(v.y), frelu(v.z), frelu(v.w) };
#pragma unroll
        for (int j = 0; j < 4; ++j){
            a0 += xe[j] * WS[(ci+j)*2];
            a1 += xe[j] * WS[(ci+j)*2 + 1];
        }
    }
    for (int e = eb; e < ee; ++e){
        int slot = e2s[e];
        float2 m = *(const float2*)(msg2 + (size_t)slot * 2);
        a0 += m.x; a1 += m.y;
    }
    out[(size_t)t*2]     = a0 * (1.0f/128.0f);
    out[(size_t)t*2 + 1] = a1 * (1.0f/128.0f);
}

// --------------------------------------------- combine: msg-sum + dns + bias
__global__ __launch_bounds__(256)
void combine0_k(const float* __restrict__ feat,
                const float* __restrict__ Wl0, const float* __restrict__ bl0,
                const float* __restrict__ bc0,
                const float* __restrict__ msg,           // [slot][32]
                const int* __restrict__ e2s,
                const int* __restrict__ tgt, int nE,
                float* __restrict__ ansA)
{
    int t = blockIdx.x * (blockDim.x >> 6) + (threadIdx.x >> 6);
    if (t >= NFL) return;
    int lane = threadIdx.x & 63;

    int lo = 0, hi = nE;
    while (lo < hi){ int mid = (lo + hi) >> 1; if (tgt[mid] <  t) lo = mid + 1; else hi = mid; }
    int eb = lo; hi = nE;
    while (lo < hi){ int mid = (lo + hi) >> 1; if (tgt[mid] <= t) lo = mid + 1; else hi = mid; }
    int ee = lo;

    if (lane < 32){
        float a = bl0[lane];
#pragma unroll
        for (int ci = 0; ci < 8; ++ci)
            a += feat[t*8 + ci] * Wl0[ci*32 + lane];
        ansA[(size_t)t*96 + lane] = a;
    } else {
        int c = lane - 32;
        float a = bc0[c];
        for (int e = eb; e < ee; ++e){
            int slot = e2s[e];
            a += msg[(size_t)slot*32 + c];
        }
        ansA[(size_t)t*96 + 32 + c] = a;
    }
}

template<int CIN, bool RESID>
__global__ __launch_bounds__(256)
void combine12_k(const float* __restrict__ prev,
                 const float* __restrict__ Wl, const float* __restrict__ bl,
                 const float* __restrict__ bc,
                 const float* __restrict__ msg,          // [slot][64]
                 const int* __restrict__ e2s,
                 const int* __restrict__ tgt, int nE,
                 float* __restrict__ y)
{
    int t = blockIdx.x * (blockDim.x >> 6) + (threadIdx.x >> 6);
    if (t >= NFL) return;
    int lane = threadIdx.x & 63;

    int lo = 0, hi = nE;
    while (lo < hi){ int mid = (lo + hi) >> 1; if (tgt[mid] <  t) lo = mid + 1; else hi = mid; }
    int eb = lo; hi = nE;
    while (lo < hi){ int mid = (lo + hi) >> 1; if (tgt[mid] <= t) lo = mid + 1; else hi = mid; }
    int ee = lo;

    const float* pr = prev + (size_t)t * CIN;
    float acc = bc[lane] + bl[lane];
#pragma unroll 8
    for (int ci = 0; ci < CIN; ++ci)
        acc += frelu(pr[ci]) * Wl[ci*64 + lane];
    if (RESID) acc += pr[lane];

    for (int e = eb; e < ee; ++e){
        int slot = e2s[e];
        acc += msg[(size_t)slot*64 + lane];
    }
    y[(size_t)t*64 + lane] = acc;
}

// ----------------------------------------- per-target conv (bconv only now)
template<int CIN, int COUT>
__global__ __launch_bounds__(256)
void conv_tgt_k(const float* __restrict__ xsrc,
                const EdgeData* __restrict__ ed,
                const int* __restrict__ tgt, int nE,
                const float* __restrict__ Wc, const float* __restrict__ bc,
                float* __restrict__ out, int out_stride, int out_off)
{
    int t = blockIdx.x * (blockDim.x >> 6) + (threadIdx.x >> 6);
    if (t >= NFL) return;
    int lane = threadIdx.x & 63;
    int cl = lane < COUT ? lane : 0;

    int lo = 0, hi = nE;
    while (lo < hi){ int mid = (lo + hi) >> 1; if (tgt[mid] <  t) lo = mid + 1; else hi = mid; }
    int eb = lo; hi = nE;
    while (lo < hi){ int mid = (lo + hi) >> 1; if (tgt[mid] <= t) lo = mid + 1; else hi = mid; }
    int ee = lo;

    float acc = 0.f;
    for (int e = eb; e < ee; ++e){
        EdgeData d = ed[e];
        int s  = __builtin_amdgcn_readfirstlane(d.src);
        int kk = __builtin_amdgcn_readfirstlane(d.ixiy);
        const float* xp = xsrc + (size_t)s * CIN;
        const float* wp = Wc + (size_t)kk * (CIN*COUT) + cl;
        float t00 = 0.f, t01 = 0.f, t10 = 0.f, t11 = 0.f;
#pragma unroll 8
        for (int ci = 0; ci < CIN; ++ci){
            float xv = xp[ci];
            t00 += xv * wp[ci*COUT];
            t01 += xv * wp[ci*COUT +   CIN*COUT];
            t10 += xv * wp[ci*COUT + 8*CIN*COUT];
            t11 += xv * wp[ci*COUT + 9*CIN*COUT];
        }
        float wx1 = d.fx, wy1 = d.fy;
        float wx0 = 1.f - wx1, wy0 = 1.f - wy1;
        acc += (wx0*wy0)*t00 + (wx0*wy1)*t01 + (wx1*wy0)*t10 + (wx1*wy1)*t11;
    }
    acc += bc[cl];
    if (lane < COUT)
        out[(size_t)t*out_stride + out_off + lane] = acc;
}

// ---------------------------------------------------------------------------
extern "C" void kernel_launch(void* const* d_in, const int* in_sizes, int n_in,
                              void* d_out, int out_size, void* d_ws, size_t ws_size,
                              hipStream_t stream)
{
    const float* fluid_pos  = (const float*)d_in[0];
    const float* bnd_pos    = (const float*)d_in[1];
    const float* fluid_feat = (const float*)d_in[2];
    const float* bnd_feat   = (const float*)d_in[3];
    const int*   f_tgt      = (const int*)  d_in[4];
    const int*   f_src      = (const int*)  d_in[5];
    const int*   b_tgt      = (const int*)  d_in[6];
    const int*   b_src      = (const int*)  d_in[7];
    const float* Wc0 = (const float*)d_in[8];  const float* bc0 = (const float*)d_in[9];
    const float* Wc1 = (const float*)d_in[10]; const float* bc1 = (const float*)d_in[11];
    const float* Wc2 = (const float*)d_in[12]; const float* bc2 = (const float*)d_in[13];
    const float* Wc3 = (const float*)d_in[14]; const float* bc3 = (const float*)d_in[15];
    const float* Wc4 = (const float*)d_in[16]; const float* bc4 = (const float*)d_in[17];
    const float* Wl0 = (const float*)d_in[18]; const float* bl0 = (const float*)d_in[19];
    const float* Wl1 = (const float*)d_in[20]; const float* bl1 = (const float*)d_in[21];
    const float* Wl2 = (const float*)d_in[22]; const float* bl2 = (const float*)d_in[23];
    const float* Wl3 = (const float*)d_in[24]; const float* bl3 = (const float*)d_in[25];

    int nEf = in_sizes[4];
    int nEb = in_sizes[6];
    int entPadMax = nEf + NCC * PADQ;
    float support = (float)sqrt(16.0 / (M_PI * 16384.0));

    char* w = (char*)d_ws;
    auto alloc = [&](size_t bytes){ char* r = w; w += (bytes + 255) & ~(size_t)255; return r; };
    EdgeData* edF      = (EdgeData*)alloc((size_t)nEf * sizeof(EdgeData));
    EdgeData* edB      = (EdgeData*)alloc((size_t)nEb * sizeof(EdgeData));
    int*      cnt      = (int*)     alloc(64 * sizeof(int));
    int*      cellOff  = (int*)     alloc(64 * sizeof(int));
    int*      gcursor  = (int*)     alloc(64 * sizeof(int));
    int4*     entries  = (int4*)    alloc((size_t)entPadMax * sizeof(int4));
    int*      e2s      = (int*)     alloc((size_t)nEf * sizeof(int));
    unsigned short* wb0 = (unsigned short*)alloc((size_t)64*8*32  * 2);
    unsigned short* wb2 = (unsigned short*)alloc((size_t)64*96*64 * 2);
    unsigned short* wb3 = (unsigned short*)alloc((size_t)64*64*64 * 2);
    float*    ansA     = (float*)   alloc((size_t)NFL * 96 * sizeof(float));
    float*    y1       = (float*)   alloc((size_t)NFL * 64 * sizeof(float));
    float*    y2       = (float*)   alloc((size_t)NFL * 64 * sizeof(float));
    float*    msg      = (float*)   alloc((size_t)entPadMax * 64 * sizeof(float));
    float*    msg2     = msg;   // reused after combine12<64> finishes

    // ---- edge prep + bucket build (reused by conv0/conv2/conv3/conv4)
    prep_edges_k<<<(nEf+255)/256, 256, 0, stream>>>(fluid_pos, fluid_pos, f_tgt, f_src, nEf, support, -1.f, edF);
    prep_edges_k<<<(nEb+255)/256, 256, 0, stream>>>(fluid_pos, bnd_pos,   b_tgt, b_src, nEb, support,  1.f, edB);
    zero64_k<<<1, 64, 0, stream>>>(cnt);
    hist_k<<<(nEf+255)/256, 256, 0, stream>>>(edF, nEf, cnt);
    scan_pad_k<<<1, 64, 0, stream>>>(cnt, cellOff, gcursor);
    fill_entries_k<<<(entPadMax+255)/256, 256, 0, stream>>>(entries, entPadMax);
    scatter_k<<<(nEf+255)/256, 256, 0, stream>>>(edF, nEf, cellOff, gcursor, entries, e2s);

    // ---- W -> bf16
    wcvt_k<<<(64*8*32 +255)/256, 256, 0, stream>>>(Wc0, wb0, 64*8*32);
    wcvt_k<<<(64*96*64+255)/256, 256, 0, stream>>>(Wc2, wb2, 64*96*64);
    wcvt_k<<<(64*64*64+255)/256, 256, 0, stream>>>(Wc3, wb3, 64*64*64);

    int grid64  = (entPadMax + 63)  / 64;
    int grid128 = (entPadMax + 127) / 128;
    dim3 tgrid(NFL/4);

    // ---- input block
    conv_cell_k<8,32,128,false><<<grid128, 128, 0, stream>>>(fluid_feat, entries, cellOff, wb0, msg);
    conv_tgt_k<8,32><<<tgrid, 256, 0, stream>>>(bnd_feat, edB, b_tgt, nEb, Wc1, bc1, ansA, 96, 64);
    combine0_k<<<tgrid, 256, 0, stream>>>(fluid_feat, Wl0, bl0, bc0, msg, e2s, f_tgt, nEf, ansA);

    // ---- block 1: y1 = conv(relu(ansA),Wc2)+bc2 + relu(ansA)@Wl1+bl1
    conv_cell_k<96,64,64,true><<<grid64, 128, 0, stream>>>(ansA, entries, cellOff, wb2, msg);
    combine12_k<96,false><<<tgrid, 256, 0, stream>>>(ansA, Wl1, bl1, bc2, msg, e2s, f_tgt, nEf, y1);

    // ---- block 2: y2 = conv(relu(y1),Wc3)+bc3 + relu(y1)@Wl2+bl2 + y1
    conv_cell_k<64,64,64,true><<<grid64, 128, 0, stream>>>(y1, entries, cellOff, wb3, msg);
    combine12_k<64,true><<<tgrid, 256, 0, stream>>>(y1, Wl2, bl2, bc3, msg, e2s, f_tgt, nEf, y2);

    // ---- block 3 (final): thread-per-edge conv + fused combine
    conv2_msg_k<<<grid128, 128, 0, stream>>>(y2, entries, cellOff, Wc4, msg2);
    final_combine_k<<<(NFL+255)/256, 256, 0, stream>>>(y2, Wl3, bl3, bc4, msg2, e2s, f_tgt, nEf, (float*)d_out);
}

// Round 5
// 467.188 us; speedup vs baseline: 12.6499x; 1.6970x over previous
//
#include <hip/hip_runtime.h>
#include <math.h>
#include <stdint.h>

#define NFL   16384
#define NCC   55      // base cells: ix,iy in 0..6 -> ixiy = ix*8+iy in 0..54
#define PADQ  128     // bucket pad quantum (multiple of all tile sizes)

struct EdgeData { int src; int ixiy; float fx; float fy; };

typedef __attribute__((ext_vector_type(8))) short short8v;   // 8 bf16
typedef __attribute__((ext_vector_type(4))) float f32x4;

__device__ __forceinline__ float frelu(float x){ return x > 0.f ? x : 0.f; }
__device__ __forceinline__ unsigned short f2bf(float f){
    unsigned int u = __float_as_uint(f);
    unsigned int r = (u + 0x7FFFu + ((u >> 16) & 1u)) >> 16;   // RNE
    return (unsigned short)r;
}

// ---------------------------------------------------------------- prep edges
__global__ void prep_edges_k(const float* __restrict__ qpos,
                             const float* __restrict__ ppos,
                             const int* __restrict__ tgt,
                             const int* __restrict__ src,
                             int nE, float support, float sgn,
                             EdgeData* __restrict__ out)
{
    int e = blockIdx.x * blockDim.x + threadIdx.x;
    if (e >= nE) return;
    int t = tgt[e], s = src[e];
    float dx = sgn * (ppos[2*s]   - qpos[2*t])   / support;
    float dy = sgn * (ppos[2*s+1] - qpos[2*t+1]) / support;
    dx = fminf(1.f, fmaxf(-1.f, dx));
    dy = fminf(1.f, fmaxf(-1.f, dy));
    float r  = sqrtf(dx*dx + dy*dy + 1e-12f);
    float th = atan2f(dy, dx);
    float m0 = fminf(1.f, fmaxf(-1.f, 2.f*r - 1.f));
    float m1 = fminf(1.f, fmaxf(-1.f, th * 0.3183098861837907f));
    float u = (m0 + 1.f) * 3.5f;
    float v = (m1 + 1.f) * 3.5f;
    int ix = (int)u; if (ix > 6) ix = 6;
    int iy = (int)v; if (iy > 6) iy = 6;
    EdgeData ed;
    ed.src  = s;
    ed.ixiy = ix*8 + iy;
    ed.fx   = u - (float)ix;
    ed.fy   = v - (float)iy;
    out[e] = ed;
}

// ------------------------------------------------------------- bucket build
__global__ void zero64_k(int* __restrict__ a){ if (threadIdx.x < 64) a[threadIdx.x] = 0; }

__global__ void hist_k(const EdgeData* __restrict__ ed, int nE, int* __restrict__ cnt)
{
    __shared__ int lc[64];
    int tid = threadIdx.x;
    if (tid < 64) lc[tid] = 0;
    __syncthreads();
    int e = blockIdx.x * blockDim.x + tid;
    if (e < nE) atomicAdd(&lc[ed[e].ixiy], 1);
    __syncthreads();
    if (tid < 64 && lc[tid] > 0) atomicAdd(&cnt[tid], lc[tid]);
}

__global__ void scan_pad_k(const int* __restrict__ cnt, int* __restrict__ cellOff,
                           int* __restrict__ gcursor)
{
    if (threadIdx.x < 64) gcursor[threadIdx.x] = 0;
    if (threadIdx.x == 0){
        int s = 0;
        for (int k = 0; k < NCC; ++k){
            cellOff[k] = s;
            s += ((cnt[k] + PADQ - 1) / PADQ) * PADQ;
        }
        cellOff[NCC] = s;
    }
}

__global__ void fill_entries_k(int4* __restrict__ entries, int n)
{
    int i = blockIdx.x * blockDim.x + threadIdx.x;
    if (i < n) entries[i] = make_int4(0, -1, 0, 0);
}

__global__ void scatter_k(const EdgeData* __restrict__ ed, int nE,
                          const int* __restrict__ cellOff,
                          int* __restrict__ gcursor,
                          int4* __restrict__ entries,
                          int* __restrict__ e2s)
{
    __shared__ int lc[64], base[64];
    int tid = threadIdx.x;
    if (tid < 64) lc[tid] = 0;
    __syncthreads();
    int e = blockIdx.x * blockDim.x + tid;
    bool ok = e < nE;
    EdgeData d; int k = 0, r = 0;
    if (ok){ d = ed[e]; k = d.ixiy; r = atomicAdd(&lc[k], 1); }
    __syncthreads();
    if (tid < 64 && lc[tid] > 0) base[tid] = atomicAdd(&gcursor[tid], lc[tid]);
    __syncthreads();
    if (ok){
        int slot = cellOff[k] + base[k] + r;
        entries[slot] = make_int4(d.src, e, __float_as_int(d.fx), __float_as_int(d.fy));
        e2s[e] = slot;
    }
}

// ------------------------------------------------------------ W fp32 -> bf16
__global__ void wcvt_k(const float* __restrict__ in, unsigned short* __restrict__ out, int n)
{
    int i = blockIdx.x * blockDim.x + threadIdx.x;
    if (i < n) out[i] = f2bf(in[i]);
}

// W [64][CIN][COUT] fp32 -> wt [64][COUT][CIN] bf16, one block per cell
template<int CIN>
__global__ __launch_bounds__(256)
void wtr_k(const float* __restrict__ Wsrc, unsigned short* __restrict__ wt)
{
    constexpr int COUT = 64;
    __shared__ unsigned short T[COUT][CIN + 2];
    int cell = blockIdx.x;
    const float* s = Wsrc + (size_t)cell * CIN * COUT;
    for (int i = threadIdx.x; i < CIN*COUT; i += 256){
        int k = i / COUT, c = i - k*COUT;
        T[c][k] = f2bf(s[i]);
    }
    __syncthreads();
    unsigned short* d = wt + (size_t)cell * COUT * CIN;
    for (int i = threadIdx.x; i < CIN*COUT; i += 256){
        int c = i / CIN, k = i - c*CIN;
        d[i] = T[c][k];
    }
}

// --------------------- x fp32 -> bf16 hi|lo rows: xb[n][0:CIN]=hi, [CIN:2CIN]=lo
template<int CIN, bool RELU>
__global__ void xcvt_k(const float* __restrict__ x, unsigned short* __restrict__ xb)
{
    constexpr int C8 = CIN / 8;
    int i = blockIdx.x * blockDim.x + threadIdx.x;
    if (i >= NFL * C8) return;
    int n = i / C8, c = (i - n*C8) * 8;
    const float* xp = x + (size_t)n*CIN + c;
    float4 v0 = *(const float4*)xp;
    float4 v1 = *(const float4*)(xp + 4);
    float f[8] = { v0.x, v0.y, v0.z, v0.w, v1.x, v1.y, v1.z, v1.w };
    unsigned int hw[4], lw[4];
#pragma unroll
    for (int j = 0; j < 4; ++j){
        float a = RELU ? frelu(f[2*j])   : f[2*j];
        float b = RELU ? frelu(f[2*j+1]) : f[2*j+1];
        unsigned int ua = __float_as_uint(a), ub = __float_as_uint(b);
        hw[j] = (ua >> 16) | (ub & 0xFFFF0000u);               // trunc hi
        float la = a - __uint_as_float(ua & 0xFFFF0000u);
        float lb = b - __uint_as_float(ub & 0xFFFF0000u);
        lw[j] = (__float_as_uint(la) >> 16) | (__float_as_uint(lb) & 0xFFFF0000u);
    }
    unsigned short* out = xb + (size_t)n * (2*CIN);
    *(uint4*)(out + c)        = make_uint4(hw[0], hw[1], hw[2], hw[3]);
    *(uint4*)(out + CIN + c)  = make_uint4(lw[0], lw[1], lw[2], lw[3]);
}

// -------------------------------------------- MFMA cell-conv: 64 edges/block
// A = gathered xb rows (hi|lo bf16), B = wt[cell_cr] (cout-major bf16).
// 4 waves: wave w owns couts [16w,16w+16); acc[corner][edge-group] 16x16 tiles.
// C layout (m89-verified): col=lane&15, row=(lane>>4)*4+reg.
template<int CIN>
__global__ __launch_bounds__(256)
void conv_mfma_k(const unsigned short* __restrict__ xb,   // [NFL][2*CIN]
                 const int4* __restrict__ entries,
                 const int* __restrict__ cellOff,
                 const unsigned short* __restrict__ wt,   // [64][64][CIN]
                 float* __restrict__ msg)                 // [slot][64]
{
    constexpr int COUT = 64;
    constexpr int K2   = 2 * CIN;
    constexpr int XROW = K2*2 + 16;        // bytes: 400 (96) / 272 (64) -> odd*16
    constexpr int WROW = CIN*2 + 16;       // bytes: 208 / 144           -> odd*16
    constexpr int C16  = K2*2/16;          // 16B chunks per x row: 24 / 16
    constexpr int W16  = CIN*2/16;         // chunks per w row: 12 / 8

    __shared__ unsigned char XL[64 * XROW];
    __shared__ unsigned char WL[4 * COUT * WROW];
    __shared__ float BW[4][64];
    __shared__ int   SRC[64];

    int total = cellOff[NCC];
    int p0 = blockIdx.x * 64;
    if (p0 >= total) return;
    int tid = threadIdx.x;

    int lo_ = 0, hi_ = NCC;
    while (hi_ - lo_ > 1){ int mid = (lo_ + hi_) >> 1; if (cellOff[mid] <= p0) lo_ = mid; else hi_ = mid; }
    const int cell = lo_;
    const int kc[4] = { cell, cell+1, cell+8, cell+9 };

    // bilinear weights + src gather list
    if (tid < 64){
        int4 en = entries[p0 + tid];
        bool ok = en.y >= 0;
        float fx = __int_as_float(en.z), fy = __int_as_float(en.w);
        BW[0][tid] = ok ? (1.f-fx)*(1.f-fy) : 0.f;
        BW[1][tid] = ok ? (1.f-fx)*fy       : 0.f;
        BW[2][tid] = ok ? fx*(1.f-fy)       : 0.f;
        BW[3][tid] = ok ? fx*fy             : 0.f;
        SRC[tid] = en.x;
    }
    // stage W (4 corners, padded rows)
    for (int i = tid; i < 4*COUT*W16; i += 256){
        int cr  = i / (COUT*W16);
        int rem = i - cr*(COUT*W16);
        int r   = rem / W16;
        int c   = rem - r*W16;
        const uint4* sp = (const uint4*)(wt + ((size_t)kc[cr]*COUT + r)*CIN) + c;
        *(uint4*)(&WL[cr*(COUT*WROW) + r*WROW + 16*c]) = *sp;
    }
    __syncthreads();
    // stage X rows (copy hi|lo bf16 rows, padded stride)
    for (int i = tid; i < 64*C16; i += 256){
        int e = i / C16, c = i - e*C16;
        const uint4* sp = (const uint4*)(xb + (size_t)SRC[e]*K2) + c;
        *(uint4*)(&XL[e*XROW + 16*c]) = *sp;
    }
    __syncthreads();

    const int lane = tid & 63, wv = tid >> 6;
    const int lr = lane & 15, lg = lane >> 4;
    const int cb = wv * 16;

    f32x4 acc[4][4];   // [corner][edge-group]
#pragma unroll
    for (int cr = 0; cr < 4; ++cr)
#pragma unroll
        for (int ae = 0; ae < 4; ++ae)
            acc[cr][ae] = (f32x4)0.f;

#pragma unroll
    for (int k0 = 0; k0 < CIN; k0 += 32){
        short8v b[4], ah[4], al[4];
#pragma unroll
        for (int cr = 0; cr < 4; ++cr)
            b[cr] = *(const short8v*)(WL + cr*(COUT*WROW) + (cb+lr)*WROW + k0*2 + lg*16);
#pragma unroll
        for (int ae = 0; ae < 4; ++ae){
            const unsigned char* rp = XL + (16*ae + lr)*XROW + k0*2 + lg*16;
            ah[ae] = *(const short8v*)rp;
            al[ae] = *(const short8v*)(rp + CIN*2);
        }
#pragma unroll
        for (int cr = 0; cr < 4; ++cr)
#pragma unroll
            for (int ae = 0; ae < 4; ++ae){
                acc[cr][ae] = __builtin_amdgcn_mfma_f32_16x16x32_bf16(ah[ae], b[cr], acc[cr][ae], 0, 0, 0);
                acc[cr][ae] = __builtin_amdgcn_mfma_f32_16x16x32_bf16(al[ae], b[cr], acc[cr][ae], 0, 0, 0);
            }
    }

    // bilinear combine + store
#pragma unroll
    for (int ae = 0; ae < 4; ++ae){
#pragma unroll
        for (int r = 0; r < 4; ++r){
            int E = 16*ae + lg*4 + r;
            float v = BW[0][E]*acc[0][ae][r] + BW[1][E]*acc[1][ae][r]
                    + BW[2][E]*acc[2][ae][r] + BW[3][E]*acc[3][ae][r];
            msg[(size_t)(p0 + E)*COUT + cb + lr] = v;
        }
    }
}

// -------------------------- fp32 cell-conv (kept for conv0: CIN=8, COUT=32)
template<int CIN, int COUT, int TILE_E, bool RELU>
__global__ __launch_bounds__(128)
void conv_cell_k(const float* __restrict__ x,
                 const int4* __restrict__ entries,
                 const int* __restrict__ cellOff,
                 const unsigned short* __restrict__ Wbf,
                 float* __restrict__ msg)
{
    constexpr int TEP = TILE_E + 4;
    constexpr int EG  = TILE_E / 4;
    constexpr int CG  = COUT / 8;
    static_assert(EG * CG == 128, "tile/thread mismatch");
    constexpr int C4  = CIN / 4;

    __shared__ float XT[CIN][TEP];
    __shared__ unsigned short WLc[4][CIN][COUT];
    __shared__ int4 EN[TILE_E];

    int total = cellOff[NCC];
    int p0 = blockIdx.x * TILE_E;
    if (p0 >= total) return;
    int tid = threadIdx.x;

    int lo = 0, hi = NCC;
    while (hi - lo > 1){ int mid = (lo + hi) >> 1; if (cellOff[mid] <= p0) lo = mid; else hi = mid; }
    const int cell = lo;

    for (int i = tid; i < TILE_E; i += 128) EN[i] = entries[p0 + i];

    const int kc[4] = { cell, cell + 1, cell + 8, cell + 9 };
#pragma unroll
    for (int c = 0; c < 4; ++c){
        const uint4* s = (const uint4*)(Wbf + (size_t)kc[c] * (CIN * COUT));
        uint4* dlds = (uint4*)(&WLc[c][0][0]);
        for (int i = tid; i < CIN * COUT / 8; i += 128) dlds[i] = s[i];
    }
    __syncthreads();

    for (int i = tid; i < TILE_E * C4; i += 128){
        int e  = i / C4;
        int c4 = i - e * C4;
        int4 en = EN[e];
        float4 v = make_float4(0.f, 0.f, 0.f, 0.f);
        if (en.y >= 0){
            v = *(const float4*)(x + (size_t)en.x * CIN + 4 * c4);
            if (RELU){ v.x = frelu(v.x); v.y = frelu(v.y); v.z = frelu(v.z); v.w = frelu(v.w); }
        }
        XT[4*c4+0][e] = v.x;
        XT[4*c4+1][e] = v.y;
        XT[4*c4+2][e] = v.z;
        XT[4*c4+3][e] = v.w;
    }
    __syncthreads();

    const int egrp = tid % EG;
    const int cgrp = tid / EG;
    const int e0 = egrp * 4;

    float fx[4], fy[4];
#pragma unroll
    for (int j = 0; j < 4; ++j){
        int4 en = EN[e0 + j];
        fx[j] = __int_as_float(en.z);
        fy[j] = __int_as_float(en.w);
    }

    float accT[4][8];
#pragma unroll
    for (int j = 0; j < 4; ++j)
#pragma unroll
        for (int c = 0; c < 8; ++c) accT[j][c] = 0.f;

#pragma unroll
    for (int cr = 0; cr < 4; ++cr){
        float accC[4][8];
#pragma unroll
        for (int j = 0; j < 4; ++j)
#pragma unroll
            for (int c = 0; c < 8; ++c) accC[j][c] = 0.f;

#pragma unroll
        for (int ci = 0; ci < CIN; ++ci){
            float4 xv = *(const float4*)&XT[ci][e0];
            uint4 wp = *(const uint4*)&WLc[cr][ci][cgrp * 8];
            float wf0 = __uint_as_float(wp.x << 16);
            float wf1 = __uint_as_float(wp.x & 0xFFFF0000u);
            float wf2 = __uint_as_float(wp.y << 16);
            float wf3 = __uint_as_float(wp.y & 0xFFFF0000u);
            float wf4 = __uint_as_float(wp.z << 16);
            float wf5 = __uint_as_float(wp.z & 0xFFFF0000u);
            float wf6 = __uint_as_float(wp.w << 16);
            float wf7 = __uint_as_float(wp.w & 0xFFFF0000u);
            const float xe[4] = { xv.x, xv.y, xv.z, xv.w };
#pragma unroll
            for (int j = 0; j < 4; ++j){
                accC[j][0] += xe[j] * wf0;
                accC[j][1] += xe[j] * wf1;
                accC[j][2] += xe[j] * wf2;
                accC[j][3] += xe[j] * wf3;
                accC[j][4] += xe[j] * wf4;
                accC[j][5] += xe[j] * wf5;
                accC[j][6] += xe[j] * wf6;
                accC[j][7] += xe[j] * wf7;
            }
        }
#pragma unroll
        for (int j = 0; j < 4; ++j){
            float wc = (cr == 0) ? (1.f - fx[j]) * (1.f - fy[j]) :
                       (cr == 1) ? (1.f - fx[j]) * fy[j] :
                       (cr == 2) ? fx[j] * (1.f - fy[j]) :
                                   fx[j] * fy[j];
#pragma unroll
            for (int c = 0; c < 8; ++c) accT[j][c] += wc * accC[j][c];
        }
    }

#pragma unroll
    for (int j = 0; j < 4; ++j){
        float* mp = msg + (size_t)(p0 + e0 + j) * COUT + cgrp * 8;
        *(float4*)mp       = make_float4(accT[j][0], accT[j][1], accT[j][2], accT[j][3]);
        *(float4*)(mp + 4) = make_float4(accT[j][4], accT[j][5], accT[j][6], accT[j][7]);
    }
}

// --------------------------- final conv (64->2): thread-per-edge -> msg2
__global__ __launch_bounds__(128)
void conv2_msg_k(const float* __restrict__ x,
                 const int4* __restrict__ entries,
                 const int* __restrict__ cellOff,
                 const float* __restrict__ Wc,
                 float* __restrict__ msg2)
{
    __shared__ float WLf[4][64][2];
    int total = cellOff[NCC];
    int p0 = blockIdx.x * 128;
    if (p0 >= total) return;
    int tid = threadIdx.x;

    int lo = 0, hi = NCC;
    while (hi - lo > 1){ int mid = (lo + hi) >> 1; if (cellOff[mid] <= p0) lo = mid; else hi = mid; }
    const int cell = lo;
    const int kc[4] = { cell, cell + 1, cell + 8, cell + 9 };
#pragma unroll
    for (int c = 0; c < 4; ++c)
        ((float*)&WLf[c][0][0])[tid] = Wc[(size_t)kc[c] * 128 + tid];
    __syncthreads();

    int4 en = entries[p0 + tid];
    if (en.y < 0) return;
    float fx = __int_as_float(en.z), fy = __int_as_float(en.w);
    const float* xp = x + (size_t)en.x * 64;

    float a[4][2] = {{0.f,0.f},{0.f,0.f},{0.f,0.f},{0.f,0.f}};
#pragma unroll 4
    for (int ci = 0; ci < 64; ci += 4){
        float4 v = *(const float4*)(xp + ci);
        float xe[4] = { frelu(v.x), frelu(v.y), frelu(v.z), frelu(v.w) };
#pragma unroll
        for (int j = 0; j < 4; ++j){
#pragma unroll
            for (int cr = 0; cr < 4; ++cr){
                a[cr][0] += xe[j] * WLf[cr][ci+j][0];
                a[cr][1] += xe[j] * WLf[cr][ci+j][1];
            }
        }
    }
    float w0 = (1.f-fx)*(1.f-fy), w1 = (1.f-fx)*fy, w2 = fx*(1.f-fy), w3 = fx*fy;
    float m0 = w0*a[0][0] + w1*a[1][0] + w2*a[2][0] + w3*a[3][0];
    float m1 = w0*a[0][1] + w1*a[1][1] + w2*a[2][1] + w3*a[3][1];
    *(float2*)(msg2 + (size_t)(p0 + tid) * 2) = make_float2(m0, m1);
}

// --------------------------- final combine: thread-per-target, out = .../128
__global__ __launch_bounds__(256)
void final_combine_k(const float* __restrict__ y2,
                     const float* __restrict__ Wl3, const float* __restrict__ bl3,
                     const float* __restrict__ bc4,
                     const float* __restrict__ msg2,
                     const int* __restrict__ e2s,
                     const int* __restrict__ tgt, int nE,
                     float* __restrict__ out)
{
    __shared__ float WS[128];
    int tid = threadIdx.x;
    if (tid < 128) WS[tid] = Wl3[tid];
    __syncthreads();

    int t = blockIdx.x * blockDim.x + tid;
    if (t >= NFL) return;

    int lo = 0, hi = nE;
    while (lo < hi){ int mid = (lo + hi) >> 1; if (tgt[mid] <  t) lo = mid + 1; else hi = mid; }
    int eb = lo; hi = nE;
    while (lo < hi){ int mid = (lo + hi) >> 1; if (tgt[mid] <= t) lo = mid + 1; else hi = mid; }
    int ee = lo;

    float a0 = bc4[0] + bl3[0];
    float a1 = bc4[1] + bl3[1];
    const float* pr = y2 + (size_t)t * 64;
#pragma unroll 4
    for (int ci = 0; ci < 64; ci += 4){
        float4 v = *(const float4*)(pr + ci);
        float xe[4] = { frelu(v.x), frelu(v.y), frelu(v.z), frelu(v.w) };
#pragma unroll
        for (int j = 0; j < 4; ++j){
            a0 += xe[j] * WS[(ci+j)*2];
            a1 += xe[j] * WS[(ci+j)*2 + 1];
        }
    }
    for (int e = eb; e < ee; ++e){
        int slot = e2s[e];
        float2 m = *(const float2*)(msg2 + (size_t)slot * 2);
        a0 += m.x; a1 += m.y;
    }
    out[(size_t)t*2]     = a0 * (1.0f/128.0f);
    out[(size_t)t*2 + 1] = a1 * (1.0f/128.0f);
}

// --------------------------------------------- combine: msg-sum + dns + bias
__global__ __launch_bounds__(256)
void combine0_k(const float* __restrict__ feat,
                const float* __restrict__ Wl0, const float* __restrict__ bl0,
                const float* __restrict__ bc0,
                const float* __restrict__ msg,           // [slot][32]
                const int* __restrict__ e2s,
                const int* __restrict__ tgt, int nE,
                float* __restrict__ ansA)
{
    int t = blockIdx.x * (blockDim.x >> 6) + (threadIdx.x >> 6);
    if (t >= NFL) return;
    int lane = threadIdx.x & 63;

    int lo = 0, hi = nE;
    while (lo < hi){ int mid = (lo + hi) >> 1; if (tgt[mid] <  t) lo = mid + 1; else hi = mid; }
    int eb = lo; hi = nE;
    while (lo < hi){ int mid = (lo + hi) >> 1; if (tgt[mid] <= t) lo = mid + 1; else hi = mid; }
    int ee = lo;

    if (lane < 32){
        float a = bl0[lane];
#pragma unroll
        for (int ci = 0; ci < 8; ++ci)
            a += feat[t*8 + ci] * Wl0[ci*32 + lane];
        ansA[(size_t)t*96 + lane] = a;
    } else {
        int c = lane - 32;
        float a = bc0[c];
        for (int e = eb; e < ee; ++e){
            int slot = e2s[e];
            a += msg[(size_t)slot*32 + c];
        }
        ansA[(size_t)t*96 + 32 + c] = a;
    }
}

template<int CIN, bool RESID>
__global__ __launch_bounds__(256)
void combine12_k(const float* __restrict__ prev,
                 const float* __restrict__ Wl, const float* __restrict__ bl,
                 const float* __restrict__ bc,
                 const float* __restrict__ msg,          // [slot][64]
                 const int* __restrict__ e2s,
                 const int* __restrict__ tgt, int nE,
                 float* __restrict__ y)
{
    int t = blockIdx.x * (blockDim.x >> 6) + (threadIdx.x >> 6);
    if (t >= NFL) return;
    int lane = threadIdx.x & 63;

    int lo = 0, hi = nE;
    while (lo < hi){ int mid = (lo + hi) >> 1; if (tgt[mid] <  t) lo = mid + 1; else hi = mid; }
    int eb = lo; hi = nE;
    while (lo < hi){ int mid = (lo + hi) >> 1; if (tgt[mid] <= t) lo = mid + 1; else hi = mid; }
    int ee = lo;

    const float* pr = prev + (size_t)t * CIN;
    float acc = bc[lane] + bl[lane];
#pragma unroll 8
    for (int ci = 0; ci < CIN; ++ci)
        acc += frelu(pr[ci]) * Wl[ci*64 + lane];
    if (RESID) acc += pr[lane];

    for (int e = eb; e < ee; ++e){
        int slot = e2s[e];
        acc += msg[(size_t)slot*64 + lane];
    }
    y[(size_t)t*64 + lane] = acc;
}

// ----------------------------------------- per-target conv (bconv only)
template<int CIN, int COUT>
__global__ __launch_bounds__(256)
void conv_tgt_k(const float* __restrict__ xsrc,
                const EdgeData* __restrict__ ed,
                const int* __restrict__ tgt, int nE,
                const float* __restrict__ Wc, const float* __restrict__ bc,
                float* __restrict__ out, int out_stride, int out_off)
{
    int t = blockIdx.x * (blockDim.x >> 6) + (threadIdx.x >> 6);
    if (t >= NFL) return;
    int lane = threadIdx.x & 63;
    int cl = lane < COUT ? lane : 0;

    int lo = 0, hi = nE;
    while (lo < hi){ int mid = (lo + hi) >> 1; if (tgt[mid] <  t) lo = mid + 1; else hi = mid; }
    int eb = lo; hi = nE;
    while (lo < hi){ int mid = (lo + hi) >> 1; if (tgt[mid] <= t) lo = mid + 1; else hi = mid; }
    int ee = lo;

    float acc = 0.f;
    for (int e = eb; e < ee; ++e){
        EdgeData d = ed[e];
        int s  = __builtin_amdgcn_readfirstlane(d.src);
        int kk = __builtin_amdgcn_readfirstlane(d.ixiy);
        const float* xp = xsrc + (size_t)s * CIN;
        const float* wp = Wc + (size_t)kk * (CIN*COUT) + cl;
        float t00 = 0.f, t01 = 0.f, t10 = 0.f, t11 = 0.f;
#pragma unroll 8
        for (int ci = 0; ci < CIN; ++ci){
            float xv = xp[ci];
            t00 += xv * wp[ci*COUT];
            t01 += xv * wp[ci*COUT +   CIN*COUT];
            t10 += xv * wp[ci*COUT + 8*CIN*COUT];
            t11 += xv * wp[ci*COUT + 9*CIN*COUT];
        }
        float wx1 = d.fx, wy1 = d.fy;
        float wx0 = 1.f - wx1, wy0 = 1.f - wy1;
        acc += (wx0*wy0)*t00 + (wx0*wy1)*t01 + (wx1*wy0)*t10 + (wx1*wy1)*t11;
    }
    acc += bc[cl];
    if (lane < COUT)
        out[(size_t)t*out_stride + out_off + lane] = acc;
}

// ---------------------------------------------------------------------------
extern "C" void kernel_launch(void* const* d_in, const int* in_sizes, int n_in,
                              void* d_out, int out_size, void* d_ws, size_t ws_size,
                              hipStream_t stream)
{
    const float* fluid_pos  = (const float*)d_in[0];
    const float* bnd_pos    = (const float*)d_in[1];
    const float* fluid_feat = (const float*)d_in[2];
    const float* bnd_feat   = (const float*)d_in[3];
    const int*   f_tgt      = (const int*)  d_in[4];
    const int*   f_src      = (const int*)  d_in[5];
    const int*   b_tgt      = (const int*)  d_in[6];
    const int*   b_src      = (const int*)  d_in[7];
    const float* Wc0 = (const float*)d_in[8];  const float* bc0 = (const float*)d_in[9];
    const float* Wc1 = (const float*)d_in[10]; const float* bc1 = (const float*)d_in[11];
    const float* Wc2 = (const float*)d_in[12]; const float* bc2 = (const float*)d_in[13];
    const float* Wc3 = (const float*)d_in[14]; const float* bc3 = (const float*)d_in[15];
    const float* Wc4 = (const float*)d_in[16]; const float* bc4 = (const float*)d_in[17];
    const float* Wl0 = (const float*)d_in[18]; const float* bl0 = (const float*)d_in[19];
    const float* Wl1 = (const float*)d_in[20]; const float* bl1 = (const float*)d_in[21];
    const float* Wl2 = (const float*)d_in[22]; const float* bl2 = (const float*)d_in[23];
    const float* Wl3 = (const float*)d_in[24]; const float* bl3 = (const float*)d_in[25];

    int nEf = in_sizes[4];
    int nEb = in_sizes[6];
    int entPadMax = nEf + NCC * PADQ;
    float support = (float)sqrt(16.0 / (M_PI * 16384.0));

    char* w = (char*)d_ws;
    auto alloc = [&](size_t bytes){ char* r = w; w += (bytes + 255) & ~(size_t)255; return r; };
    EdgeData* edF      = (EdgeData*)alloc((size_t)nEf * sizeof(EdgeData));
    EdgeData* edB      = (EdgeData*)alloc((size_t)nEb * sizeof(EdgeData));
    int*      cnt      = (int*)     alloc(64 * sizeof(int));
    int*      cellOff  = (int*)     alloc(64 * sizeof(int));
    int*      gcursor  = (int*)     alloc(64 * sizeof(int));
    int4*     entries  = (int4*)    alloc((size_t)entPadMax * sizeof(int4));
    int*      e2s      = (int*)     alloc((size_t)nEf * sizeof(int));
    unsigned short* wb0 = (unsigned short*)alloc((size_t)64*8*32  * 2);
    unsigned short* wt2 = (unsigned short*)alloc((size_t)64*64*96 * 2);  // [cell][cout][k]
    unsigned short* wt3 = (unsigned short*)alloc((size_t)64*64*64 * 2);
    unsigned short* xbA = (unsigned short*)alloc((size_t)NFL*192 * 2);   // hi|lo
    unsigned short* xb1 = (unsigned short*)alloc((size_t)NFL*128 * 2);
    float*    ansA     = (float*)   alloc((size_t)NFL * 96 * sizeof(float));
    float*    y1       = (float*)   alloc((size_t)NFL * 64 * sizeof(float));
    float*    y2       = (float*)   alloc((size_t)NFL * 64 * sizeof(float));
    float*    msg      = (float*)   alloc((size_t)entPadMax * 64 * sizeof(float));
    float*    msg2     = msg;   // reused after combine12<64> finishes

    // ---- edge prep + bucket build
    prep_edges_k<<<(nEf+255)/256, 256, 0, stream>>>(fluid_pos, fluid_pos, f_tgt, f_src, nEf, support, -1.f, edF);
    prep_edges_k<<<(nEb+255)/256, 256, 0, stream>>>(fluid_pos, bnd_pos,   b_tgt, b_src, nEb, support,  1.f, edB);
    zero64_k<<<1, 64, 0, stream>>>(cnt);
    hist_k<<<(nEf+255)/256, 256, 0, stream>>>(edF, nEf, cnt);
    scan_pad_k<<<1, 64, 0, stream>>>(cnt, cellOff, gcursor);
    fill_entries_k<<<(entPadMax+255)/256, 256, 0, stream>>>(entries, entPadMax);
    scatter_k<<<(nEf+255)/256, 256, 0, stream>>>(edF, nEf, cellOff, gcursor, entries, e2s);

    // ---- weight preprociessing
    wcvt_k<<<(64*8*32 +255)/256, 256, 0, stream>>>(Wc0, wb0, 64*8*32);
    wtr_k<96><<<64, 256, 0, stream>>>(Wc2, wt2);
    wtr_k<64><<<64, 256, 0, stream>>>(Wc3, wt3);

    int gridM   = (entPadMax + 63)  / 64;
    int grid128 = (entPadMax + 127) / 128;
    dim3 tgrid(NFL/4);

    // ---- input block
    conv_cell_k<8,32,128,false><<<grid128, 128, 0, stream>>>(fluid_feat, entries, cellOff, wb0, msg);
    conv_tgt_k<8,32><<<tgrid, 256, 0, stream>>>(bnd_feat, edB, b_tgt, nEb, Wc1, bc1, ansA, 96, 64);
    combine0_k<<<tgrid, 256, 0, stream>>>(fluid_feat, Wl0, bl0, bc0, msg, e2s, f_tgt, nEf, ansA);

    // ---- block 1: y1 = conv(relu(ansA),Wc2)+bc2 + relu(ansA)@Wl1+bl1
    xcvt_k<96,true><<<(NFL*12+255)/256, 256, 0, stream>>>(ansA, xbA);
    conv_mfma_k<96><<<gridM, 256, 0, stream>>>(xbA, entries, cellOff, wt2, msg);
    combine12_k<96,false><<<tgrid, 256, 0, stream>>>(ansA, Wl1, bl1, bc2, msg, e2s, f_tgt, nEf, y1);

    // ---- block 2: y2 = conv(relu(y1),Wc3)+bc3 + relu(y1)@Wl2+bl2 + y1
    xcvt_k<64,true><<<(NFL*8+255)/256, 256, 0, stream>>>(y1, xb1);
    conv_mfma_k<64><<<gridM, 256, 0, stream>>>(xb1, entries, cellOff, wt3, msg);
    combine12_k<64,true><<<tgrid, 256, 0, stream>>>(y1, Wl2, bl2, bc3, msg, e2s, f_tgt, nEf, y2);

    // ---- block 3 (final): thread-per-edge conv + fused combine
    conv2_msg_k<<<grid128, 128, 0, stream>>>(y2, entries, cellOff, Wc4, msg2);
    final_combine_k<<<(NFL+255)/256, 256, 0, stream>>>(y2, Wl3, bl3, bc4, msg2, e2s, f_tgt, nEf, (float*)d_out);
}

// Round 6
// 379.684 us; speedup vs baseline: 15.5653x; 1.2305x over previous
//
#include <hip/hip_runtime.h>
#include <math.h>
#include <stdint.h>

#define NFL   16384
#define NCC   55      // base cells: ix,iy in 0..6 -> ixiy = ix*8+iy in 0..54
#define PADQ  128     // bucket pad quantum (multiple of all tile sizes)

struct EdgeData { int src; int ixiy; float fx; float fy; };

typedef __attribute__((ext_vector_type(8))) short short8v;   // 8 bf16
typedef __attribute__((ext_vector_type(4))) float f32x4;

__device__ __forceinline__ float frelu(float x){ return x > 0.f ? x : 0.f; }
__device__ __forceinline__ unsigned short f2bf(float f){
    unsigned int u = __float_as_uint(f);
    unsigned int r = (u + 0x7FFFu + ((u >> 16) & 1u)) >> 16;   // RNE
    return (unsigned short)r;
}

// ---------------------------------------------------------------- prep edges
__global__ void prep_edges_k(const float* __restrict__ qpos,
                             const float* __restrict__ ppos,
                             const int* __restrict__ tgt,
                             const int* __restrict__ src,
                             int nE, float support, float sgn,
                             EdgeData* __restrict__ out)
{
    int e = blockIdx.x * blockDim.x + threadIdx.x;
    if (e >= nE) return;
    int t = tgt[e], s = src[e];
    float dx = sgn * (ppos[2*s]   - qpos[2*t])   / support;
    float dy = sgn * (ppos[2*s+1] - qpos[2*t+1]) / support;
    dx = fminf(1.f, fmaxf(-1.f, dx));
    dy = fminf(1.f, fmaxf(-1.f, dy));
    float r  = sqrtf(dx*dx + dy*dy + 1e-12f);
    float th = atan2f(dy, dx);
    float m0 = fminf(1.f, fmaxf(-1.f, 2.f*r - 1.f));
    float m1 = fminf(1.f, fmaxf(-1.f, th * 0.3183098861837907f));
    float u = (m0 + 1.f) * 3.5f;
    float v = (m1 + 1.f) * 3.5f;
    int ix = (int)u; if (ix > 6) ix = 6;
    int iy = (int)v; if (iy > 6) iy = 6;
    EdgeData ed;
    ed.src  = s;
    ed.ixiy = ix*8 + iy;
    ed.fx   = u - (float)ix;
    ed.fy   = v - (float)iy;
    out[e] = ed;
}

// --------------------------------------------------------- rowptr for f_tgt
__global__ void rowptr_k(const int* __restrict__ tgt, int nE, int* __restrict__ rowptr)
{
    int t = blockIdx.x * blockDim.x + threadIdx.x;
    if (t > NFL) return;
    if (t == NFL){ rowptr[NFL] = nE; return; }
    int lo = 0, hi = nE;
    while (lo < hi){ int mid = (lo + hi) >> 1; if (tgt[mid] < t) lo = mid + 1; else hi = mid; }
    rowptr[t] = lo;
}

// ------------------------------------------------------------- bucket build
__global__ void zero64_k(int* __restrict__ a){ if (threadIdx.x < 64) a[threadIdx.x] = 0; }

__global__ void hist_k(const EdgeData* __restrict__ ed, int nE, int* __restrict__ cnt)
{
    __shared__ int lc[64];
    int tid = threadIdx.x;
    if (tid < 64) lc[tid] = 0;
    __syncthreads();
    int e = blockIdx.x * blockDim.x + tid;
    if (e < nE) atomicAdd(&lc[ed[e].ixiy], 1);
    __syncthreads();
    if (tid < 64 && lc[tid] > 0) atomicAdd(&cnt[tid], lc[tid]);
}

__global__ void scan_pad_k(const int* __restrict__ cnt, int* __restrict__ cellOff,
                           int* __restrict__ gcursor)
{
    if (threadIdx.x < 64) gcursor[threadIdx.x] = 0;
    if (threadIdx.x == 0){
        int s = 0;
        for (int k = 0; k < NCC; ++k){
            cellOff[k] = s;
            s += ((cnt[k] + PADQ - 1) / PADQ) * PADQ;
        }
        cellOff[NCC] = s;
    }
}

__global__ void fill_entries_k(int4* __restrict__ entries, int n)
{
    int i = blockIdx.x * blockDim.x + threadIdx.x;
    if (i < n) entries[i] = make_int4(0, -1, 0, 0);
}

__global__ void scatter_k(const EdgeData* __restrict__ ed, int nE,
                          const int* __restrict__ cellOff,
                          int* __restrict__ gcursor,
                          int4* __restrict__ entries,
                          int* __restrict__ e2s)
{
    __shared__ int lc[64], base[64];
    int tid = threadIdx.x;
    if (tid < 64) lc[tid] = 0;
    __syncthreads();
    int e = blockIdx.x * blockDim.x + tid;
    bool ok = e < nE;
    EdgeData d; int k = 0, r = 0;
    if (ok){ d = ed[e]; k = d.ixiy; r = atomicAdd(&lc[k], 1); }
    __syncthreads();
    if (tid < 64 && lc[tid] > 0) base[tid] = atomicAdd(&gcursor[tid], lc[tid]);
    __syncthreads();
    if (ok){
        int slot = cellOff[k] + base[k] + r;
        entries[slot] = make_int4(d.src, e, __float_as_int(d.fx), __float_as_int(d.fy));
        e2s[e] = slot;
    }
}

// ------------------------------------------------------------ W fp32 -> bf16
__global__ void wcvt_k(const float* __restrict__ in, unsigned short* __restrict__ out, int n)
{
    int i = blockIdx.x * blockDim.x + threadIdx.x;
    if (i < n) out[i] = f2bf(in[i]);
}

// W [64][CIN][COUT] fp32 -> wt [64][COUT][CIN] bf16, one block per cell
template<int CIN>
__global__ __launch_bounds__(256)
void wtr_k(const float* __restrict__ Wsrc, unsigned short* __restrict__ wt)
{
    constexpr int COUT = 64;
    __shared__ unsigned short T[COUT][CIN + 2];
    int cell = blockIdx.x;
    const float* s = Wsrc + (size_t)cell * CIN * COUT;
    for (int i = threadIdx.x; i < CIN*COUT; i += 256){
        int k = i / COUT, c = i - k*COUT;
        T[c][k] = f2bf(s[i]);
    }
    __syncthreads();
    unsigned short* d = wt + (size_t)cell * COUT * CIN;
    for (int i = threadIdx.x; i < CIN*COUT; i += 256){
        int c = i / CIN, k = i - c*CIN;
        d[i] = T[c][k];
    }
}

// --------------------- x fp32 -> bf16 hi|lo rows: xb[n][0:CIN]=hi, [CIN:2CIN]=lo
template<int CIN, bool RELU>
__global__ void xcvt_k(const float* __restrict__ x, unsigned short* __restrict__ xb)
{
    constexpr int C8 = CIN / 8;
    int i = blockIdx.x * blockDim.x + threadIdx.x;
    if (i >= NFL * C8) return;
    int n = i / C8, c = (i - n*C8) * 8;
    const float* xp = x + (size_t)n*CIN + c;
    float4 v0 = *(const float4*)xp;
    float4 v1 = *(const float4*)(xp + 4);
    float f[8] = { v0.x, v0.y, v0.z, v0.w, v1.x, v1.y, v1.z, v1.w };
    unsigned int hw[4], lw[4];
#pragma unroll
    for (int j = 0; j < 4; ++j){
        float a = RELU ? frelu(f[2*j])   : f[2*j];
        float b = RELU ? frelu(f[2*j+1]) : f[2*j+1];
        unsigned int ua = __float_as_uint(a), ub = __float_as_uint(b);
        hw[j] = (ua >> 16) | (ub & 0xFFFF0000u);               // trunc hi
        float la = a - __uint_as_float(ua & 0xFFFF0000u);
        float lb = b - __uint_as_float(ub & 0xFFFF0000u);
        lw[j] = (__float_as_uint(la) >> 16) | (__float_as_uint(lb) & 0xFFFF0000u);
    }
    unsigned short* out = xb + (size_t)n * (2*CIN);
    *(uint4*)(out + c)        = make_uint4(hw[0], hw[1], hw[2], hw[3]);
    *(uint4*)(out + CIN + c)  = make_uint4(lw[0], lw[1], lw[2], lw[3]);
}

// -------------------------------------------- MFMA cell-conv: 64 edges/block
// A = gathered xb rows (hi|lo bf16) staged in LDS; B read DIRECTLY from global
// wt (L2-resident, 786KB) -> no W LDS tile, 27KB LDS -> high occupancy.
// 4 waves: wave w owns couts [16w,16w+16). C layout: col=lane&15, row=(lane>>4)*4+reg.
template<int CIN>
__global__ __launch_bounds__(256)
void conv_mfma_k(const unsigned short* __restrict__ xb,   // [NFL][2*CIN]
                 const int4* __restrict__ entries,
                 const int* __restrict__ cellOff,
                 const unsigned short* __restrict__ wt,   // [64][64][CIN]
                 float* __restrict__ msg)                 // [slot][64]
{
    constexpr int COUT = 64;
    constexpr int K2   = 2 * CIN;
    constexpr int XROW = K2*2 + 16;        // bytes: 400 (96) / 272 (64)
    constexpr int C16  = K2*2/16;          // 16B chunks per x row: 24 / 16

    __shared__ unsigned char XL[64 * XROW];
    __shared__ float BW[4][64];
    __shared__ int   SRC[64];

    int total = cellOff[NCC];
    int p0 = blockIdx.x * 64;
    if (p0 >= total) return;
    int tid = threadIdx.x;

    int lo_ = 0, hi_ = NCC;
    while (hi_ - lo_ > 1){ int mid = (lo_ + hi_) >> 1; if (cellOff[mid] <= p0) lo_ = mid; else hi_ = mid; }
    const int cell = lo_;
    const int kc[4] = { cell, cell+1, cell+8, cell+9 };

    // bilinear weights + src gather list
    if (tid < 64){
        int4 en = entries[p0 + tid];
        bool ok = en.y >= 0;
        float fx = __int_as_float(en.z), fy = __int_as_float(en.w);
        BW[0][tid] = ok ? (1.f-fx)*(1.f-fy) : 0.f;
        BW[1][tid] = ok ? (1.f-fx)*fy       : 0.f;
        BW[2][tid] = ok ? fx*(1.f-fy)       : 0.f;
        BW[3][tid] = ok ? fx*fy             : 0.f;
        SRC[tid] = en.x;
    }
    __syncthreads();
    // stage X rows (hi|lo bf16, padded stride)
    for (int i = tid; i < 64*C16; i += 256){
        int e = i / C16, c = i - e*C16;
        const uint4* sp = (const uint4*)(xb + (size_t)SRC[e]*K2) + c;
        *(uint4*)(&XL[e*XROW + 16*c]) = *sp;
    }
    __syncthreads();

    const int lane = tid & 63, wv = tid >> 6;
    const int lr = lane & 15, lg = lane >> 4;
    const int cb = wv * 16;

    // per-lane W base: cout = cb+lr, k-offset lg*8; corner adds scalar offset
    const unsigned short* wbase = wt + (size_t)(cb + lr) * CIN + lg * 8;

    f32x4 acc[4][4];   // [corner][edge-group]
#pragma unroll
    for (int cr = 0; cr < 4; ++cr)
#pragma unroll
        for (int ae = 0; ae < 4; ++ae)
            acc[cr][ae] = (f32x4)0.f;

#pragma unroll
    for (int k0 = 0; k0 < CIN; k0 += 32){
        short8v b[4], ah[4], al[4];
#pragma unroll
        for (int cr = 0; cr < 4; ++cr)
            b[cr] = *(const short8v*)(wbase + (size_t)kc[cr]*(COUT*CIN) + k0);
#pragma unroll
        for (int ae = 0; ae < 4; ++ae){
            const unsigned char* rp = XL + (16*ae + lr)*XROW + k0*2 + lg*16;
            ah[ae] = *(const short8v*)rp;
            al[ae] = *(const short8v*)(rp + CIN*2);
        }
#pragma unroll
        for (int cr = 0; cr < 4; ++cr)
#pragma unroll
            for (int ae = 0; ae < 4; ++ae){
                acc[cr][ae] = __builtin_amdgcn_mfma_f32_16x16x32_bf16(ah[ae], b[cr], acc[cr][ae], 0, 0, 0);
                acc[cr][ae] = __builtin_amdgcn_mfma_f32_16x16x32_bf16(al[ae], b[cr], acc[cr][ae], 0, 0, 0);
            }
    }

    // bilinear combine + store
#pragma unroll
    for (int ae = 0; ae < 4; ++ae){
#pragma unroll
        for (int r = 0; r < 4; ++r){
            int E = 16*ae + lg*4 + r;
            float v = BW[0][E]*acc[0][ae][r] + BW[1][E]*acc[1][ae][r]
                    + BW[2][E]*acc[2][ae][r] + BW[3][E]*acc[3][ae][r];
            msg[(size_t)(p0 + E)*COUT + cb + lr] = v;
        }
    }
}

// -------------------------- fp32 cell-conv (kept for conv0: CIN=8, COUT=32)
template<int CIN, int COUT, int TILE_E, bool RELU>
__global__ __launch_bounds__(128)
void conv_cell_k(const float* __restrict__ x,
                 const int4* __restrict__ entries,
                 const int* __restrict__ cellOff,
                 const unsigned short* __restrict__ Wbf,
                 float* __restrict__ msg)
{
    constexpr int TEP = TILE_E + 4;
    constexpr int EG  = TILE_E / 4;
    constexpr int CG  = COUT / 8;
    static_assert(EG * CG == 128, "tile/thread mismatch");
    constexpr int C4  = CIN / 4;

    __shared__ float XT[CIN][TEP];
    __shared__ unsigned short WLc[4][CIN][COUT];
    __shared__ int4 EN[TILE_E];

    int total = cellOff[NCC];
    int p0 = blockIdx.x * TILE_E;
    if (p0 >= total) return;
    int tid = threadIdx.x;

    int lo = 0, hi = NCC;
    while (hi - lo > 1){ int mid = (lo + hi) >> 1; if (cellOff[mid] <= p0) lo = mid; else hi = mid; }
    const int cell = lo;

    for (int i = tid; i < TILE_E; i += 128) EN[i] = entries[p0 + i];

    const int kc[4] = { cell, cell + 1, cell + 8, cell + 9 };
#pragma unroll
    for (int c = 0; c < 4; ++c){
        const uint4* s = (const uint4*)(Wbf + (size_t)kc[c] * (CIN * COUT));
        uint4* dlds = (uint4*)(&WLc[c][0][0]);
        for (int i = tid; i < CIN * COUT / 8; i += 128) dlds[i] = s[i];
    }
    __syncthreads();

    for (int i = tid; i < TILE_E * C4; i += 128){
        int e  = i / C4;
        int c4 = i - e * C4;
        int4 en = EN[e];
        float4 v = make_float4(0.f, 0.f, 0.f, 0.f);
        if (en.y >= 0){
            v = *(const float4*)(x + (size_t)en.x * CIN + 4 * c4);
            if (RELU){ v.x = frelu(v.x); v.y = frelu(v.y); v.z = frelu(v.z); v.w = frelu(v.w); }
        }
        XT[4*c4+0][e] = v.x;
        XT[4*c4+1][e] = v.y;
        XT[4*c4+2][e] = v.z;
        XT[4*c4+3][e] = v.w;
    }
    __syncthreads();

    const int egrp = tid % EG;
    const int cgrp = tid / EG;
    const int e0 = egrp * 4;

    float fx[4], fy[4];
#pragma unroll
    for (int j = 0; j < 4; ++j){
        int4 en = EN[e0 + j];
        fx[j] = __int_as_float(en.z);
        fy[j] = __int_as_float(en.w);
    }

    float accT[4][8];
#pragma unroll
    for (int j = 0; j < 4; ++j)
#pragma unroll
        for (int c = 0; c < 8; ++c) accT[j][c] = 0.f;

#pragma unroll
    for (int cr = 0; cr < 4; ++cr){
        float accC[4][8];
#pragma unroll
        for (int j = 0; j < 4; ++j)
#pragma unroll
            for (int c = 0; c < 8; ++c) accC[j][c] = 0.f;

#pragma unroll
        for (int ci = 0; ci < CIN; ++ci){
            float4 xv = *(const float4*)&XT[ci][e0];
            uint4 wp = *(const uint4*)&WLc[cr][ci][cgrp * 8];
            float wf0 = __uint_as_float(wp.x << 16);
            float wf1 = __uint_as_float(wp.x & 0xFFFF0000u);
            float wf2 = __uint_as_float(wp.y << 16);
            float wf3 = __uint_as_float(wp.y & 0xFFFF0000u);
            float wf4 = __uint_as_float(wp.z << 16);
            float wf5 = __uint_as_float(wp.z & 0xFFFF0000u);
            float wf6 = __uint_as_float(wp.w << 16);
            float wf7 = __uint_as_float(wp.w & 0xFFFF0000u);
            const float xe[4] = { xv.x, xv.y, xv.z, xv.w };
#pragma unroll
            for (int j = 0; j < 4; ++j){
                accC[j][0] += xe[j] * wf0;
                accC[j][1] += xe[j] * wf1;
                accC[j][2] += xe[j] * wf2;
                accC[j][3] += xe[j] * wf3;
                accC[j][4] += xe[j] * wf4;
                accC[j][5] += xe[j] * wf5;
                accC[j][6] += xe[j] * wf6;
                accC[j][7] += xe[j] * wf7;
            }
        }
#pragma unroll
        for (int j = 0; j < 4; ++j){
            float wc = (cr == 0) ? (1.f - fx[j]) * (1.f - fy[j]) :
                       (cr == 1) ? (1.f - fx[j]) * fy[j] :
                       (cr == 2) ? fx[j] * (1.f - fy[j]) :
                                   fx[j] * fy[j];
#pragma unroll
            for (int c = 0; c < 8; ++c) accT[j][c] += wc * accC[j][c];
        }
    }

#pragma unroll
    for (int j = 0; j < 4; ++j){
        float* mp = msg + (size_t)(p0 + e0 + j) * COUT + cgrp * 8;
        *(float4*)mp       = make_float4(accT[j][0], accT[j][1], accT[j][2], accT[j][3]);
        *(float4*)(mp + 4) = make_float4(accT[j][4], accT[j][5], accT[j][6], accT[j][7]);
    }
}

// --------------------------- final conv (64->2): thread-per-edge -> msg2
__global__ __launch_bounds__(128)
void conv2_msg_k(const float* __restrict__ x,
                 const int4* __restrict__ entries,
                 const int* __restrict__ cellOff,
                 const float* __restrict__ Wc,
                 float* __restrict__ msg2)
{
    __shared__ float WLf[4][64][2];
    int total = cellOff[NCC];
    int p0 = blockIdx.x * 128;
    if (p0 >= total) return;
    int tid = threadIdx.x;

    int lo = 0, hi = NCC;
    while (hi - lo > 1){ int mid = (lo + hi) >> 1; if (cellOff[mid] <= p0) lo = mid; else hi = mid; }
    const int cell = lo;
    const int kc[4] = { cell, cell + 1, cell + 8, cell + 9 };
#pragma unroll
    for (int c = 0; c < 4; ++c)
        ((float*)&WLf[c][0][0])[tid] = Wc[(size_t)kc[c] * 128 + tid];
    __syncthreads();

    int4 en = entries[p0 + tid];
    if (en.y < 0) return;
    float fx = __int_as_float(en.z), fy = __int_as_float(en.w);
    const float* xp = x + (size_t)en.x * 64;

    float a[4][2] = {{0.f,0.f},{0.f,0.f},{0.f,0.f},{0.f,0.f}};
#pragma unroll 4
    for (int ci = 0; ci < 64; ci += 4){
        float4 v = *(const float4*)(xp + ci);
        float xe[4] = { frelu(v.x), frelu(v.y), frelu(v.z), frelu(v.w) };
#pragma unroll
        for (int j = 0; j < 4; ++j){
#pragma unroll
            for (int cr = 0; cr < 4; ++cr){
                a[cr][0] += xe[j] * WLf[cr][ci+j][0];
                a[cr][1] += xe[j] * WLf[cr][ci+j][1];
            }
        }
    }
    float w0 = (1.f-fx)*(1.f-fy), w1 = (1.f-fx)*fy, w2 = fx*(1.f-fy), w3 = fx*fy;
    float m0 = w0*a[0][0] + w1*a[1][0] + w2*a[2][0] + w3*a[3][0];
    float m1 = w0*a[0][1] + w1*a[1][1] + w2*a[2][1] + w3*a[3][1];
    *(float2*)(msg2 + (size_t)(p0 + tid) * 2) = make_float2(m0, m1);
}

// --------------------------- final combine: thread-per-target, out = .../128
__global__ __launch_bounds__(256)
void final_combine_k(const float* __restrict__ y2,
                     const float* __restrict__ Wl3, const float* __restrict__ bl3,
                     const float* __restrict__ bc4,
                     const float* __restrict__ msg2,
                     const int* __restrict__ e2s,
                     const int* __restrict__ rowptr,
                     float* __restrict__ out)
{
    __shared__ float WS[128];
    int tid = threadIdx.x;
    if (tid < 128) WS[tid] = Wl3[tid];
    __syncthreads();

    int t = blockIdx.x * blockDim.x + tid;
    if (t >= NFL) return;
    int eb = rowptr[t], ee = rowptr[t+1];

    float a0 = bc4[0] + bl3[0];
    float a1 = bc4[1] + bl3[1];
    const float* pr = y2 + (size_t)t * 64;
#pragma unroll 4
    for (int ci = 0; ci < 64; ci += 4){
        float4 v = *(const float4*)(pr + ci);
        float xe[4] = { frelu(v.x), frelu(v.y), frelu(v.z), frelu(v.w) };
#pragma unroll
        for (int j = 0; j < 4; ++j){
            a0 += xe[j] * WS[(ci+j)*2];
            a1 += xe[j] * WS[(ci+j)*2 + 1];
        }
    }
    for (int e = eb; e < ee; ++e){
        int slot = e2s[e];
        float2 m = *(const float2*)(msg2 + (size_t)slot * 2);
        a0 += m.x; a1 += m.y;
    }
    out[(size_t)t*2]     = a0 * (1.0f/128.0f);
    out[(size_t)t*2 + 1] = a1 * (1.0f/128.0f);
}

// --------------------------------------------- combine: msg-sum + dns + bias
__global__ __launch_bounds__(256)
void combine0_k(const float* __restrict__ feat,
                const float* __restrict__ Wl0, const float* __restrict__ bl0,
                const float* __restrict__ bc0,
                const float* __restrict__ msg,           // [slot][32]
                const int* __restrict__ e2s,
                const int* __restrict__ rowptr,
                float* __restrict__ ansA)
{
    int t = blockIdx.x * (blockDim.x >> 6) + (threadIdx.x >> 6);
    if (t >= NFL) return;
    int lane = threadIdx.x & 63;
    int eb = rowptr[t], ee = rowptr[t+1];

    if (lane < 32){
        float a = bl0[lane];
#pragma unroll
        for (int ci = 0; ci < 8; ++ci)
            a += feat[t*8 + ci] * Wl0[ci*32 + lane];
        ansA[(size_t)t*96 + lane] = a;
    } else {
        int c = lane - 32;
        float a = bc0[c];
        for (int e = eb; e < ee; ++e){
            int slot = e2s[e];
            a += msg[(size_t)slot*32 + c];
        }
        ansA[(size_t)t*96 + 32 + c] = a;
    }
}

// combine + optionally write relu(y) hi|lo bf16 (fused xcvt for next conv layer)
template<int CIN, bool RESID, bool WRITE_XB>
__global__ __launch_bounds__(256)
void combine12_k(const float* __restrict__ prev,
                 const float* __restrict__ Wl, const float* __restrict__ bl,
                 const float* __restrict__ bc,
                 const float* __restrict__ msg,          // [slot][64]
                 const int* __restrict__ e2s,
                 const int* __restrict__ rowptr,
                 float* __restrict__ y,
                 unsigned short* __restrict__ xbnext)    // [NFL][128] hi|lo (WRITE_XB)
{
    int t = blockIdx.x * (blockDim.x >> 6) + (threadIdx.x >> 6);
    if (t >= NFL) return;
    int lane = threadIdx.x & 63;
    int eb = rowptr[t], ee = rowptr[t+1];

    const float* pr = prev + (size_t)t * CIN;
    float acc = bc[lane] + bl[lane];
#pragma unroll 8
    for (int ci = 0; ci < CIN; ++ci)
        acc += frelu(pr[ci]) * Wl[ci*64 + lane];
    if (RESID) acc += pr[lane];

    for (int e = eb; e < ee; ++e){
        int slot = e2s[e];
        acc += msg[(size_t)slot*64 + lane];
    }
    y[(size_t)t*64 + lane] = acc;

    if (WRITE_XB){
        float a = frelu(acc);
        unsigned int ua = __float_as_uint(a);
        unsigned short hi = (unsigned short)(ua >> 16);        // trunc hi
        float la = a - __uint_as_float(ua & 0xFFFF0000u);
        unsigned short lo = (unsigned short)(__float_as_uint(la) >> 16);
        xbnext[(size_t)t*128 + lane]      = hi;
        xbnext[(size_t)t*128 + 64 + lane] = lo;
    }
}

// ----------------------------------------- per-target conv (bconv only)
template<int CIN, int COUT>
__global__ __launch_bounds__(256)
void conv_tgt_k(const float* __restrict__ xsrc,
                const EdgeData* __restrict__ ed,
                const int* __restrict__ tgt, int nE,
                const float* __restrict__ Wc, const float* __restrict__ bc,
                float* __restrict__ out, int out_stride, int out_off)
{
    int t = blockIdx.x * (blockDim.x >> 6) + (threadIdx.x >> 6);
    if (t >= NFL) return;
    int lane = threadIdx.x & 63;
    int cl = lane < COUT ? lane : 0;

    int lo = 0, hi = nE;
    while (lo < hi){ int mid = (lo + hi) >> 1; if (tgt[mid] <  t) lo = mid + 1; else hi = mid; }
    int eb = lo; hi = nE;
    while (lo < hi){ int mid = (lo + hi) >> 1; if (tgt[mid] <= t) lo = mid + 1; else hi = mid; }
    int ee = lo;

    float acc = 0.f;
    for (int e = eb; e < ee; ++e){
        EdgeData d = ed[e];
        int s  = __builtin_amdgcn_readfirstlane(d.src);
        int kk = __builtin_amdgcn_readfirstlane(d.ixiy);
        const float* xp = xsrc + (size_t)s * CIN;
        const float* wp = Wc + (size_t)kk * (CIN*COUT) + cl;
        float t00 = 0.f, t01 = 0.f, t10 = 0.f, t11 = 0.f;
#pragma unroll 8
        for (int ci = 0; ci < CIN; ++ci){
            float xv = xp[ci];
            t00 += xv * wp[ci*COUT];
            t01 += xv * wp[ci*COUT +   CIN*COUT];
            t10 += xv * wp[ci*COUT + 8*CIN*COUT];
            t11 += xv * wp[ci*COUT + 9*CIN*COUT];
        }
        float wx1 = d.fx, wy1 = d.fy;
        float wx0 = 1.f - wx1, wy0 = 1.f - wy1;
        acc += (wx0*wy0)*t00 + (wx0*wy1)*t01 + (wx1*wy0)*t10 + (wx1*wy1)*t11;
    }
    acc += bc[cl];
    if (lane < COUT)
        out[(size_t)t*out_stride + out_off + lane] = acc;
}

// ---------------------------------------------------------------------------
extern "C" void kernel_launch(void* const* d_in, const int* in_sizes, int n_in,
                              void* d_out, int out_size, void* d_ws, size_t ws_size,
                              hipStream_t stream)
{
    const float* fluid_pos  = (const float*)d_in[0];
    const float* bnd_pos    = (const float*)d_in[1];
    const float* fluid_feat = (const float*)d_in[2];
    const float* bnd_feat   = (const float*)d_in[3];
    const int*   f_tgt      = (const int*)  d_in[4];
    const int*   f_src      = (const int*)  d_in[5];
    const int*   b_tgt      = (const int*)  d_in[6];
    const int*   b_src      = (const int*)  d_in[7];
    const float* Wc0 = (const float*)d_in[8];  const float* bc0 = (const float*)d_in[9];
    const float* Wc1 = (const float*)d_in[10]; const float* bc1 = (const float*)d_in[11];
    const float* Wc2 = (const float*)d_in[12]; const float* bc2 = (const float*)d_in[13];
    const float* Wc3 = (const float*)d_in[14]; const float* bc3 = (const float*)d_in[15];
    const float* Wc4 = (const float*)d_in[16]; const float* bc4 = (const float*)d_in[17];
    const float* Wl0 = (const float*)d_in[18]; const float* bl0 = (const float*)d_in[19];
    const float* Wl1 = (const float*)d_in[20]; const float* bl1 = (const float*)d_in[21];
    const float* Wl2 = (const float*)d_in[22]; const float* bl2 = (const float*)d_in[23];
    const float* Wl3 = (const float*)d_in[24]; const float* bl3 = (const float*)d_in[25];

    int nEf = in_sizes[4];
    int nEb = in_sizes[6];
    int entPadMax = nEf + NCC * PADQ;
    float support = (float)sqrt(16.0 / (M_PI * 16384.0));

    char* w = (char*)d_ws;
    auto alloc = [&](size_t bytes){ char* r = w; w += (bytes + 255) & ~(size_t)255; return r; };
    EdgeData* edF      = (EdgeData*)alloc((size_t)nEf * sizeof(EdgeData));
    EdgeData* edB      = (EdgeData*)alloc((size_t)nEb * sizeof(EdgeData));
    int*      cnt      = (int*)     alloc(64 * sizeof(int));
    int*      cellOff  = (int*)     alloc(64 * sizeof(int));
    int*      gcursor  = (int*)     alloc(64 * sizeof(int));
    int*      rowptr   = (int*)     alloc((NFL+1) * sizeof(int));
    int4*     entries  = (int4*)    alloc((size_t)entPadMax * sizeof(int4));
    int*      e2s      = (int*)     alloc((size_t)nEf * sizeof(int));
    unsigned short* wb0 = (unsigned short*)alloc((size_t)64*8*32  * 2);
    unsigned short* wt2 = (unsigned short*)alloc((size_t)64*64*96 * 2);  // [cell][cout][k]
    unsigned short* wt3 = (unsigned short*)alloc((size_t)64*64*64 * 2);
    unsigned short* xbA = (unsigned short*)alloc((size_t)NFL*192 * 2);   // hi|lo
    unsigned short* xb1 = (unsigned short*)alloc((size_t)NFL*128 * 2);
    float*    ansA     = (float*)   alloc((size_t)NFL * 96 * sizeof(float));
    float*    y1       = (float*)   alloc((size_t)NFL * 64 * sizeof(float));
    float*    y2       = (float*)   alloc((size_t)NFL * 64 * sizeof(float));
    float*    msg      = (float*)   alloc((size_t)entPadMax * 64 * sizeof(float));
    float*    msg2     = msg;   // reused after combine12<64> finishes

    // ---- edge prep + bucket build
    prep_edges_k<<<(nEf+255)/256, 256, 0, stream>>>(fluid_pos, fluid_pos, f_tgt, f_src, nEf, support, -1.f, edF);
    prep_edges_k<<<(nEb+255)/256, 256, 0, stream>>>(fluid_pos, bnd_pos,   b_tgt, b_src, nEb, support,  1.f, edB);
    rowptr_k<<<(NFL+1+255)/256, 256, 0, stream>>>(f_tgt, nEf, rowptr);
    zero64_k<<<1, 64, 0, stream>>>(cnt);
    hist_k<<<(nEf+255)/256, 256, 0, stream>>>(edF, nEf, cnt);
    scan_pad_k<<<1, 64, 0, stream>>>(cnt, cellOff, gcursor);
    fill_entries_k<<<(entPadMax+255)/256, 256, 0, stream>>>(entries, entPadMax);
    scatter_k<<<(nEf+255)/256, 256, 0, stream>>>(edF, nEf, cellOff, gcursor, entries, e2s);

    // ---- weight preprocessing
    wcvt_k<<<(64*8*32 +255)/256, 256, 0, stream>>>(Wc0, wb0, 64*8*32);
    wtr_k<96><<<64, 256, 0, stream>>>(Wc2, wt2);
    wtr_k<64><<<64, 256, 0, stream>>>(Wc3, wt3);

    int gridM   = (entPadMax + 63)  / 64;
    int grid128 = (entPadMax + 127) / 128;
    dim3 tgrid(NFL/4);

    // ---- input block
    conv_cell_k<8,32,128,false><<<grid128, 128, 0, stream>>>(fluid_feat, entries, cellOff, wb0, msg);
    conv_tgt_k<8,32><<<tgrid, 256, 0, stream>>>(bnd_feat, edB, b_tgt, nEb, Wc1, bc1, ansA, 96, 64);
    combine0_k<<<tgrid, 256, 0, stream>>>(fluid_feat, Wl0, bl0, bc0, msg, e2s, rowptr, ansA);

    // ---- block 1: y1 = conv(relu(ansA),Wc2)+bc2 + relu(ansA)@Wl1+bl1 ; fused xcvt->xb1
    xcvt_k<96,true><<<(NFL*12+255)/256, 256, 0, stream>>>(ansA, xbA);
    conv_mfma_k<96><<<gridM, 256, 0, stream>>>(xbA, entries, cellOff, wt2, msg);
    combine12_k<96,false,true><<<tgrid, 256, 0, stream>>>(ansA, Wl1, bl1, bc2, msg, e2s, rowptr, y1, xb1);

    // ---- block 2: y2 = conv(relu(y1),Wc3)+bc3 + relu(y1)@Wl2+bl2 + y1
    conv_mfma_k<64><<<gridM, 256, 0, stream>>>(xb1, entries, cellOff, wt3, msg);
    combine12_k<64,true,false><<<tgrid, 256, 0, stream>>>(y1, Wl2, bl2, bc3, msg, e2s, rowptr, y2, nullptr);

    // ---- block 3 (final): thread-per-edge conv + fused combine
    conv2_msg_k<<<grid128, 128, 0, stream>>>(y2, entries, cellOff, Wc4, msg2);
    final_combine_k<<<(NFL+255)/256, 256, 0, stream>>>(y2, Wl3, bl3, bc4, msg2, e2s, rowptr, (float*)d_out);
}

// Round 7
// 326.853 us; speedup vs baseline: 18.0812x; 1.1616x over previous
//
#include <hip/hip_runtime.h>
#include <math.h>
#include <stdint.h>

#define NFL   16384
#define NCC   55      // base cells: ix,iy in 0..6 -> ixiy = ix*8+iy in 0..54
#define PADQ  128     // bucket pad quantum

struct EdgeData { int src; int ixiy; float fx; float fy; };

typedef _Float16 half8 __attribute__((ext_vector_type(8)));
typedef __attribute__((ext_vector_type(4))) float f32x4;

__device__ __forceinline__ float frelu(float x){ return x > 0.f ? x : 0.f; }
__device__ __forceinline__ unsigned short f2bf(float f){
    unsigned int u = __float_as_uint(f);
    unsigned int r = (u + 0x7FFFu + ((u >> 16) & 1u)) >> 16;   // RNE
    return (unsigned short)r;
}

// ---------------------------------------------------------------- prep edges
__global__ void prep_edges_k(const float* __restrict__ qpos,
                             const float* __restrict__ ppos,
                             const int* __restrict__ tgt,
                             const int* __restrict__ src,
                             int nE, float support, float sgn,
                             EdgeData* __restrict__ out)
{
    int e = blockIdx.x * blockDim.x + threadIdx.x;
    if (e >= nE) return;
    int t = tgt[e], s = src[e];
    float dx = sgn * (ppos[2*s]   - qpos[2*t])   / support;
    float dy = sgn * (ppos[2*s+1] - qpos[2*t+1]) / support;
    dx = fminf(1.f, fmaxf(-1.f, dx));
    dy = fminf(1.f, fmaxf(-1.f, dy));
    float r  = sqrtf(dx*dx + dy*dy + 1e-12f);
    float th = atan2f(dy, dx);
    float m0 = fminf(1.f, fmaxf(-1.f, 2.f*r - 1.f));
    float m1 = fminf(1.f, fmaxf(-1.f, th * 0.3183098861837907f));
    float u = (m0 + 1.f) * 3.5f;
    float v = (m1 + 1.f) * 3.5f;
    int ix = (int)u; if (ix > 6) ix = 6;
    int iy = (int)v; if (iy > 6) iy = 6;
    EdgeData ed;
    ed.src  = s;
    ed.ixiy = ix*8 + iy;
    ed.fx   = u - (float)ix;
    ed.fy   = v - (float)iy;
    out[e] = ed;
}

// ------------------------------------------------- rowptr for a sorted tgt[]
__global__ void rowptr_k(const int* __restrict__ tgt, int nE, int* __restrict__ rowptr)
{
    int t = blockIdx.x * blockDim.x + threadIdx.x;
    if (t > NFL) return;
    if (t == NFL){ rowptr[NFL] = nE; return; }
    int lo = 0, hi = nE;
    while (lo < hi){ int mid = (lo + hi) >> 1; if (tgt[mid] < t) lo = mid + 1; else hi = mid; }
    rowptr[t] = lo;
}

// ------------------------------------------------------------- bucket build
__global__ void zero64_k(int* __restrict__ a){ if (threadIdx.x < 64) a[threadIdx.x] = 0; }

__global__ void hist_k(const EdgeData* __restrict__ ed, int nE, int* __restrict__ cnt)
{
    __shared__ int lc[64];
    int tid = threadIdx.x;
    if (tid < 64) lc[tid] = 0;
    __syncthreads();
    int e = blockIdx.x * blockDim.x + tid;
    if (e < nE) atomicAdd(&lc[ed[e].ixiy], 1);
    __syncthreads();
    if (tid < 64 && lc[tid] > 0) atomicAdd(&cnt[tid], lc[tid]);
}

__global__ void scan_pad_k(const int* __restrict__ cnt, int* __restrict__ cellOff,
                           int* __restrict__ gcursor)
{
    if (threadIdx.x < 64) gcursor[threadIdx.x] = 0;
    if (threadIdx.x == 0){
        int s = 0;
        for (int k = 0; k < NCC; ++k){
            cellOff[k] = s;
            s += ((cnt[k] + PADQ - 1) / PADQ) * PADQ;
        }
        cellOff[NCC] = s;
    }
}

__global__ void fill_entries_k(int4* __restrict__ entries, int n)
{
    int i = blockIdx.x * blockDim.x + threadIdx.x;
    if (i < n) entries[i] = make_int4(0, -1, 0, 0);
}

__global__ void scatter_k(const EdgeData* __restrict__ ed, int nE,
                          const int* __restrict__ cellOff,
                          int* __restrict__ gcursor,
                          int4* __restrict__ entries,
                          int* __restrict__ e2s)
{
    __shared__ int lc[64], base[64];
    int tid = threadIdx.x;
    if (tid < 64) lc[tid] = 0;
    __syncthreads();
    int e = blockIdx.x * blockDim.x + tid;
    bool ok = e < nE;
    EdgeData d; int k = 0, r = 0;
    if (ok){ d = ed[e]; k = d.ixiy; r = atomicAdd(&lc[k], 1); }
    __syncthreads();
    if (tid < 64 && lc[tid] > 0) base[tid] = atomicAdd(&gcursor[tid], lc[tid]);
    __syncthreads();
    if (ok){
        int slot = cellOff[k] + base[k] + r;
        entries[slot] = make_int4(d.src, e, __float_as_int(d.fx), __float_as_int(d.fy));
        e2s[e] = slot;
    }
}

// ------------------------------------------------------------ W fp32 -> bf16 (conv0 only)
__global__ void wcvt_k(const float* __restrict__ in, unsigned short* __restrict__ out, int n)
{
    int i = blockIdx.x * blockDim.x + threadIdx.x;
    if (i < n) out[i] = f2bf(in[i]);
}

// W [64][CIN][64] fp32 -> wt [64][64][CIN] fp16 (cout-major), one block per cell
template<int CIN>
__global__ __launch_bounds__(256)
void wtr_k(const float* __restrict__ Wsrc, _Float16* __restrict__ wt)
{
    constexpr int COUT = 64;
    __shared__ _Float16 T[COUT][CIN + 2];
    int cell = blockIdx.x;
    const float* s = Wsrc + (size_t)cell * CIN * COUT;
    for (int i = threadIdx.x; i < CIN*COUT; i += 256){
        int k = i / COUT, c = i - k*COUT;
        T[c][k] = (_Float16)s[i];
    }
    __syncthreads();
    _Float16* d = wt + (size_t)cell * COUT * CIN;
    for (int i = threadIdx.x; i < CIN*COUT; i += 256){
        int c = i / CIN, k = i - c*CIN;
        d[i] = T[c][k];
    }
}

// -------------------------------------------- MFMA cell-conv: 64 edges/block
// A = gathered fp16 x rows staged in LDS (14.6KB); B = fp16 W read directly
// from global (L2-resident). 4 waves; wave w owns couts [16w,16w+16).
// C layout: col=lane&15, row=(lane>>4)*4+reg.
template<int CIN>
__global__ __launch_bounds__(256)
void conv_mfma_k(const _Float16* __restrict__ xh,        // [NFL][CIN]
                 const int4* __restrict__ entries,
                 const int* __restrict__ cellOff,
                 const _Float16* __restrict__ wt,        // [64][64][CIN]
                 _Float16* __restrict__ msg)             // [slot][64]
{
    constexpr int COUT = 64;
    constexpr int XROW = CIN*2 + 16;       // bytes: 208 (96) / 144 (64) -> odd*16
    constexpr int C16  = CIN*2/16;         // 16B chunks per row: 12 / 8

    __shared__ unsigned char XL[64 * XROW];
    __shared__ float BW[4][64];
    __shared__ int   SRC[64];

    int total = cellOff[NCC];
    int p0 = blockIdx.x * 64;
    if (p0 >= total) return;
    int tid = threadIdx.x;

    int lo_ = 0, hi_ = NCC;
    while (hi_ - lo_ > 1){ int mid = (lo_ + hi_) >> 1; if (cellOff[mid] <= p0) lo_ = mid; else hi_ = mid; }
    const int cell = lo_;
    const int kc[4] = { cell, cell+1, cell+8, cell+9 };

    if (tid < 64){
        int4 en = entries[p0 + tid];
        bool ok = en.y >= 0;
        float fx = __int_as_float(en.z), fy = __int_as_float(en.w);
        BW[0][tid] = ok ? (1.f-fx)*(1.f-fy) : 0.f;
        BW[1][tid] = ok ? (1.f-fx)*fy       : 0.f;
        BW[2][tid] = ok ? fx*(1.f-fy)       : 0.f;
        BW[3][tid] = ok ? fx*fy             : 0.f;
        SRC[tid] = en.x;
    }
    __syncthreads();
    for (int i = tid; i < 64*C16; i += 256){
        int e = i / C16, c = i - e*C16;
        const uint4* sp = (const uint4*)(xh + (size_t)SRC[e]*CIN) + c;
        *(uint4*)(&XL[e*XROW + 16*c]) = *sp;
    }
    __syncthreads();

    const int lane = tid & 63, wv = tid >> 6;
    const int lr = lane & 15, lg = lane >> 4;
    const int cb = wv * 16;

    const _Float16* wbase = wt + (size_t)(cb + lr) * CIN + lg * 8;

    f32x4 acc[4][4];   // [corner][edge-group]
#pragma unroll
    for (int cr = 0; cr < 4; ++cr)
#pragma unroll
        for (int ae = 0; ae < 4; ++ae)
            acc[cr][ae] = (f32x4)0.f;

#pragma unroll
    for (int k0 = 0; k0 < CIN; k0 += 32){
        half8 b[4], a[4];
#pragma unroll
        for (int cr = 0; cr < 4; ++cr)
            b[cr] = *(const half8*)(wbase + (size_t)kc[cr]*(COUT*CIN) + k0);
#pragma unroll
        for (int ae = 0; ae < 4; ++ae)
            a[ae] = *(const half8*)(XL + (16*ae + lr)*XROW + k0*2 + lg*16);
#pragma unroll
        for (int cr = 0; cr < 4; ++cr)
#pragma unroll
            for (int ae = 0; ae < 4; ++ae)
                acc[cr][ae] = __builtin_amdgcn_mfma_f32_16x16x32_f16(a[ae], b[cr], acc[cr][ae], 0, 0, 0);
    }

#pragma unroll
    for (int ae = 0; ae < 4; ++ae){
#pragma unroll
        for (int r = 0; r < 4; ++r){
            int E = 16*ae + lg*4 + r;
            float v = BW[0][E]*acc[0][ae][r] + BW[1][E]*acc[1][ae][r]
                    + BW[2][E]*acc[2][ae][r] + BW[3][E]*acc[3][ae][r];
            msg[(size_t)(p0 + E)*COUT + cb + lr] = (_Float16)v;
        }
    }
}

// -------------------------- fp32 cell-conv (conv0: CIN=8, COUT=32), fp16 msg
template<int CIN, int COUT, int TILE_E, bool RELU>
__global__ __launch_bounds__(128)
void conv_cell_k(const float* __restrict__ x,
                 const int4* __restrict__ entries,
                 const int* __restrict__ cellOff,
                 const unsigned short* __restrict__ Wbf,
                 _Float16* __restrict__ msg)             // [slot][COUT]
{
    constexpr int TEP = TILE_E + 4;
    constexpr int EG  = TILE_E / 4;
    constexpr int CG  = COUT / 8;
    static_assert(EG * CG == 128, "tile/thread mismatch");
    constexpr int C4  = CIN / 4;

    __shared__ float XT[CIN][TEP];
    __shared__ unsigned short WLc[4][CIN][COUT];
    __shared__ int4 EN[TILE_E];

    int total = cellOff[NCC];
    int p0 = blockIdx.x * TILE_E;
    if (p0 >= total) return;
    int tid = threadIdx.x;

    int lo = 0, hi = NCC;
    while (hi - lo > 1){ int mid = (lo + hi) >> 1; if (cellOff[mid] <= p0) lo = mid; else hi = mid; }
    const int cell = lo;

    for (int i = tid; i < TILE_E; i += 128) EN[i] = entries[p0 + i];

    const int kc[4] = { cell, cell + 1, cell + 8, cell + 9 };
#pragma unroll
    for (int c = 0; c < 4; ++c){
        const uint4* s = (const uint4*)(Wbf + (size_t)kc[c] * (CIN * COUT));
        uint4* dlds = (uint4*)(&WLc[c][0][0]);
        for (int i = tid; i < CIN * COUT / 8; i += 128) dlds[i] = s[i];
    }
    __syncthreads();

    for (int i = tid; i < TILE_E * C4; i += 128){
        int e  = i / C4;
        int c4 = i - e * C4;
        int4 en = EN[e];
        float4 v = make_float4(0.f, 0.f, 0.f, 0.f);
        if (en.y >= 0){
            v = *(const float4*)(x + (size_t)en.x * CIN + 4 * c4);
            if (RELU){ v.x = frelu(v.x); v.y = frelu(v.y); v.z = frelu(v.z); v.w = frelu(v.w); }
        }
        XT[4*c4+0][e] = v.x;
        XT[4*c4+1][e] = v.y;
        XT[4*c4+2][e] = v.z;
        XT[4*c4+3][e] = v.w;
    }
    __syncthreads();

    const int egrp = tid % EG;
    const int cgrp = tid / EG;
    const int e0 = egrp * 4;

    float fx[4], fy[4];
#pragma unroll
    for (int j = 0; j < 4; ++j){
        int4 en = EN[e0 + j];
        fx[j] = __int_as_float(en.z);
        fy[j] = __int_as_float(en.w);
    }

    float accT[4][8];
#pragma unroll
    for (int j = 0; j < 4; ++j)
#pragma unroll
        for (int c = 0; c < 8; ++c) accT[j][c] = 0.f;

#pragma unroll
    for (int cr = 0; cr < 4; ++cr){
        float accC[4][8];
#pragma unroll
        for (int j = 0; j < 4; ++j)
#pragma unroll
            for (int c = 0; c < 8; ++c) accC[j][c] = 0.f;

#pragma unroll
        for (int ci = 0; ci < CIN; ++ci){
            float4 xv = *(const float4*)&XT[ci][e0];
            uint4 wp = *(const uint4*)&WLc[cr][ci][cgrp * 8];
            float wf0 = __uint_as_float(wp.x << 16);
            float wf1 = __uint_as_float(wp.x & 0xFFFF0000u);
            float wf2 = __uint_as_float(wp.y << 16);
            float wf3 = __uint_as_float(wp.y & 0xFFFF0000u);
            float wf4 = __uint_as_float(wp.z << 16);
            float wf5 = __uint_as_float(wp.z & 0xFFFF0000u);
            float wf6 = __uint_as_float(wp.w << 16);
            float wf7 = __uint_as_float(wp.w & 0xFFFF0000u);
            const float xe[4] = { xv.x, xv.y, xv.z, xv.w };
#pragma unroll
            for (int j = 0; j < 4; ++j){
                accC[j][0] += xe[j] * wf0;
                accC[j][1] += xe[j] * wf1;
                accC[j][2] += xe[j] * wf2;
                accC[j][3] += xe[j] * wf3;
                accC[j][4] += xe[j] * wf4;
                accC[j][5] += xe[j] * wf5;
                accC[j][6] += xe[j] * wf6;
                accC[j][7] += xe[j] * wf7;
            }
        }
#pragma unroll
        for (int j = 0; j < 4; ++j){
            float wc = (cr == 0) ? (1.f - fx[j]) * (1.f - fy[j]) :
                       (cr == 1) ? (1.f - fx[j]) * fy[j] :
                       (cr == 2) ? fx[j] * (1.f - fy[j]) :
                                   fx[j] * fy[j];
#pragma unroll
            for (int c = 0; c < 8; ++c) accT[j][c] += wc * accC[j][c];
        }
    }

#pragma unroll
    for (int j = 0; j < 4; ++j){
        half8 hv;
#pragma unroll
        for (int c = 0; c < 8; ++c) hv[c] = (_Float16)accT[j][c];
        *(half8*)(msg + (size_t)(p0 + e0 + j) * COUT + cgrp * 8) = hv;
    }
}

// --------------------------- final conv (64->2): thread-per-edge, fp16 x rows
__global__ __launch_bounds__(128)
void conv2_msg_k(const _Float16* __restrict__ xh,        // xb2 = relu(y2) fp16 [NFL][64]
                 const int4* __restrict__ entries,
                 const int* __restrict__ cellOff,
                 const float* __restrict__ Wc,
                 float* __restrict__ msg2)
{
    __shared__ float WLf[4][64][2];
    int total = cellOff[NCC];
    int p0 = blockIdx.x * 128;
    if (p0 >= total) return;
    int tid = threadIdx.x;

    int lo = 0, hi = NCC;
    while (hi - lo > 1){ int mid = (lo + hi) >> 1; if (cellOff[mid] <= p0) lo = mid; else hi = mid; }
    const int cell = lo;
    const int kc[4] = { cell, cell + 1, cell + 8, cell + 9 };
#pragma unroll
    for (int c = 0; c < 4; ++c)
        ((float*)&WLf[c][0][0])[tid] = Wc[(size_t)kc[c] * 128 + tid];
    __syncthreads();

    int4 en = entries[p0 + tid];
    if (en.y < 0) return;
    float fx = __int_as_float(en.z), fy = __int_as_float(en.w);
    const _Float16* xp = xh + (size_t)en.x * 64;

    float a[4][2] = {{0.f,0.f},{0.f,0.f},{0.f,0.f},{0.f,0.f}};
#pragma unroll
    for (int ci = 0; ci < 64; ci += 8){
        half8 v = *(const half8*)(xp + ci);
#pragma unroll
        for (int j = 0; j < 8; ++j){
            float xe = (float)v[j];
#pragma unroll
            for (int cr = 0; cr < 4; ++cr){
                a[cr][0] += xe * WLf[cr][ci+j][0];
                a[cr][1] += xe * WLf[cr][ci+j][1];
            }
        }
    }
    float w0 = (1.f-fx)*(1.f-fy), w1 = (1.f-fx)*fy, w2 = fx*(1.f-fy), w3 = fx*fy;
    float m0 = w0*a[0][0] + w1*a[1][0] + w2*a[2][0] + w3*a[3][0];
    float m1 = w0*a[0][1] + w1*a[1][1] + w2*a[2][1] + w3*a[3][1];
    *(float2*)(msg2 + (size_t)(p0 + tid) * 2) = make_float2(m0, m1);
}

// --------------------------- final combine: thread-per-target, out = .../128
__global__ __launch_bounds__(256)
void final_combine_k(const float* __restrict__ y2,
                     const float* __restrict__ Wl3, const float* __restrict__ bl3,
                     const float* __restrict__ bc4,
                     const float* __restrict__ msg2,
                     const int* __restrict__ e2s,
                     const int* __restrict__ rowptr,
                     float* __restrict__ out)
{
    __shared__ float WS[128];
    int tid = threadIdx.x;
    if (tid < 128) WS[tid] = Wl3[tid];
    __syncthreads();

    int t = blockIdx.x * blockDim.x + tid;
    if (t >= NFL) return;
    int eb = rowptr[t], ee = rowptr[t+1];

    float a0 = bc4[0] + bl3[0];
    float a1 = bc4[1] + bl3[1];
    const float* pr = y2 + (size_t)t * 64;
#pragma unroll 4
    for (int ci = 0; ci < 64; ci += 4){
        float4 v = *(const float4*)(pr + ci);
        float xe[4] = { frelu(v.x), frelu(v.y), frelu(v.z), frelu(v.w) };
#pragma unroll
        for (int j = 0; j < 4; ++j){
            a0 += xe[j] * WS[(ci+j)*2];
            a1 += xe[j] * WS[(ci+j)*2 + 1];
        }
    }
    for (int e = eb; e < ee; ++e){
        int slot = e2s[e];
        float2 m = *(const float2*)(msg2 + (size_t)slot * 2);
        a0 += m.x; a1 += m.y;
    }
    out[(size_t)t*2]     = a0 * (1.0f/128.0f);
    out[(size_t)t*2 + 1] = a1 * (1.0f/128.0f);
}

// ---------------- combine0: lin + conv0-msg-sum + FUSED bconv; emits ansA + xbA
__global__ __launch_bounds__(256)
void combine0_k(const float* __restrict__ feat,
                const float* __restrict__ bnd_feat,
                const float* __restrict__ Wl0, const float* __restrict__ bl0,
                const float* __restrict__ bc0,
                const float* __restrict__ Wc1, const float* __restrict__ bc1,
                const EdgeData* __restrict__ edB,
                const int* __restrict__ rowptrB,
                const _Float16* __restrict__ msg,        // [slot][32]
                const int* __restrict__ e2s,
                const int* __restrict__ rowptrF,
                float* __restrict__ ansA,
                _Float16* __restrict__ xbA)              // [NFL][96] relu fp16
{
    int t = blockIdx.x * (blockDim.x >> 6) + (threadIdx.x >> 6);
    if (t >= NFL) return;
    int lane = threadIdx.x & 63;

    if (lane < 32){
        // lin (col = lane)
        float a = bl0[lane];
#pragma unroll
        for (int ci = 0; ci < 8; ++ci)
            a += feat[t*8 + ci] * Wl0[ci*32 + lane];
        ansA[(size_t)t*96 + lane] = a;
        xbA[(size_t)t*96 + lane]  = (_Float16)frelu(a);

        // bconv (col = 64 + lane)
        float b = bc1[lane];
        int eb = rowptrB[t], ee = rowptrB[t+1];
        for (int e = eb; e < ee; ++e){
            EdgeData d = edB[e];
            const float* xp = bnd_feat + (size_t)d.src * 8;
            const float* wp = Wc1 + (size_t)d.ixiy * 256 + lane;
            float t00 = 0.f, t01 = 0.f, t10 = 0.f, t11 = 0.f;
#pragma unroll
            for (int ci = 0; ci < 8; ++ci){
                float xv = xp[ci];
                t00 += xv * wp[ci*32];
                t01 += xv * wp[ci*32 + 256];
                t10 += xv * wp[ci*32 + 2048];
                t11 += xv * wp[ci*32 + 2304];
            }
            float wx1 = d.fx, wy1 = d.fy;
            float wx0 = 1.f - wx1, wy0 = 1.f - wy1;
            b += (wx0*wy0)*t00 + (wx0*wy1)*t01 + (wx1*wy0)*t10 + (wx1*wy1)*t11;
        }
        ansA[(size_t)t*96 + 64 + lane] = b;
        xbA[(size_t)t*96 + 64 + lane]  = (_Float16)frelu(b);
    } else {
        int c = lane - 32;
        float a = bc0[c];
        int eb = rowptrF[t], ee = rowptrF[t+1];
        for (int e = eb; e < ee; ++e)
            a += (float)msg[(size_t)e2s[e]*32 + c];
        ansA[(size_t)t*96 + 32 + c] = a;
        xbA[(size_t)t*96 + 32 + c]  = (_Float16)frelu(a);
    }
}

// ------- combine: msg-sum + dns + bias (+resid); emits y fp32 + relu fp16 row
template<int CIN, bool RESID, bool WRITE_XB>
__global__ __launch_bounds__(256)
void combine12_k(const float* __restrict__ prev,
                 const float* __restrict__ Wl, const float* __restrict__ bl,
                 const float* __restrict__ bc,
                 const _Float16* __restrict__ msg,       // [slot][64]
                 const int* __restrict__ e2s,
                 const int* __restrict__ rowptr,
                 float* __restrict__ y,
                 _Float16* __restrict__ xbnext)          // [NFL][64]
{
    int t = blockIdx.x * (blockDim.x >> 6) + (threadIdx.x >> 6);
    if (t >= NFL) return;
    int lane = threadIdx.x & 63;
    int eb = rowptr[t], ee = rowptr[t+1];

    const float* pr = prev + (size_t)t * CIN;
    float acc = bc[lane] + bl[lane];
#pragma unroll 8
    for (int ci = 0; ci < CIN; ++ci)
        acc += frelu(pr[ci]) * Wl[ci*64 + lane];
    if (RESID) acc += pr[lane];

    for (int e = eb; e < ee; ++e)
        acc += (float)msg[(size_t)e2s[e]*64 + lane];
    y[(size_t)t*64 + lane] = acc;

    if (WRITE_XB)
        xbnext[(size_t)t*64 + lane] = (_Float16)frelu(acc);
}

// ---------------------------------------------------------------------------
extern "C" void kernel_launch(void* const* d_in, const int* in_sizes, int n_in,
                              void* d_out, int out_size, void* d_ws, size_t ws_size,
                              hipStream_t stream)
{
    const float* fluid_pos  = (const float*)d_in[0];
    const float* bnd_pos    = (const float*)d_in[1];
    const float* fluid_feat = (const float*)d_in[2];
    const float* bnd_feat   = (const float*)d_in[3];
    const int*   f_tgt      = (const int*)  d_in[4];
    const int*   f_src      = (const int*)  d_in[5];
    const int*   b_tgt      = (const int*)  d_in[6];
    const int*   b_src      = (const int*)  d_in[7];
    const float* Wc0 = (const float*)d_in[8];  const float* bc0 = (const float*)d_in[9];
    const float* Wc1 = (const float*)d_in[10]; const float* bc1 = (const float*)d_in[11];
    const float* Wc2 = (const float*)d_in[12]; const float* bc2 = (const float*)d_in[13];
    const float* Wc3 = (const float*)d_in[14]; const float* bc3 = (const float*)d_in[15];
    const float* Wc4 = (const float*)d_in[16]; const float* bc4 = (const float*)d_in[17];
    const float* Wl0 = (const float*)d_in[18]; const float* bl0 = (const float*)d_in[19];
    const float* Wl1 = (const float*)d_in[20]; const float* bl1 = (const float*)d_in[21];
    const float* Wl2 = (const float*)d_in[22]; const float* bl2 = (const float*)d_in[23];
    const float* Wl3 = (const float*)d_in[24]; const float* bl3 = (const float*)d_in[25];

    int nEf = in_sizes[4];
    int nEb = in_sizes[6];
    int entPadMax = nEf + NCC * PADQ;
    float support = (float)sqrt(16.0 / (M_PI * 16384.0));

    char* w = (char*)d_ws;
    auto alloc = [&](size_t bytes){ char* r = w; w += (bytes + 255) & ~(size_t)255; return r; };
    EdgeData* edF      = (EdgeData*)alloc((size_t)nEf * sizeof(EdgeData));
    EdgeData* edB      = (EdgeData*)alloc((size_t)nEb * sizeof(EdgeData));
    int*      cnt      = (int*)     alloc(64 * sizeof(int));
    int*      cellOff  = (int*)     alloc(64 * sizeof(int));
    int*      gcursor  = (int*)     alloc(64 * sizeof(int));
    int*      rowptrF  = (int*)     alloc((NFL+1) * sizeof(int));
    int*      rowptrB  = (int*)     alloc((NFL+1) * sizeof(int));
    int4*     entries  = (int4*)    alloc((size_t)entPadMax * sizeof(int4));
    int*      e2s      = (int*)     alloc((size_t)nEf * sizeof(int));
    unsigned short* wb0 = (unsigned short*)alloc((size_t)64*8*32 * 2);
    _Float16* wt2      = (_Float16*)alloc((size_t)64*64*96 * 2);  // [cell][cout][k]
    _Float16* wt3      = (_Float16*)alloc((size_t)64*64*64 * 2);
    _Float16* xbA      = (_Float16*)alloc((size_t)NFL*96 * 2);
    _Float16* xb1      = (_Float16*)alloc((size_t)NFL*64 * 2);
    _Float16* xb2      = (_Float16*)alloc((size_t)NFL*64 * 2);
    float*    ansA     = (float*)   alloc((size_t)NFL * 96 * sizeof(float));
    float*    y1       = (float*)   alloc((size_t)NFL * 64 * sizeof(float));
    float*    y2       = (float*)   alloc((size_t)NFL * 64 * sizeof(float));
    _Float16* msg      = (_Float16*)alloc((size_t)entPadMax * 64 * 2);
    float*    msg2     = (float*)   alloc((size_t)entPadMax * 2 * sizeof(float));

    // ---- edge prep + bucket build
    prep_edges_k<<<(nEf+255)/256, 256, 0, stream>>>(fluid_pos, fluid_pos, f_tgt, f_src, nEf, support, -1.f, edF);
    prep_edges_k<<<(nEb+255)/256, 256, 0, stream>>>(fluid_pos, bnd_pos,   b_tgt, b_src, nEb, support,  1.f, edB);
    rowptr_k<<<(NFL+1+255)/256, 256, 0, stream>>>(f_tgt, nEf, rowptrF);
    rowptr_k<<<(NFL+1+255)/256, 256, 0, stream>>>(b_tgt, nEb, rowptrB);
    zero64_k<<<1, 64, 0, stream>>>(cnt);
    hist_k<<<(nEf+255)/256, 256, 0, stream>>>(edF, nEf, cnt);
    scan_pad_k<<<1, 64, 0, stream>>>(cnt, cellOff, gcursor);
    fill_entries_k<<<(entPadMax+255)/256, 256, 0, stream>>>(entries, entPadMax);
    scatter_k<<<(nEf+255)/256, 256, 0, stream>>>(edF, nEf, cellOff, gcursor, entries, e2s);

    // ---- weight preprocessing
    wcvt_k<<<(64*8*32 +255)/256, 256, 0, stream>>>(Wc0, wb0, 64*8*32);
    wtr_k<96><<<64, 256, 0, stream>>>(Wc2, wt2);
    wtr_k<64><<<64, 256, 0, stream>>>(Wc3, wt3);

    int gridM   = (entPadMax + 63)  / 64;
    int grid128 = (entPadMax + 127) / 128;
    dim3 tgrid(NFL/4);

    // ---- input block: conv0 -> fp16 msg; combine0 fuses lin + msg-sum + bconv
    conv_cell_k<8,32,128,false><<<grid128, 128, 0, stream>>>(fluid_feat, entries, cellOff, wb0, msg);
    combine0_k<<<tgrid, 256, 0, stream>>>(fluid_feat, bnd_feat, Wl0, bl0, bc0,
                                          Wc1, bc1, edB, rowptrB,
                                          msg, e2s, rowptrF, ansA, xbA);

    // ---- block 1
    conv_mfma_k<96><<<gridM, 256, 0, stream>>>(xbA, entries, cellOff, wt2, msg);
    combine12_k<96,false,true><<<tgrid, 256, 0, stream>>>(ansA, Wl1, bl1, bc2, msg, e2s, rowptrF, y1, xb1);

    // ---- block 2
    conv_mfma_k<64><<<gridM, 256, 0, stream>>>(xb1, entries, cellOff, wt3, msg);
    combine12_k<64,true,true><<<tgrid, 256, 0, stream>>>(y1, Wl2, bl2, bc3, msg, e2s, rowptrF, y2, xb2);

    // ---- block 3 (final)
    conv2_msg_k<<<grid128, 128, 0, stream>>>(xb2, entries, cellOff, Wc4, msg2);
    final_combine_k<<<(NFL+255)/256, 256, 0, stream>>>(y2, Wl3, bl3, bc4, msg2, e2s, rowptrF, (float*)d_out);
}

// Round 8
// 293.121 us; speedup vs baseline: 20.1620x; 1.1151x over previous
//
#include <hip/hip_runtime.h>
#include <math.h>
#include <stdint.h>

#define NFL   16384
#define NCC   55      // base cells: ix,iy in 0..6 -> ixiy = ix*8+iy in 0..54
#define PADQ  128     // bucket pad quantum

struct EdgeData { int src; int ixiy; float fx; float fy; };

typedef _Float16 half8 __attribute__((ext_vector_type(8)));
typedef __attribute__((ext_vector_type(4))) float f32x4;

__device__ __forceinline__ float frelu(float x){ return x > 0.f ? x : 0.f; }
__device__ __forceinline__ unsigned short f2bf(float f){
    unsigned int u = __float_as_uint(f);
    unsigned int r = (u + 0x7FFFu + ((u >> 16) & 1u)) >> 16;   // RNE
    return (unsigned short)r;
}

// ---------------------------------------------------------------- prep edges
__global__ void prep_edges_k(const float* __restrict__ qpos,
                             const float* __restrict__ ppos,
                             const int* __restrict__ tgt,
                             const int* __restrict__ src,
                             int nE, float support, float sgn,
                             EdgeData* __restrict__ out)
{
    int e = blockIdx.x * blockDim.x + threadIdx.x;
    if (e >= nE) return;
    int t = tgt[e], s = src[e];
    float dx = sgn * (ppos[2*s]   - qpos[2*t])   / support;
    float dy = sgn * (ppos[2*s+1] - qpos[2*t+1]) / support;
    dx = fminf(1.f, fmaxf(-1.f, dx));
    dy = fminf(1.f, fmaxf(-1.f, dy));
    float r  = sqrtf(dx*dx + dy*dy + 1e-12f);
    float th = atan2f(dy, dx);
    float m0 = fminf(1.f, fmaxf(-1.f, 2.f*r - 1.f));
    float m1 = fminf(1.f, fmaxf(-1.f, th * 0.3183098861837907f));
    float u = (m0 + 1.f) * 3.5f;
    float v = (m1 + 1.f) * 3.5f;
    int ix = (int)u; if (ix > 6) ix = 6;
    int iy = (int)v; if (iy > 6) iy = 6;
    EdgeData ed;
    ed.src  = s;
    ed.ixiy = ix*8 + iy;
    ed.fx   = u - (float)ix;
    ed.fy   = v - (float)iy;
    out[e] = ed;
}

// ------------------------------------------------- rowptr for a sorted tgt[]
__global__ void rowptr_k(const int* __restrict__ tgt, int nE, int* __restrict__ rowptr)
{
    int t = blockIdx.x * blockDim.x + threadIdx.x;
    if (t > NFL) return;
    if (t == NFL){ rowptr[NFL] = nE; return; }
    int lo = 0, hi = nE;
    while (lo < hi){ int mid = (lo + hi) >> 1; if (tgt[mid] < t) lo = mid + 1; else hi = mid; }
    rowptr[t] = lo;
}

// ------------------------------------------------------------- bucket build
__global__ void zero64_k(int* __restrict__ a){ if (threadIdx.x < 64) a[threadIdx.x] = 0; }

__global__ void hist_k(const EdgeData* __restrict__ ed, int nE, int* __restrict__ cnt)
{
    __shared__ int lc[64];
    int tid = threadIdx.x;
    if (tid < 64) lc[tid] = 0;
    __syncthreads();
    int e = blockIdx.x * blockDim.x + tid;
    if (e < nE) atomicAdd(&lc[ed[e].ixiy], 1);
    __syncthreads();
    if (tid < 64 && lc[tid] > 0) atomicAdd(&cnt[tid], lc[tid]);
}

__global__ void scan_pad_k(const int* __restrict__ cnt, int* __restrict__ cellOff,
                           int* __restrict__ gcursor)
{
    if (threadIdx.x < 64) gcursor[threadIdx.x] = 0;
    if (threadIdx.x == 0){
        int s = 0;
        for (int k = 0; k < NCC; ++k){
            cellOff[k] = s;
            s += ((cnt[k] + PADQ - 1) / PADQ) * PADQ;
        }
        cellOff[NCC] = s;
    }
}

__global__ void fill_entries_k(int4* __restrict__ entries, int n)
{
    int i = blockIdx.x * blockDim.x + threadIdx.x;
    if (i < n) entries[i] = make_int4(0, -1, 0, 0);
}

__global__ void scatter_k(const EdgeData* __restrict__ ed, int nE,
                          const int* __restrict__ cellOff,
                          int* __restrict__ gcursor,
                          int4* __restrict__ entries)
{
    __shared__ int lc[64], base[64];
    int tid = threadIdx.x;
    if (tid < 64) lc[tid] = 0;
    __syncthreads();
    int e = blockIdx.x * blockDim.x + tid;
    bool ok = e < nE;
    EdgeData d; int k = 0, r = 0;
    if (ok){ d = ed[e]; k = d.ixiy; r = atomicAdd(&lc[k], 1); }
    __syncthreads();
    if (tid < 64 && lc[tid] > 0) base[tid] = atomicAdd(&gcursor[tid], lc[tid]);
    __syncthreads();
    if (ok){
        int slot = cellOff[k] + base[k] + r;
        entries[slot] = make_int4(d.src, e, __float_as_int(d.fx), __float_as_int(d.fy));
    }
}

// ------------------------------------------------------------ W fp32 -> bf16 (conv0 only)
__global__ void wcvt_k(const float* __restrict__ in, unsigned short* __restrict__ out, int n)
{
    int i = blockIdx.x * blockDim.x + threadIdx.x;
    if (i < n) out[i] = f2bf(in[i]);
}

// W [64][CIN][64] fp32 -> wt [64][64][CIN] fp16 (cout-major), one block per cell
template<int CIN>
__global__ __launch_bounds__(256)
void wtr_k(const float* __restrict__ Wsrc, _Float16* __restrict__ wt)
{
    constexpr int COUT = 64;
    __shared__ _Float16 T[COUT][CIN + 2];
    int cell = blockIdx.x;
    const float* s = Wsrc + (size_t)cell * CIN * COUT;
    for (int i = threadIdx.x; i < CIN*COUT; i += 256){
        int k = i / COUT, c = i - k*COUT;
        T[c][k] = (_Float16)s[i];
    }
    __syncthreads();
    _Float16* d = wt + (size_t)cell * COUT * CIN;
    for (int i = threadIdx.x; i < CIN*COUT; i += 256){
        int c = i / CIN, k = i - c*CIN;
        d[i] = T[c][k];
    }
}

// -------------------------------------------- MFMA cell-conv: 64 edges/block
// Messages stored EDGE-ORDERED (msg[edge_id]) so combine reads are sequential.
template<int CIN>
__global__ __launch_bounds__(256)
void conv_mfma_k(const _Float16* __restrict__ xh,        // [NFL][CIN]
                 const int4* __restrict__ entries,
                 const int* __restrict__ cellOff,
                 const _Float16* __restrict__ wt,        // [64][64][CIN]
                 _Float16* __restrict__ msg)             // [edge][64]
{
    constexpr int COUT = 64;
    constexpr int XROW = CIN*2 + 16;       // bytes: 208 (96) / 144 (64)
    constexpr int C16  = CIN*2/16;

    __shared__ unsigned char XL[64 * XROW];
    __shared__ float BW[4][64];
    __shared__ int   SRC[64];
    __shared__ int   EID[64];

    int total = cellOff[NCC];
    int p0 = blockIdx.x * 64;
    if (p0 >= total) return;
    int tid = threadIdx.x;

    int lo_ = 0, hi_ = NCC;
    while (hi_ - lo_ > 1){ int mid = (lo_ + hi_) >> 1; if (cellOff[mid] <= p0) lo_ = mid; else hi_ = mid; }
    const int cell = lo_;
    const int kc[4] = { cell, cell+1, cell+8, cell+9 };

    if (tid < 64){
        int4 en = entries[p0 + tid];
        bool ok = en.y >= 0;
        float fx = __int_as_float(en.z), fy = __int_as_float(en.w);
        BW[0][tid] = ok ? (1.f-fx)*(1.f-fy) : 0.f;
        BW[1][tid] = ok ? (1.f-fx)*fy       : 0.f;
        BW[2][tid] = ok ? fx*(1.f-fy)       : 0.f;
        BW[3][tid] = ok ? fx*fy             : 0.f;
        SRC[tid] = en.x;
        EID[tid] = en.y;
    }
    __syncthreads();
    for (int i = tid; i < 64*C16; i += 256){
        int e = i / C16, c = i - e*C16;
        const uint4* sp = (const uint4*)(xh + (size_t)SRC[e]*CIN) + c;
        *(uint4*)(&XL[e*XROW + 16*c]) = *sp;
    }
    __syncthreads();

    const int lane = tid & 63, wv = tid >> 6;
    const int lr = lane & 15, lg = lane >> 4;
    const int cb = wv * 16;

    const _Float16* wbase = wt + (size_t)(cb + lr) * CIN + lg * 8;

    f32x4 acc[4][4];   // [corner][edge-group]
#pragma unroll
    for (int cr = 0; cr < 4; ++cr)
#pragma unroll
        for (int ae = 0; ae < 4; ++ae)
            acc[cr][ae] = (f32x4)0.f;

#pragma unroll
    for (int k0 = 0; k0 < CIN; k0 += 32){
        half8 b[4], a[4];
#pragma unroll
        for (int cr = 0; cr < 4; ++cr)
            b[cr] = *(const half8*)(wbase + (size_t)kc[cr]*(COUT*CIN) + k0);
#pragma unroll
        for (int ae = 0; ae < 4; ++ae)
            a[ae] = *(const half8*)(XL + (16*ae + lr)*XROW + k0*2 + lg*16);
#pragma unroll
        for (int cr = 0; cr < 4; ++cr)
#pragma unroll
            for (int ae = 0; ae < 4; ++ae)
                acc[cr][ae] = __builtin_amdgcn_mfma_f32_16x16x32_f16(a[ae], b[cr], acc[cr][ae], 0, 0, 0);
    }

#pragma unroll
    for (int ae = 0; ae < 4; ++ae){
#pragma unroll
        for (int r = 0; r < 4; ++r){
            int E = 16*ae + lg*4 + r;
            int eid = EID[E];
            if (eid >= 0){
                float v = BW[0][E]*acc[0][ae][r] + BW[1][E]*acc[1][ae][r]
                        + BW[2][E]*acc[2][ae][r] + BW[3][E]*acc[3][ae][r];
                msg[(size_t)eid*COUT + cb + lr] = (_Float16)v;
            }
        }
    }
}

// -------------------------- fp32 cell-conv (conv0: CIN=8, COUT=32), fp16 msg
template<int CIN, int COUT, int TILE_E, bool RELU>
__global__ __launch_bounds__(128)
void conv_cell_k(const float* __restrict__ x,
                 const int4* __restrict__ entries,
                 const int* __restrict__ cellOff,
                 const unsigned short* __restrict__ Wbf,
                 _Float16* __restrict__ msg)             // [edge][COUT]
{
    constexpr int TEP = TILE_E + 4;
    constexpr int EG  = TILE_E / 4;
    constexpr int CG  = COUT / 8;
    static_assert(EG * CG == 128, "tile/thread mismatch");
    constexpr int C4  = CIN / 4;

    __shared__ float XT[CIN][TEP];
    __shared__ unsigned short WLc[4][CIN][COUT];
    __shared__ int4 EN[TILE_E];

    int total = cellOff[NCC];
    int p0 = blockIdx.x * TILE_E;
    if (p0 >= total) return;
    int tid = threadIdx.x;

    int lo = 0, hi = NCC;
    while (hi - lo > 1){ int mid = (lo + hi) >> 1; if (cellOff[mid] <= p0) lo = mid; else hi = mid; }
    const int cell = lo;

    for (int i = tid; i < TILE_E; i += 128) EN[i] = entries[p0 + i];

    const int kc[4] = { cell, cell + 1, cell + 8, cell + 9 };
#pragma unroll
    for (int c = 0; c < 4; ++c){
        const uint4* s = (const uint4*)(Wbf + (size_t)kc[c] * (CIN * COUT));
        uint4* dlds = (uint4*)(&WLc[c][0][0]);
        for (int i = tid; i < CIN * COUT / 8; i += 128) dlds[i] = s[i];
    }
    __syncthreads();

    for (int i = tid; i < TILE_E * C4; i += 128){
        int e  = i / C4;
        int c4 = i - e * C4;
        int4 en = EN[e];
        float4 v = make_float4(0.f, 0.f, 0.f, 0.f);
        if (en.y >= 0){
            v = *(const float4*)(x + (size_t)en.x * CIN + 4 * c4);
            if (RELU){ v.x = frelu(v.x); v.y = frelu(v.y); v.z = frelu(v.z); v.w = frelu(v.w); }
        }
        XT[4*c4+0][e] = v.x;
        XT[4*c4+1][e] = v.y;
        XT[4*c4+2][e] = v.z;
        XT[4*c4+3][e] = v.w;
    }
    __syncthreads();

    const int egrp = tid % EG;
    const int cgrp = tid / EG;
    const int e0 = egrp * 4;

    float fx[4], fy[4];
    int eid[4];
#pragma unroll
    for (int j = 0; j < 4; ++j){
        int4 en = EN[e0 + j];
        fx[j] = __int_as_float(en.z);
        fy[j] = __int_as_float(en.w);
        eid[j] = en.y;
    }

    float accT[4][8];
#pragma unroll
    for (int j = 0; j < 4; ++j)
#pragma unroll
        for (int c = 0; c < 8; ++c) accT[j][c] = 0.f;

#pragma unroll
    for (int cr = 0; cr < 4; ++cr){
        float accC[4][8];
#pragma unroll
        for (int j = 0; j < 4; ++j)
#pragma unroll
            for (int c = 0; c < 8; ++c) accC[j][c] = 0.f;

#pragma unroll
        for (int ci = 0; ci < CIN; ++ci){
            float4 xv = *(const float4*)&XT[ci][e0];
            uint4 wp = *(const uint4*)&WLc[cr][ci][cgrp * 8];
            float wf0 = __uint_as_float(wp.x << 16);
            float wf1 = __uint_as_float(wp.x & 0xFFFF0000u);
            float wf2 = __uint_as_float(wp.y << 16);
            float wf3 = __uint_as_float(wp.y & 0xFFFF0000u);
            float wf4 = __uint_as_float(wp.z << 16);
            float wf5 = __uint_as_float(wp.z & 0xFFFF0000u);
            float wf6 = __uint_as_float(wp.w << 16);
            float wf7 = __uint_as_float(wp.w & 0xFFFF0000u);
            const float xe[4] = { xv.x, xv.y, xv.z, xv.w };
#pragma unroll
            for (int j = 0; j < 4; ++j){
                accC[j][0] += xe[j] * wf0;
                accC[j][1] += xe[j] * wf1;
                accC[j][2] += xe[j] * wf2;
                accC[j][3] += xe[j] * wf3;
                accC[j][4] += xe[j] * wf4;
                accC[j][5] += xe[j] * wf5;
                accC[j][6] += xe[j] * wf6;
                accC[j][7] += xe[j] * wf7;
            }
        }
#pragma unroll
        for (int j = 0; j < 4; ++j){
            float wc = (cr == 0) ? (1.f - fx[j]) * (1.f - fy[j]) :
                       (cr == 1) ? (1.f - fx[j]) * fy[j] :
                       (cr == 2) ? fx[j] * (1.f - fy[j]) :
                                   fx[j] * fy[j];
#pragma unroll
            for (int c = 0; c < 8; ++c) accT[j][c] += wc * accC[j][c];
        }
    }

#pragma unroll
    for (int j = 0; j < 4; ++j){
        if (eid[j] < 0) continue;
        half8 hv;
#pragma unroll
        for (int c = 0; c < 8; ++c) hv[c] = (_Float16)accT[j][c];
        *(half8*)(msg + (size_t)eid[j] * COUT + cgrp * 8) = hv;
    }
}

// --------------------------- final conv (64->2): thread-per-edge, fp16 x rows
__global__ __launch_bounds__(128)
void conv2_msg_k(const _Float16* __restrict__ xh,        // xb2 = relu(y2) fp16 [NFL][64]
                 const int4* __restrict__ entries,
                 const int* __restrict__ cellOff,
                 const float* __restrict__ Wc,
                 float* __restrict__ msg2)                // [edge][2]
{
    __shared__ float WLf[4][64][2];
    int total = cellOff[NCC];
    int p0 = blockIdx.x * 128;
    if (p0 >= total) return;
    int tid = threadIdx.x;

    int lo = 0, hi = NCC;
    while (hi - lo > 1){ int mid = (lo + hi) >> 1; if (cellOff[mid] <= p0) lo = mid; else hi = mid; }
    const int cell = lo;
    const int kc[4] = { cell, cell + 1, cell + 8, cell + 9 };
#pragma unroll
    for (int c = 0; c < 4; ++c)
        ((float*)&WLf[c][0][0])[tid] = Wc[(size_t)kc[c] * 128 + tid];
    __syncthreads();

    int4 en = entries[p0 + tid];
    if (en.y < 0) return;
    float fx = __int_as_float(en.z), fy = __int_as_float(en.w);
    const _Float16* xp = xh + (size_t)en.x * 64;

    float a[4][2] = {{0.f,0.f},{0.f,0.f},{0.f,0.f},{0.f,0.f}};
#pragma unroll
    for (int ci = 0; ci < 64; ci += 8){
        half8 v = *(const half8*)(xp + ci);
#pragma unroll
        for (int j = 0; j < 8; ++j){
            float xe = (float)v[j];
#pragma unroll
            for (int cr = 0; cr < 4; ++cr){
                a[cr][0] += xe * WLf[cr][ci+j][0];
                a[cr][1] += xe * WLf[cr][ci+j][1];
            }
        }
    }
    float w0 = (1.f-fx)*(1.f-fy), w1 = (1.f-fx)*fy, w2 = fx*(1.f-fy), w3 = fx*fy;
    float m0 = w0*a[0][0] + w1*a[1][0] + w2*a[2][0] + w3*a[3][0];
    float m1 = w0*a[0][1] + w1*a[1][1] + w2*a[2][1] + w3*a[3][1];
    *(float2*)(msg2 + (size_t)en.y * 2) = make_float2(m0, m1);
}

// --------------------------- final combine: thread-per-target, out = .../128
__global__ __launch_bounds__(256)
void final_combine_k(const float* __restrict__ y2,
                     const float* __restrict__ Wl3, const float* __restrict__ bl3,
                     const float* __restrict__ bc4,
                     const float* __restrict__ msg2,
                     const int* __restrict__ rowptr,
                     float* __restrict__ out)
{
    __shared__ float WS[128];
    int tid = threadIdx.x;
    if (tid < 128) WS[tid] = Wl3[tid];
    __syncthreads();

    int t = blockIdx.x * blockDim.x + tid;
    if (t >= NFL) return;
    int eb = rowptr[t], ee = rowptr[t+1];

    float a0 = bc4[0] + bl3[0];
    float a1 = bc4[1] + bl3[1];
    const float* pr = y2 + (size_t)t * 64;
#pragma unroll 4
    for (int ci = 0; ci < 64; ci += 4){
        float4 v = *(const float4*)(pr + ci);
        float xe[4] = { frelu(v.x), frelu(v.y), frelu(v.z), frelu(v.w) };
#pragma unroll
        for (int j = 0; j < 4; ++j){
            a0 += xe[j] * WS[(ci+j)*2];
            a1 += xe[j] * WS[(ci+j)*2 + 1];
        }
    }
    for (int e = eb; e < ee; ++e){
        float2 m = *(const float2*)(msg2 + (size_t)e * 2);
        a0 += m.x; a1 += m.y;
    }
    out[(size_t)t*2]     = a0 * (1.0f/128.0f);
    out[(size_t)t*2 + 1] = a1 * (1.0f/128.0f);
}

// ---------------- combine0: lin + conv0-msg-sum + FUSED bconv; emits ansA + xbA
__global__ __launch_bounds__(256)
void combine0_k(const float* __restrict__ feat,
                const float* __restrict__ bnd_feat,
                const float* __restrict__ Wl0, const float* __restrict__ bl0,
                const float* __restrict__ bc0,
                const float* __restrict__ Wc1, const float* __restrict__ bc1,
                const EdgeData* __restrict__ edB,
                const int* __restrict__ rowptrB,
                const _Float16* __restrict__ msg,        // [edge][32]
                const int* __restrict__ rowptrF,
                float* __restrict__ ansA,
                _Float16* __restrict__ xbA)              // [NFL][96] relu fp16
{
    int t = blockIdx.x * (blockDim.x >> 6) + (threadIdx.x >> 6);
    if (t >= NFL) return;
    int lane = threadIdx.x & 63;

    if (lane < 32){
        float a = bl0[lane];
#pragma unroll
        for (int ci = 0; ci < 8; ++ci)
            a += feat[t*8 + ci] * Wl0[ci*32 + lane];
        ansA[(size_t)t*96 + lane] = a;
        xbA[(size_t)t*96 + lane]  = (_Float16)frelu(a);

        float b = bc1[lane];
        int eb = rowptrB[t], ee = rowptrB[t+1];
        for (int e = eb; e < ee; ++e){
            EdgeData d = edB[e];
            const float* xp = bnd_feat + (size_t)d.src * 8;
            const float* wp = Wc1 + (size_t)d.ixiy * 256 + lane;
            float t00 = 0.f, t01 = 0.f, t10 = 0.f, t11 = 0.f;
#pragma unroll
            for (int ci = 0; ci < 8; ++ci){
                float xv = xp[ci];
                t00 += xv * wp[ci*32];
                t01 += xv * wp[ci*32 + 256];
                t10 += xv * wp[ci*32 + 2048];
                t11 += xv * wp[ci*32 + 2304];
            }
            float wx1 = d.fx, wy1 = d.fy;
            float wx0 = 1.f - wx1, wy0 = 1.f - wy1;
            b += (wx0*wy0)*t00 + (wx0*wy1)*t01 + (wx1*wy0)*t10 + (wx1*wy1)*t11;
        }
        ansA[(size_t)t*96 + 64 + lane] = b;
        xbA[(size_t)t*96 + 64 + lane]  = (_Float16)frelu(b);
    } else {
        int c = lane - 32;
        float a = bc0[c];
        int eb = rowptrF[t], ee = rowptrF[t+1];
        for (int e = eb; e < ee; ++e)
            a += (float)msg[(size_t)e*32 + c];
        ansA[(size_t)t*96 + 32 + c] = a;
        xbA[(size_t)t*96 + 32 + c]  = (_Float16)frelu(a);
    }
}

// ------- combine: msg-sum + dns + bias (+resid); emits y fp32 + relu fp16 row
template<int CIN, bool RESID, bool WRITE_XB>
__global__ __launch_bounds__(256)
void combine12_k(const float* __restrict__ prev,
                 const float* __restrict__ Wl, const float* __restrict__ bl,
                 const float* __restrict__ bc,
                 const _Float16* __restrict__ msg,       // [edge][64]
                 const int* __restrict__ rowptr,
                 float* __restrict__ y,
                 _Float16* __restrict__ xbnext)          // [NFL][64]
{
    int t = blockIdx.x * (blockDim.x >> 6) + (threadIdx.x >> 6);
    if (t >= NFL) return;
    int lane = threadIdx.x & 63;
    int eb = rowptr[t], ee = rowptr[t+1];

    const float* pr = prev + (size_t)t * CIN;
    float acc = bc[lane] + bl[lane];
#pragma unroll 8
    for (int ci = 0; ci < CIN; ++ci)
        acc += frelu(pr[ci]) * Wl[ci*64 + lane];
    if (RESID) acc += pr[lane];

    for (int e = eb; e < ee; ++e)
        acc += (float)msg[(size_t)e*64 + lane];
    y[(size_t)t*64 + lane] = acc;

    if (WRITE_XB)
        xbnext[(size_t)t*64 + lane] = (_Float16)frelu(acc);
}

// ---------------------------------------------------------------------------
extern "C" void kernel_launch(void* const* d_in, const int* in_sizes, int n_in,
                              void* d_out, int out_size, void* d_ws, size_t ws_size,
                              hipStream_t stream)
{
    const float* fluid_pos  = (const float*)d_in[0];
    const float* bnd_pos    = (const float*)d_in[1];
    const float* fluid_feat = (const float*)d_in[2];
    const float* bnd_feat   = (const float*)d_in[3];
    const int*   f_tgt      = (const int*)  d_in[4];
    const int*   f_src      = (const int*)  d_in[5];
    const int*   b_tgt      = (const int*)  d_in[6];
    const int*   b_src      = (const int*)  d_in[7];
    const float* Wc0 = (const float*)d_in[8];  const float* bc0 = (const float*)d_in[9];
    const float* Wc1 = (const float*)d_in[10]; const float* bc1 = (const float*)d_in[11];
    const float* Wc2 = (const float*)d_in[12]; const float* bc2 = (const float*)d_in[13];
    const float* Wc3 = (const float*)d_in[14]; const float* bc3 = (const float*)d_in[15];
    const float* Wc4 = (const float*)d_in[16]; const float* bc4 = (const float*)d_in[17];
    const float* Wl0 = (const float*)d_in[18]; const float* bl0 = (const float*)d_in[19];
    const float* Wl1 = (const float*)d_in[20]; const float* bl1 = (const float*)d_in[21];
    const float* Wl2 = (const float*)d_in[22]; const float* bl2 = (const float*)d_in[23];
    const float* Wl3 = (const float*)d_in[24]; const float* bl3 = (const float*)d_in[25];

    int nEf = in_sizes[4];
    int nEb = in_sizes[6];
    int entPadMax = nEf + NCC * PADQ;
    float support = (float)sqrt(16.0 / (M_PI * 16384.0));

    char* w = (char*)d_ws;
    auto alloc = [&](size_t bytes){ char* r = w; w += (bytes + 255) & ~(size_t)255; return r; };
    EdgeData* edF      = (EdgeData*)alloc((size_t)nEf * sizeof(EdgeData));
    EdgeData* edB      = (EdgeData*)alloc((size_t)nEb * sizeof(EdgeData));
    int*      cnt      = (int*)     alloc(64 * sizeof(int));
    int*      cellOff  = (int*)     alloc(64 * sizeof(int));
    int*      gcursor  = (int*)     alloc(64 * sizeof(int));
    int*      rowptrF  = (int*)     alloc((NFL+1) * sizeof(int));
    int*      rowptrB  = (int*)     alloc((NFL+1) * sizeof(int));
    int4*     entries  = (int4*)    alloc((size_t)entPadMax * sizeof(int4));
    unsigned short* wb0 = (unsigned short*)alloc((size_t)64*8*32 * 2);
    _Float16* wt2      = (_Float16*)alloc((size_t)64*64*96 * 2);  // [cell][cout][k]
    _Float16* wt3      = (_Float16*)alloc((size_t)64*64*64 * 2);
    _Float16* xbA      = (_Float16*)alloc((size_t)NFL*96 * 2);
    _Float16* xb1      = (_Float16*)alloc((size_t)NFL*64 * 2);
    _Float16* xb2      = (_Float16*)alloc((size_t)NFL*64 * 2);
    float*    ansA     = (float*)   alloc((size_t)NFL * 96 * sizeof(float));
    float*    y1       = (float*)   alloc((size_t)NFL * 64 * sizeof(float));
    float*    y2       = (float*)   alloc((size_t)NFL * 64 * sizeof(float));
    _Float16* msg      = (_Float16*)alloc((size_t)nEf * 64 * 2);
    float*    msg2     = (float*)   alloc((size_t)nEf * 2 * sizeof(float));

    // ---- edge prep + bucket build
    prep_edges_k<<<(nEf+255)/256, 256, 0, stream>>>(fluid_pos, fluid_pos, f_tgt, f_src, nEf, support, -1.f, edF);
    prep_edges_k<<<(nEb+255)/256, 256, 0, stream>>>(fluid_pos, bnd_pos,   b_tgt, b_src, nEb, support,  1.f, edB);
    rowptr_k<<<(NFL+1+255)/256, 256, 0, stream>>>(f_tgt, nEf, rowptrF);
    rowptr_k<<<(NFL+1+255)/256, 256, 0, stream>>>(b_tgt, nEb, rowptrB);
    zero64_k<<<1, 64, 0, stream>>>(cnt);
    hist_k<<<(nEf+255)/256, 256, 0, stream>>>(edF, nEf, cnt);
    scan_pad_k<<<1, 64, 0, stream>>>(cnt, cellOff, gcursor);
    fill_entries_k<<<(entPadMax+255)/256, 256, 0, stream>>>(entries, entPadMax);
    scatter_k<<<(nEf+255)/256, 256, 0, stream>>>(edF, nEf, cellOff, gcursor, entries);

    // ---- weight preprocessing
    wcvt_k<<<(64*8*32 +255)/256, 256, 0, stream>>>(Wc0, wb0, 64*8*32);
    wtr_k<96><<<64, 256, 0, stream>>>(Wc2, wt2);
    wtr_k<64><<<64, 256, 0, stream>>>(Wc3, wt3);

    int gridM   = (entPadMax + 63)  / 64;
    int grid128 = (entPadMax + 127) / 128;
    dim3 tgrid(NFL/4);

    // ---- input block
    conv_cell_k<8,32,128,false><<<grid128, 128, 0, stream>>>(fluid_feat, entries, cellOff, wb0, msg);
    combine0_k<<<tgrid, 256, 0, stream>>>(fluid_feat, bnd_feat, Wl0, bl0, bc0,
                                          Wc1, bc1, edB, rowptrB,
                                          msg, rowptrF, ansA, xbA);

    // ---- block 1
    conv_mfma_k<96><<<gridM, 256, 0, stream>>>(xbA, entries, cellOff, wt2, msg);
    combine12_k<96,false,true><<<tgrid, 256, 0, stream>>>(ansA, Wl1, bl1, bc2, msg, rowptrF, y1, xb1);

    // ---- block 2
    conv_mfma_k<64><<<gridM, 256, 0, stream>>>(xb1, entries, cellOff, wt3, msg);
    combine12_k<64,true,true><<<tgrid, 256, 0, stream>>>(y1, Wl2, bl2, bc3, msg, rowptrF, y2, xb2);

    // ---- block 3 (final)
    conv2_msg_k<<<grid128, 128, 0, stream>>>(xb2, entries, cellOff, Wc4, msg2);
    final_combine_k<<<(NFL+255)/256, 256, 0, stream>>>(y2, Wl3, bl3, bc4, msg2, rowptrF, (float*)d_out);
}

// Round 9
// 283.028 us; speedup vs baseline: 20.8810x; 1.0357x over previous
//
#include <hip/hip_runtime.h>
#include <math.h>
#include <stdint.h>

#define NFL   16384
#define NCC   55      // base cells: ix,iy in 0..6 -> ixiy = ix*8+iy in 0..54
#define PADQ  128     // bucket pad quantum (=2 conv chunks)

struct EdgeData { int src; int ixiy; float fx; float fy; };

typedef _Float16 half8 __attribute__((ext_vector_type(8)));
typedef __attribute__((ext_vector_type(4))) float f32x4;

__device__ __forceinline__ float frelu(float x){ return x > 0.f ? x : 0.f; }
__device__ __forceinline__ unsigned short f2bf(float f){
    unsigned int u = __float_as_uint(f);
    unsigned int r = (u + 0x7FFFu + ((u >> 16) & 1u)) >> 16;   // RNE
    return (unsigned short)r;
}

__device__ __forceinline__ EdgeData make_edge(const float* qpos, const float* ppos,
                                              int t, int s, float support, float sgn)
{
    float dx = sgn * (ppos[2*s]   - qpos[2*t])   / support;
    float dy = sgn * (ppos[2*s+1] - qpos[2*t+1]) / support;
    dx = fminf(1.f, fmaxf(-1.f, dx));
    dy = fminf(1.f, fmaxf(-1.f, dy));
    float r  = sqrtf(dx*dx + dy*dy + 1e-12f);
    float th = atan2f(dy, dx);
    float m0 = fminf(1.f, fmaxf(-1.f, 2.f*r - 1.f));
    float m1 = fminf(1.f, fmaxf(-1.f, th * 0.3183098861837907f));
    float u = (m0 + 1.f) * 3.5f;
    float v = (m1 + 1.f) * 3.5f;
    int ix = (int)u; if (ix > 6) ix = 6;
    int iy = (int)v; if (iy > 6) iy = 6;
    EdgeData ed;
    ed.src  = s;
    ed.ixiy = ix*8 + iy;
    ed.fx   = u - (float)ix;
    ed.fy   = v - (float)iy;
    return ed;
}

// ---------------- fused setup: edge prep (F+B) + cell hist + rowptrs --------
__global__ __launch_bounds__(256)
void setup_k(const float* __restrict__ fluid_pos, const float* __restrict__ bnd_pos,
             const int* __restrict__ f_tgt, const int* __restrict__ f_src, int nEf,
             const int* __restrict__ b_tgt, const int* __restrict__ b_src, int nEb,
             float support,
             EdgeData* __restrict__ edF, EdgeData* __restrict__ edB,
             int* __restrict__ cnt,                // pre-zeroed via memset
             int* __restrict__ rowptrF, int* __restrict__ rowptrB,
             int nA, int nB, int nC)
{
    int b = blockIdx.x, tid = threadIdx.x;
    if (b < nA){
        __shared__ int lc[64];
        if (tid < 64) lc[tid] = 0;
        __syncthreads();
        int e = b*256 + tid;
        if (e < nEf){
            EdgeData d = make_edge(fluid_pos, fluid_pos, f_tgt[e], f_src[e], support, -1.f);
            edF[e] = d;
            atomicAdd(&lc[d.ixiy], 1);
        }
        __syncthreads();
        if (tid < 64 && lc[tid] > 0) atomicAdd(&cnt[tid], lc[tid]);
    } else if (b < nA + nB){
        int e = (b - nA)*256 + tid;
        if (e < nEb)
            edB[e] = make_edge(fluid_pos, bnd_pos, b_tgt[e], b_src[e], support, 1.f);
    } else if (b < nA + nB + nC){
        int t = (b - nA - nB)*256 + tid;
        if (t > NFL) return;
        if (t == NFL){ rowptrF[NFL] = nEf; return; }
        int lo = 0, hi = nEf;
        while (lo < hi){ int mid = (lo + hi) >> 1; if (f_tgt[mid] < t) lo = mid + 1; else hi = mid; }
        rowptrF[t] = lo;
    } else {
        int t = (b - nA - nB - nC)*256 + tid;
        if (t > NFL) return;
        if (t == NFL){ rowptrB[NFL] = nEb; return; }
        int lo = 0, hi = nEb;
        while (lo < hi){ int mid = (lo + hi) >> 1; if (b_tgt[mid] < t) lo = mid + 1; else hi = mid; }
        rowptrB[t] = lo;
    }
}

// -------- scan + cursor init + pad-slot fill (only the <=7k padding entries)
__global__ __launch_bounds__(256)
void scan_pad_k(const int* __restrict__ cnt, int* __restrict__ cellOff,
                int* __restrict__ gcursor, int4* __restrict__ entries)
{
    __shared__ int offS[NCC+1], cntS[NCC];
    int tid = threadIdx.x;
    if (tid < 64) gcursor[tid] = 0;
    if (tid == 0){
        int s = 0;
        for (int k = 0; k < NCC; ++k){
            offS[k] = s; int c = cnt[k]; cntS[k] = c;
            s += ((c + PADQ - 1) / PADQ) * PADQ;
        }
        offS[NCC] = s;
        for (int k = 0; k <= NCC; ++k) cellOff[k] = offS[k];
    }
    __syncthreads();
    for (int k = 0; k < NCC; ++k){
        int base = offS[k] + cntS[k];
        int pads = (offS[k+1] - offS[k]) - cntS[k];
        for (int i = tid; i < pads; i += 256)
            entries[base + i] = make_int4(0, -1, 0, 0);
    }
}

__global__ void scatter_k(const EdgeData* __restrict__ ed, int nE,
                          const int* __restrict__ cellOff,
                          int* __restrict__ gcursor,
                          int4* __restrict__ entries)
{
    __shared__ int lc[64], base[64];
    int tid = threadIdx.x;
    if (tid < 64) lc[tid] = 0;
    __syncthreads();
    int e = blockIdx.x * blockDim.x + tid;
    bool ok = e < nE;
    EdgeData d; int k = 0, r = 0;
    if (ok){ d = ed[e]; k = d.ixiy; r = atomicAdd(&lc[k], 1); }
    __syncthreads();
    if (tid < 64 && lc[tid] > 0) base[tid] = atomicAdd(&gcursor[tid], lc[tid]);
    __syncthreads();
    if (ok){
        int slot = cellOff[k] + base[k] + r;
        entries[slot] = make_int4(d.src, e, __float_as_int(d.fx), __float_as_int(d.fy));
    }
}

// ---------------- fused weight prep: wt2 (96), wt3 (64) fp16 T; wb0 bf16 ----
__global__ __launch_bounds__(256)
void wprep_k(const float* __restrict__ Wc2, const float* __restrict__ Wc3,
             const float* __restrict__ Wc0,
             _Float16* __restrict__ wt2, _Float16* __restrict__ wt3,
             unsigned short* __restrict__ wb0)
{
    __shared__ _Float16 T[64][98];
    int b = blockIdx.x, tid = threadIdx.x;
    if (b < 64){
        const float* s = Wc2 + (size_t)b * 96 * 64;
        for (int i = tid; i < 96*64; i += 256){ int k = i/64, c = i - k*64; T[c][k] = (_Float16)s[i]; }
        __syncthreads();
        _Float16* d = wt2 + (size_t)b * 64 * 96;
        for (int i = tid; i < 96*64; i += 256){ int c = i/96, k = i - c*96; d[i] = T[c][k]; }
    } else if (b < 128){
        int cell = b - 64;
        const float* s = Wc3 + (size_t)cell * 64 * 64;
        for (int i = tid; i < 64*64; i += 256){ int k = i/64, c = i - k*64; T[c][k] = (_Float16)s[i]; }
        __syncthreads();
        _Float16* d = wt3 + (size_t)cell * 64 * 64;
        for (int i = tid; i < 64*64; i += 256){ int c = i/64, k = i - c*64; d[i] = T[c][k]; }
    } else {
        for (int i = tid; i < 64*8*32; i += 256) wb0[i] = f2bf(Wc0[i]);
    }
}

// -------------------------------------------- MFMA cell-conv: 128 edges/block
// Two 64-edge chunks (same cell: PADQ=128). Edge-ordered msg stores.
template<int CIN>
__global__ __launch_bounds__(256)
void conv_mfma_k(const _Float16* __restrict__ xh,        // [NFL][CIN]
                 const int4* __restrict__ entries,
                 const int* __restrict__ cellOff,
                 const _Float16* __restrict__ wt,        // [64][64][CIN]
                 _Float16* __restrict__ msg)             // [edge][64]
{
    constexpr int COUT = 64;
    constexpr int XROW = CIN*2 + 16;       // bytes: 208 (96) / 144 (64)
    constexpr int C16  = CIN*2/16;

    __shared__ unsigned char XL[64 * XROW];
    __shared__ float BW[4][64];
    __shared__ int   SRC[64];
    __shared__ int   EID[64];

    int total = cellOff[NCC];
    int pb = blockIdx.x * 128;
    if (pb >= total) return;
    int tid = threadIdx.x;

    int lo_ = 0, hi_ = NCC;
    while (hi_ - lo_ > 1){ int mid = (lo_ + hi_) >> 1; if (cellOff[mid] <= pb) lo_ = mid; else hi_ = mid; }
    const int cell = lo_;
    const int kc[4] = { cell, cell+1, cell+8, cell+9 };

    const int lane = tid & 63, wv = tid >> 6;
    const int lr = lane & 15, lg = lane >> 4;
    const int cb = wv * 16;
    const _Float16* wbase = wt + (size_t)(cb + lr) * CIN + lg * 8;

    for (int ch = 0; ch < 2; ++ch){
        int p0 = pb + ch * 64;

        if (tid < 64){
            int4 en = entries[p0 + tid];
            bool ok = en.y >= 0;
            float fx = __int_as_float(en.z), fy = __int_as_float(en.w);
            BW[0][tid] = ok ? (1.f-fx)*(1.f-fy) : 0.f;
            BW[1][tid] = ok ? (1.f-fx)*fy       : 0.f;
            BW[2][tid] = ok ? fx*(1.f-fy)       : 0.f;
            BW[3][tid] = ok ? fx*fy             : 0.f;
            SRC[tid] = en.x;
            EID[tid] = en.y;
        }
        __syncthreads();
        for (int i = tid; i < 64*C16; i += 256){
            int e = i / C16, c = i - e*C16;
            const uint4* sp = (const uint4*)(xh + (size_t)SRC[e]*CIN) + c;
            *(uint4*)(&XL[e*XROW + 16*c]) = *sp;
        }
        __syncthreads();

        f32x4 acc[4][4];   // [corner][edge-group]
#pragma unroll
        for (int cr = 0; cr < 4; ++cr)
#pragma unroll
            for (int ae = 0; ae < 4; ++ae)
                acc[cr][ae] = (f32x4)0.f;

#pragma unroll
        for (int k0 = 0; k0 < CIN; k0 += 32){
            half8 b[4], a[4];
#pragma unroll
            for (int cr = 0; cr < 4; ++cr)
                b[cr] = *(const half8*)(wbase + (size_t)kc[cr]*(COUT*CIN) + k0);
#pragma unroll
            for (int ae = 0; ae < 4; ++ae)
                a[ae] = *(const half8*)(XL + (16*ae + lr)*XROW + k0*2 + lg*16);
#pragma unroll
            for (int cr = 0; cr < 4; ++cr)
#pragma unroll
                for (int ae = 0; ae < 4; ++ae)
                    acc[cr][ae] = __builtin_amdgcn_mfma_f32_16x16x32_f16(a[ae], b[cr], acc[cr][ae], 0, 0, 0);
        }

#pragma unroll
        for (int ae = 0; ae < 4; ++ae){
#pragma unroll
            for (int r = 0; r < 4; ++r){
                int E = 16*ae + lg*4 + r;
                int eid = EID[E];
                if (eid >= 0){
                    float v = BW[0][E]*acc[0][ae][r] + BW[1][E]*acc[1][ae][r]
                            + BW[2][E]*acc[2][ae][r] + BW[3][E]*acc[3][ae][r];
                    msg[(size_t)eid*COUT + cb + lr] = (_Float16)v;
                }
            }
        }
        __syncthreads();   // protect BW/SRC/EID/XL before next chunk restage
    }
}

// -------------------------- fp32 cell-conv (conv0: CIN=8, COUT=32), fp16 msg
template<int CIN, int COUT, int TILE_E, bool RELU>
__global__ __launch_bounds__(128)
void conv_cell_k(const float* __restrict__ x,
                 const int4* __restrict__ entries,
                 const int* __restrict__ cellOff,
                 const unsigned short* __restrict__ Wbf,
                 _Float16* __restrict__ msg)             // [edge][COUT]
{
    constexpr int TEP = TILE_E + 4;
    constexpr int EG  = TILE_E / 4;
    constexpr int CG  = COUT / 8;
    static_assert(EG * CG == 128, "tile/thread mismatch");
    constexpr int C4  = CIN / 4;

    __shared__ float XT[CIN][TEP];
    __shared__ unsigned short WLc[4][CIN][COUT];
    __shared__ int4 EN[TILE_E];

    int total = cellOff[NCC];
    int p0 = blockIdx.x * TILE_E;
    if (p0 >= total) return;
    int tid = threadIdx.x;

    int lo = 0, hi = NCC;
    while (hi - lo > 1){ int mid = (lo + hi) >> 1; if (cellOff[mid] <= p0) lo = mid; else hi = mid; }
    const int cell = lo;

    for (int i = tid; i < TILE_E; i += 128) EN[i] = entries[p0 + i];

    const int kc[4] = { cell, cell + 1, cell + 8, cell + 9 };
#pragma unroll
    for (int c = 0; c < 4; ++c){
        const uint4* s = (const uint4*)(Wbf + (size_t)kc[c] * (CIN * COUT));
        uint4* dlds = (uint4*)(&WLc[c][0][0]);
        for (int i = tid; i < CIN * COUT / 8; i += 128) dlds[i] = s[i];
    }
    __syncthreads();

    for (int i = tid; i < TILE_E * C4; i += 128){
        int e  = i / C4;
        int c4 = i - e * C4;
        int4 en = EN[e];
        float4 v = make_float4(0.f, 0.f, 0.f, 0.f);
        if (en.y >= 0){
            v = *(const float4*)(x + (size_t)en.x * CIN + 4 * c4);
            if (RELU){ v.x = frelu(v.x); v.y = frelu(v.y); v.z = frelu(v.z); v.w = frelu(v.w); }
        }
        XT[4*c4+0][e] = v.x;
        XT[4*c4+1][e] = v.y;
        XT[4*c4+2][e] = v.z;
        XT[4*c4+3][e] = v.w;
    }
    __syncthreads();

    const int egrp = tid % EG;
    const int cgrp = tid / EG;
    const int e0 = egrp * 4;

    float fx[4], fy[4];
    int eid[4];
#pragma unroll
    for (int j = 0; j < 4; ++j){
        int4 en = EN[e0 + j];
        fx[j] = __int_as_float(en.z);
        fy[j] = __int_as_float(en.w);
        eid[j] = en.y;
    }

    float accT[4][8];
#pragma unroll
    for (int j = 0; j < 4; ++j)
#pragma unroll
        for (int c = 0; c < 8; ++c) accT[j][c] = 0.f;

#pragma unroll
    for (int cr = 0; cr < 4; ++cr){
        float accC[4][8];
#pragma unroll
        for (int j = 0; j < 4; ++j)
#pragma unroll
            for (int c = 0; c < 8; ++c) accC[j][c] = 0.f;

#pragma unroll
        for (int ci = 0; ci < CIN; ++ci){
            float4 xv = *(const float4*)&XT[ci][e0];
            uint4 wp = *(const uint4*)&WLc[cr][ci][cgrp * 8];
            float wf0 = __uint_as_float(wp.x << 16);
            float wf1 = __uint_as_float(wp.x & 0xFFFF0000u);
            float wf2 = __uint_as_float(wp.y << 16);
            float wf3 = __uint_as_float(wp.y & 0xFFFF0000u);
            float wf4 = __uint_as_float(wp.z << 16);
            float wf5 = __uint_as_float(wp.z & 0xFFFF0000u);
            float wf6 = __uint_as_float(wp.w << 16);
            float wf7 = __uint_as_float(wp.w & 0xFFFF0000u);
            const float xe[4] = { xv.x, xv.y, xv.z, xv.w };
#pragma unroll
            for (int j = 0; j < 4; ++j){
                accC[j][0] += xe[j] * wf0;
                accC[j][1] += xe[j] * wf1;
                accC[j][2] += xe[j] * wf2;
                accC[j][3] += xe[j] * wf3;
                accC[j][4] += xe[j] * wf4;
                accC[j][5] += xe[j] * wf5;
                accC[j][6] += xe[j] * wf6;
                accC[j][7] += xe[j] * wf7;
            }
        }
#pragma unroll
        for (int j = 0; j < 4; ++j){
            float wc = (cr == 0) ? (1.f - fx[j]) * (1.f - fy[j]) :
                       (cr == 1) ? (1.f - fx[j]) * fy[j] :
                       (cr == 2) ? fx[j] * (1.f - fy[j]) :
                                   fx[j] * fy[j];
#pragma unroll
            for (int c = 0; c < 8; ++c) accT[j][c] += wc * accC[j][c];
        }
    }

#pragma unroll
    for (int j = 0; j < 4; ++j){
        if (eid[j] < 0) continue;
        half8 hv;
#pragma unroll
        for (int c = 0; c < 8; ++c) hv[c] = (_Float16)accT[j][c];
        *(half8*)(msg + (size_t)eid[j] * COUT + cgrp * 8) = hv;
    }
}

// --------------------------- final conv (64->2): thread-per-edge, fp16 x rows
__global__ __launch_bounds__(128)
void conv2_msg_k(const _Float16* __restrict__ xh,        // relu(y2) fp16 [NFL][64]
                 const int4* __restrict__ entries,
                 const int* __restrict__ cellOff,
                 const float* __restrict__ Wc,
                 float* __restrict__ msg2)                // [edge][2]
{
    __shared__ float WLf[4][64][2];
    int total = cellOff[NCC];
    int p0 = blockIdx.x * 128;
    if (p0 >= total) return;
    int tid = threadIdx.x;

    int lo = 0, hi = NCC;
    while (hi - lo > 1){ int mid = (lo + hi) >> 1; if (cellOff[mid] <= p0) lo = mid; else hi = mid; }
    const int cell = lo;
    const int kc[4] = { cell, cell + 1, cell + 8, cell + 9 };
#pragma unroll
    for (int c = 0; c < 4; ++c)
        ((float*)&WLf[c][0][0])[tid] = Wc[(size_t)kc[c] * 128 + tid];
    __syncthreads();

    int4 en = entries[p0 + tid];
    if (en.y < 0) return;
    float fx = __int_as_float(en.z), fy = __int_as_float(en.w);
    const _Float16* xp = xh + (size_t)en.x * 64;

    float a[4][2] = {{0.f,0.f},{0.f,0.f},{0.f,0.f},{0.f,0.f}};
#pragma unroll
    for (int ci = 0; ci < 64; ci += 8){
        half8 v = *(const half8*)(xp + ci);
#pragma unroll
        for (int j = 0; j < 8; ++j){
            float xe = (float)v[j];
#pragma unroll
            for (int cr = 0; cr < 4; ++cr){
                a[cr][0] += xe * WLf[cr][ci+j][0];
                a[cr][1] += xe * WLf[cr][ci+j][1];
            }
        }
    }
    float w0 = (1.f-fx)*(1.f-fy), w1 = (1.f-fx)*fy, w2 = fx*(1.f-fy), w3 = fx*fy;
    float m0 = w0*a[0][0] + w1*a[1][0] + w2*a[2][0] + w3*a[3][0];
    float m1 = w0*a[0][1] + w1*a[1][1] + w2*a[2][1] + w3*a[3][1];
    *(float2*)(msg2 + (size_t)en.y * 2) = make_float2(m0, m1);
}

// --------------------------- final combine: thread-per-target, out = .../128
__global__ __launch_bounds__(256)
void final_combine_k(const float* __restrict__ y2,
                     const float* __restrict__ Wl3, const float* __restrict__ bl3,
                     const float* __restrict__ bc4,
                     const float* __restrict__ msg2,
                     const int* __restrict__ rowptr,
                     float* __restrict__ out)
{
    __shared__ float WS[128];
    int tid = threadIdx.x;
    if (tid < 128) WS[tid] = Wl3[tid];
    __syncthreads();

    int t = blockIdx.x * blockDim.x + tid;
    if (t >= NFL) return;
    int eb = rowptr[t], ee = rowptr[t+1];

    float a0 = bc4[0] + bl3[0];
    float a1 = bc4[1] + bl3[1];
    const float* pr = y2 + (size_t)t * 64;
#pragma unroll 4
    for (int ci = 0; ci < 64; ci += 4){
        float4 v = *(const float4*)(pr + ci);
        float xe[4] = { frelu(v.x), frelu(v.y), frelu(v.z), frelu(v.w) };
#pragma unroll
        for (int j = 0; j < 4; ++j){
            a0 += xe[j] * WS[(ci+j)*2];
            a1 += xe[j] * WS[(ci+j)*2 + 1];
        }
    }
    for (int e = eb; e < ee; ++e){
        float2 m = *(const float2*)(msg2 + (size_t)e * 2);
        a0 += m.x; a1 += m.y;
    }
    out[(size_t)t*2]     = a0 * (1.0f/128.0f);
    out[(size_t)t*2 + 1] = a1 * (1.0f/128.0f);
}

// ---------------- combine0: lin + conv0-msg-sum + FUSED bconv; ansA + xbA ---
__global__ __launch_bounds__(256)
void combine0_k(const float* __restrict__ feat,
                const float* __restrict__ bnd_feat,
                const float* __restrict__ Wl0, const float* __restrict__ bl0,
                const float* __restrict__ bc0,
                const float* __restrict__ Wc1, const float* __restrict__ bc1,
                const EdgeData* __restrict__ edB,
                const int* __restrict__ rowptrB,
                const _Float16* __restrict__ msg,        // [edge][32]
                const int* __restrict__ rowptrF,
                float* __restrict__ ansA,
                _Float16* __restrict__ xbA)              // [NFL][96] relu fp16
{
    int t = blockIdx.x * (blockDim.x >> 6) + (threadIdx.x >> 6);
    if (t >= NFL) return;
    int lane = threadIdx.x & 63;

    if (lane < 32){
        float a = bl0[lane];
#pragma unroll
        for (int ci = 0; ci < 8; ++ci)
            a += feat[t*8 + ci] * Wl0[ci*32 + lane];
        ansA[(size_t)t*96 + lane] = a;
        xbA[(size_t)t*96 + lane]  = (_Float16)frelu(a);

        float b = bc1[lane];
        int eb = rowptrB[t], ee = rowptrB[t+1];
        for (int e = eb; e < ee; ++e){
            EdgeData d = edB[e];
            const float* xp = bnd_feat + (size_t)d.src * 8;
            const float* wp = Wc1 + (size_t)d.ixiy * 256 + lane;
            float t00 = 0.f, t01 = 0.f, t10 = 0.f, t11 = 0.f;
#pragma unroll
            for (int ci = 0; ci < 8; ++ci){
                float xv = xp[ci];
                t00 += xv * wp[ci*32];
                t01 += xv * wp[ci*32 + 256];
                t10 += xv * wp[ci*32 + 2048];
                t11 += xv * wp[ci*32 + 2304];
            }
            float wx1 = d.fx, wy1 = d.fy;
            float wx0 = 1.f - wx1, wy0 = 1.f - wy1;
            b += (wx0*wy0)*t00 + (wx0*wy1)*t01 + (wx1*wy0)*t10 + (wx1*wy1)*t11;
        }
        ansA[(size_t)t*96 + 64 + lane] = b;
        xbA[(size_t)t*96 + 64 + lane]  = (_Float16)frelu(b);
    } else {
        int c = lane - 32;
        float a = bc0[c];
        int eb = rowptrF[t], ee = rowptrF[t+1];
        for (int e = eb; e < ee; ++e)
            a += (float)msg[(size_t)e*32 + c];
        ansA[(size_t)t*96 + 32 + c] = a;
        xbA[(size_t)t*96 + 32 + c]  = (_Float16)frelu(a);
    }
}

// ------- combine: msg-sum + dns (fp16 input) + bias (+resid); y + relu fp16
template<int CIN, bool RESID, bool WRITE_XB>
__global__ __launch_bounds__(256)
void combine12_k(const float* __restrict__ yprev,        // for residual only
                 const _Float16* __restrict__ xprev,     // relu'd fp16 [NFL][CIN]
                 const float* __restrict__ Wl, const float* __restrict__ bl,
                 const float* __restrict__ bc,
                 const _Float16* __restrict__ msg,       // [edge][64]
                 const int* __restrict__ rowptr,
                 float* __restrict__ y,
                 _Float16* __restrict__ xbnext)          // [NFL][64]
{
    int t = blockIdx.x * (blockDim.x >> 6) + (threadIdx.x >> 6);
    if (t >= NFL) return;
    int lane = threadIdx.x & 63;
    int eb = rowptr[t], ee = rowptr[t+1];

    const _Float16* pr = xprev + (size_t)t * CIN;
    float acc = bc[lane] + bl[lane];
#pragma unroll 8
    for (int ci = 0; ci < CIN; ++ci)
        acc += (float)pr[ci] * Wl[ci*64 + lane];
    if (RESID) acc += yprev[(size_t)t*64 + lane];

    for (int e = eb; e < ee; ++e)
        acc += (float)msg[(size_t)e*64 + lane];
    y[(size_t)t*64 + lane] = acc;

    if (WRITE_XB)
        xbnext[(size_t)t*64 + lane] = (_Float16)frelu(acc);
}

// ---------------------------------------------------------------------------
extern "C" void kernel_launch(void* const* d_in, const int* in_sizes, int n_in,
                              void* d_out, int out_size, void* d_ws, size_t ws_size,
                              hipStream_t stream)
{
    const float* fluid_pos  = (const float*)d_in[0];
    const float* bnd_pos    = (const float*)d_in[1];
    const float* fluid_feat = (const float*)d_in[2];
    const float* bnd_feat   = (const float*)d_in[3];
    const int*   f_tgt      = (const int*)  d_in[4];
    const int*   f_src      = (const int*)  d_in[5];
    const int*   b_tgt      = (const int*)  d_in[6];
    const int*   b_src      = (const int*)  d_in[7];
    const float* Wc0 = (const float*)d_in[8];  const float* bc0 = (const float*)d_in[9];
    const float* Wc1 = (const float*)d_in[10]; const float* bc1 = (const float*)d_in[11];
    const float* Wc2 = (const float*)d_in[12]; const float* bc2 = (const float*)d_in[13];
    const float* Wc3 = (const float*)d_in[14]; const float* bc3 = (const float*)d_in[15];
    const float* Wc4 = (const float*)d_in[16]; const float* bc4 = (const float*)d_in[17];
    const float* Wl0 = (const float*)d_in[18]; const float* bl0 = (const float*)d_in[19];
    const float* Wl1 = (const float*)d_in[20]; const float* bl1 = (const float*)d_in[21];
    const float* Wl2 = (const float*)d_in[22]; const float* bl2 = (const float*)d_in[23];
    const float* Wl3 = (const float*)d_in[24]; const float* bl3 = (const float*)d_in[25];

    int nEf = in_sizes[4];
    int nEb = in_sizes[6];
    int entPadMax = nEf + NCC * PADQ;
    float support = (float)sqrt(16.0 / (M_PI * 16384.0));

    char* w = (char*)d_ws;
    auto alloc = [&](size_t bytes){ char* r = w; w += (bytes + 255) & ~(size_t)255; return r; };
    EdgeData* edF      = (EdgeData*)alloc((size_t)nEf * sizeof(EdgeData));
    EdgeData* edB      = (EdgeData*)alloc((size_t)nEb * sizeof(EdgeData));
    int*      cnt      = (int*)     alloc(64 * sizeof(int));
    int*      cellOff  = (int*)     alloc(64 * sizeof(int));
    int*      gcursor  = (int*)     alloc(64 * sizeof(int));
    int*      rowptrF  = (int*)     alloc((NFL+1) * sizeof(int));
    int*      rowptrB  = (int*)     alloc((NFL+1) * sizeof(int));
    int4*     entries  = (int4*)    alloc((size_t)entPadMax * sizeof(int4));
    unsigned short* wb0 = (unsigned short*)alloc((size_t)64*8*32 * 2);
    _Float16* wt2      = (_Float16*)alloc((size_t)64*64*96 * 2);  // [cell][cout][k]
    _Float16* wt3      = (_Float16*)alloc((size_t)64*64*64 * 2);
    _Float16* xbA      = (_Float16*)alloc((size_t)NFL*96 * 2);
    _Float16* xb1      = (_Float16*)alloc((size_t)NFL*64 * 2);
    _Float16* xb2      = (_Float16*)alloc((size_t)NFL*64 * 2);
    float*    ansA     = (float*)   alloc((size_t)NFL * 96 * sizeof(float));
    float*    y1       = (float*)   alloc((size_t)NFL * 64 * sizeof(float));
    float*    y2       = (float*)   alloc((size_t)NFL * 64 * sizeof(float));
    _Float16* msg      = (_Float16*)alloc((size_t)nEf * 64 * 2);
    float*    msg2     = (float*)   alloc((size_t)nEf * 2 * sizeof(float));

    // ---- setup: zero hist + fused prep (edges F/B, hist, rowptrs)
    hipMemsetAsync(cnt, 0, 64 * sizeof(int), stream);
    int nA = (nEf + 255)/256, nB = (nEb + 255)/256, nC = (NFL + 256)/256;
    setup_k<<<nA + nB + 2*nC, 256, 0, stream>>>(fluid_pos, bnd_pos,
                                                f_tgt, f_src, nEf,
                                                b_tgt, b_src, nEb, support,
                                                edF, edB, cnt, rowptrF, rowptrB,
                                                nA, nB, nC);
    scan_pad_k<<<1, 256, 0, stream>>>(cnt, cellOff, gcursor, entries);
    scatter_k<<<nA, 256, 0, stream>>>(edF, nEf, cellOff, gcursor, entries);
    wprep_k<<<129, 256, 0, stream>>>(Wc2, Wc3, Wc0, wt2, wt3, wb0);

    int gridM   = (entPadMax + 127) / 128;
    dim3 tgrid(NFL/4);

    // ---- input block
    conv_cell_k<8,32,128,false><<<gridM, 128, 0, stream>>>(fluid_feat, entries, cellOff, wb0, msg);
    combine0_k<<<tgrid, 256, 0, stream>>>(fluid_feat, bnd_feat, Wl0, bl0, bc0,
                                          Wc1, bc1, edB, rowptrB,
                                          msg, rowptrF, ansA, xbA);

    // ---- block 1
    conv_mfma_k<96><<<gridM, 256, 0, stream>>>(xbA, entries, cellOff, wt2, msg);
    combine12_k<96,false,true><<<tgrid, 256, 0, stream>>>(nullptr, xbA, Wl1, bl1, bc2, msg, rowptrF, y1, xb1);

    // ---- block 2
    conv_mfma_k<64><<<gridM, 256, 0, stream>>>(xb1, entries, cellOff, wt3, msg);
    combine12_k<64,true,true><<<tgrid, 256, 0, stream>>>(y1, xb1, Wl2, bl2, bc3, msg, rowptrF, y2, xb2);

    // ---- block 3 (final)
    conv2_msg_k<<<gridM, 128, 0, stream>>>(xb2, entries, cellOff, Wc4, msg2);
    final_combine_k<<<(NFL+255)/256, 256, 0, stream>>>(y2, Wl3, bl3, bc4, msg2, rowptrF, (float*)d_out);
}